// Round 1
// baseline (7594.090 us; speedup 1.0000x reference)
//
#include <hip/hip_runtime.h>
#include <math.h>

#define NL 50000
#define NN 50000
#define NE 600000
#define NG 64
#define DD 128
#define BIGF 6400000   // 50000*128 floats

// ---------------- degree kernels ----------------
__global__ void deg_kernel(const int* __restrict__ src, const int* __restrict__ dst,
                           float* __restrict__ dsrc, float* __restrict__ ddst, int E) {
    int e = blockIdx.x * blockDim.x + threadIdx.x;
    if (e < E) {
        atomicAdd(&dsrc[src[e]], 1.0f);
        atomicAdd(&ddst[dst[e]], 1.0f);
    }
}

__global__ void rsq_kernel(float* __restrict__ a, int n) {
    int i = blockIdx.x * blockDim.x + threadIdx.x;
    if (i < n) a[i] = rsqrtf(fmaxf(a[i], 1.0f));
}

// ---------------- row-scaled GEMM: out[m][n] = rsq[m] * sum_k A[m][k]*W[k][n] ----------------
// BM=64, BN=128, BK=16, 256 threads, each thread 8 rows x 4 cols
__global__ __launch_bounds__(256) void proj_gemm(const float* __restrict__ A,
                                                 const float* __restrict__ W,
                                                 const float* __restrict__ rsq,
                                                 float* __restrict__ out,
                                                 int M, int K) {
    __shared__ float As[16][72];    // [k][m], row stride 72 floats (288B, 16B-mult)
    __shared__ float Ws[16][128];
    const int bm = blockIdx.x * 64;
    const int t  = threadIdx.x;
    const int ty = t >> 5;          // 0..7  (row group)
    const int tx = t & 31;          // 0..31 (col group of 4)

    float acc[8][4];
#pragma unroll
    for (int r = 0; r < 8; ++r)
#pragma unroll
        for (int c = 0; c < 4; ++c) acc[r][c] = 0.0f;

    for (int k0 = 0; k0 < K; k0 += 16) {
        // A tile: 64 x 16
#pragma unroll
        for (int it = 0; it < 4; ++it) {
            int m = (t >> 4) + 16 * it;   // 0..63
            int k = (t & 15);
            int gm = bm + m, gk = k0 + k;
            float v = (gm < M && gk < K) ? A[(size_t)gm * K + gk] : 0.0f;
            As[k][m] = v;
        }
        // W tile: 16 x 128
#pragma unroll
        for (int it = 0; it < 8; ++it) {
            int k = (t >> 7) + 2 * it;    // 0..15
            int n = (t & 127);
            int gk = k0 + k;
            Ws[k][n] = (gk < K) ? W[(size_t)gk * 128 + n] : 0.0f;
        }
        __syncthreads();
#pragma unroll
        for (int kk = 0; kk < 16; ++kk) {
            float a0[8];
#pragma unroll
            for (int r = 0; r < 8; ++r) a0[r] = As[kk][ty * 8 + r];
            float4 wv = *(const float4*)&Ws[kk][tx * 4];
#pragma unroll
            for (int r = 0; r < 8; ++r) {
                acc[r][0] = fmaf(a0[r], wv.x, acc[r][0]);
                acc[r][1] = fmaf(a0[r], wv.y, acc[r][1]);
                acc[r][2] = fmaf(a0[r], wv.z, acc[r][2]);
                acc[r][3] = fmaf(a0[r], wv.w, acc[r][3]);
            }
        }
        __syncthreads();
    }
#pragma unroll
    for (int r = 0; r < 8; ++r) {
        int gm = bm + ty * 8 + r;
        if (gm < M) {
            float s = rsq[gm];
            float4 v = make_float4(acc[r][0] * s, acc[r][1] * s, acc[r][2] * s, acc[r][3] * s);
            *(float4*)&out[(size_t)gm * 128 + tx * 4] = v;
        }
    }
}

// ---------------- edge scatter: agg[dst] += xs[src] ----------------
__global__ __launch_bounds__(256) void scatter_kernel(const float* __restrict__ xs,
                                                      const int* __restrict__ src,
                                                      const int* __restrict__ dst,
                                                      float* __restrict__ agg, int E) {
    int gid = blockIdx.x * blockDim.x + threadIdx.x;
    int e = gid >> 5;
    if (e >= E) return;
    int f4 = gid & 31;
    int s = src[e], d = dst[e];
    float4 v = ((const float4*)xs)[(size_t)s * 32 + f4];
    float* p = &agg[(size_t)d * 128 + f4 * 4];
    atomicAdd(p + 0, v.x);
    atomicAdd(p + 1, v.y);
    atomicAdd(p + 2, v.z);
    atomicAdd(p + 3, v.w);
}

// ---------------- finalize: h = elu(ln(agg*rsq_in + bias)) ; one wave per row ----------------
__global__ __launch_bounds__(256) void finalize_kernel(const float* __restrict__ agg,
                                                       const float* __restrict__ rsq_in,
                                                       const float* __restrict__ bias,
                                                       const float* __restrict__ g,
                                                       const float* __restrict__ bln,
                                                       float* __restrict__ out, int M) {
    int row  = blockIdx.x * 4 + (threadIdx.x >> 6);
    int lane = threadIdx.x & 63;
    if (row >= M) return;
    float s = rsq_in[row];
    float2 xv = *(const float2*)&agg[(size_t)row * 128 + lane * 2];
    float2 bv = *(const float2*)&bias[lane * 2];
    float x0 = xv.x * s + bv.x;
    float x1 = xv.y * s + bv.y;

    float sum = x0 + x1;
#pragma unroll
    for (int m = 1; m < 64; m <<= 1) sum += __shfl_xor(sum, m, 64);
    float mu = sum * (1.0f / 128.0f);

    float d0 = x0 - mu, d1 = x1 - mu;
    float ss = d0 * d0 + d1 * d1;
#pragma unroll
    for (int m = 1; m < 64; m <<= 1) ss += __shfl_xor(ss, m, 64);
    float rstd = rsqrtf(ss * (1.0f / 128.0f) + 1e-5f);

    float2 gv = *(const float2*)&g[lane * 2];
    float2 bl = *(const float2*)&bln[lane * 2];
    float y0 = d0 * rstd * gv.x + bl.x;
    float y1 = d1 * rstd * gv.y + bl.y;
    // ELU (alpha=1)
    y0 = (y0 > 0.0f) ? y0 : expm1f(y0);
    y1 = (y1 > 0.0f) ? y1 : expm1f(y1);
    float2 o = make_float2(y0, y1);
    *(float2*)&out[(size_t)row * 128 + lane * 2] = o;
}

// ---------------- pooling accumulate ----------------
__global__ __launch_bounds__(256) void pool_acc(const float* __restrict__ h,
                                                const int* __restrict__ gid,
                                                float* __restrict__ sum,
                                                float* __restrict__ cnt, int M) {
    int i = blockIdx.x * blockDim.x + threadIdx.x;
    int node = i >> 5;
    if (node >= M) return;
    int f4 = i & 31;
    int gI = gid[node];
    float4 v = ((const float4*)h)[(size_t)node * 32 + f4];
    float* p = &sum[gI * 128 + f4 * 4];
    atomicAdd(p + 0, v.x);
    atomicAdd(p + 1, v.y);
    atomicAdd(p + 2, v.z);
    atomicAdd(p + 3, v.w);
    if (f4 == 0) atomicAdd(&cnt[gI], 1.0f);
}

// ---------------- head: hg = mean_l + mean_n ; relu(hg@Wfc+bfc) @ Wout + bout ----------------
__global__ __launch_bounds__(128) void head_kernel(const float* __restrict__ sum_l,
                                                   const float* __restrict__ cnt_l,
                                                   const float* __restrict__ sum_n,
                                                   const float* __restrict__ cnt_n,
                                                   const float* __restrict__ W_fc,
                                                   const float* __restrict__ b_fc,
                                                   const float* __restrict__ W_out,
                                                   const float* __restrict__ b_out,
                                                   float* __restrict__ out) {
    int gI = blockIdx.x;
    int j = threadIdx.x;   // 0..127
    __shared__ float hg[128];
    __shared__ float red[2];
    float cl = fmaxf(cnt_l[gI], 1.0f);
    float cn = fmaxf(cnt_n[gI], 1.0f);
    hg[j] = sum_l[gI * 128 + j] / cl + sum_n[gI * 128 + j] / cn;
    __syncthreads();
    float acc = b_fc[j];
#pragma unroll 8
    for (int k = 0; k < 128; ++k) acc = fmaf(hg[k], W_fc[k * 128 + j], acc);
    float fc = fmaxf(acc, 0.0f);
    float v = fc * W_out[j];
#pragma unroll
    for (int m = 1; m < 64; m <<= 1) v += __shfl_xor(v, m, 64);
    if ((j & 63) == 0) red[j >> 6] = v;
    __syncthreads();
    if (j == 0) out[gI] = red[0] + red[1] + b_out[0];
}

extern "C" void kernel_launch(void* const* d_in, const int* in_sizes, int n_in,
                              void* d_out, int out_size, void* d_ws, size_t ws_size,
                              hipStream_t stream) {
    const float* feat_l = (const float*)d_in[0];
    const float* feat_n = (const float*)d_in[1];
    const float* W0_l2n = (const float*)d_in[2];
    const float* b0_l2n = (const float*)d_in[3];
    const float* W0_n2l = (const float*)d_in[4];
    const float* b0_n2l = (const float*)d_in[5];
    const float* W_l2n  = (const float*)d_in[6];
    const float* b_l2n  = (const float*)d_in[7];
    const float* W_n2l  = (const float*)d_in[8];
    const float* b_n2l  = (const float*)d_in[9];
    const float* ln_g_n = (const float*)d_in[10];
    const float* ln_b_n = (const float*)d_in[11];
    const float* ln_g_l = (const float*)d_in[12];
    const float* ln_b_l = (const float*)d_in[13];
    const float* W_fc   = (const float*)d_in[14];
    const float* b_fc   = (const float*)d_in[15];
    const float* W_out  = (const float*)d_in[16];
    const float* b_out  = (const float*)d_in[17];
    const int* src_l2n  = (const int*)d_in[18];
    const int* dst_l2n  = (const int*)d_in[19];
    const int* src_n2l  = (const int*)d_in[20];
    const int* dst_n2l  = (const int*)d_in[21];
    const int* gid_l    = (const int*)d_in[22];
    const int* gid_n    = (const int*)d_in[23];

    float* wsf = (float*)d_ws;
    float* deg = wsf;                       // 200000 floats
    float* rsq_src_l2n = deg;               // NL
    float* rsq_dst_l2n = deg + NL;          // NN
    float* rsq_src_n2l = deg + NL + NN;     // NN
    float* rsq_dst_n2l = deg + NL + 2 * NN; // NL
    float* big = deg + 200000;
    float* B0 = big;
    float* B1 = big + (size_t)BIGF;
    float* B2 = big + (size_t)2 * BIGF;
    float* B3 = big + (size_t)3 * BIGF;
    float* pool = big + (size_t)4 * BIGF;
    float* sum_l = pool;
    float* sum_n = pool + NG * DD;
    float* cnt_l = pool + 2 * NG * DD;
    float* cnt_n = cnt_l + NG;

    const int TB = 256;
    const int gemm_grid = (NL + 63) / 64;          // 782
    const int scat_grid = ((size_t)NE * 32 + TB - 1) / TB;
    const int fin_grid  = (NL + 3) / 4;
    const int pool_grid = ((size_t)NL * 32 + TB - 1) / TB;

    // degrees (once; same edge lists all layers)
    hipMemsetAsync(deg, 0, 200000 * sizeof(float), stream);
    deg_kernel<<<(NE + TB - 1) / TB, TB, 0, stream>>>(src_l2n, dst_l2n, rsq_src_l2n, rsq_dst_l2n, NE);
    deg_kernel<<<(NE + TB - 1) / TB, TB, 0, stream>>>(src_n2l, dst_n2l, rsq_src_n2l, rsq_dst_n2l, NE);
    rsq_kernel<<<(200000 + TB - 1) / TB, TB, 0, stream>>>(deg, 200000);

    // ---- layer 0 (K=300 l2n, K=200 n2l) ----
    proj_gemm<<<gemm_grid, TB, 0, stream>>>(feat_l, W0_l2n, rsq_src_l2n, B2, NL, 300);
    hipMemsetAsync(B3, 0, (size_t)BIGF * sizeof(float), stream);
    scatter_kernel<<<scat_grid, TB, 0, stream>>>(B2, src_l2n, dst_l2n, B3, NE);
    finalize_kernel<<<fin_grid, TB, 0, stream>>>(B3, rsq_dst_l2n, b0_l2n, ln_g_n, ln_b_n, B3, NN);

    proj_gemm<<<gemm_grid, TB, 0, stream>>>(feat_n, W0_n2l, rsq_src_n2l, B2, NN, 200);
    hipMemsetAsync(B0, 0, (size_t)BIGF * sizeof(float), stream);
    scatter_kernel<<<scat_grid, TB, 0, stream>>>(B2, src_n2l, dst_n2l, B0, NE);
    finalize_kernel<<<fin_grid, TB, 0, stream>>>(B0, rsq_dst_n2l, b0_n2l, ln_g_l, ln_b_l, B0, NL);

    float* hl = B0;
    float* hn = B3;
    float* fa = B1;
    float* fb = B2;

    // ---- layers 1,2 (K=128) ----
    for (int i = 1; i <= 2; ++i) {
        const float* Wl = W_l2n + (size_t)(i - 1) * DD * DD;
        const float* bl = b_l2n + (size_t)(i - 1) * DD;
        const float* Wn = W_n2l + (size_t)(i - 1) * DD * DD;
        const float* bn = b_n2l + (size_t)(i - 1) * DD;

        proj_gemm<<<gemm_grid, TB, 0, stream>>>(hl, Wl, rsq_src_l2n, fa, NL, DD);
        hipMemsetAsync(fb, 0, (size_t)BIGF * sizeof(float), stream);
        scatter_kernel<<<scat_grid, TB, 0, stream>>>(fa, src_l2n, dst_l2n, fb, NE);
        finalize_kernel<<<fin_grid, TB, 0, stream>>>(fb, rsq_dst_l2n, bl, ln_g_n + (size_t)i * DD,
                                                     ln_b_n + (size_t)i * DD, fb, NN);

        proj_gemm<<<gemm_grid, TB, 0, stream>>>(hn, Wn, rsq_src_n2l, fa, NN, DD);
        hipMemsetAsync(hn, 0, (size_t)BIGF * sizeof(float), stream);  // old hn now free
        scatter_kernel<<<scat_grid, TB, 0, stream>>>(fa, src_n2l, dst_n2l, hn, NE);
        finalize_kernel<<<fin_grid, TB, 0, stream>>>(hn, rsq_dst_n2l, bn, ln_g_l + (size_t)i * DD,
                                                     ln_b_l + (size_t)i * DD, hn, NL);

        float* nhl = hn;   // finalized into old hn buffer
        float* nhn = fb;
        fb = hl;
        hl = nhl;
        hn = nhn;
        // fa unchanged
    }

    // ---- pooling + head ----
    hipMemsetAsync(sum_l, 0, (size_t)(2 * NG * DD + 2 * NG) * sizeof(float), stream);
    pool_acc<<<pool_grid, TB, 0, stream>>>(hl, gid_l, sum_l, cnt_l, NL);
    pool_acc<<<pool_grid, TB, 0, stream>>>(hn, gid_n, sum_n, cnt_n, NN);
    head_kernel<<<NG, 128, 0, stream>>>(sum_l, cnt_l, sum_n, cnt_n, W_fc, b_fc, W_out, b_out,
                                        (float*)d_out);
}

// Round 2
// 1768.910 us; speedup vs baseline: 4.2931x; 4.2931x over previous
//
#include <hip/hip_runtime.h>
#include <math.h>

#define NL 50000
#define NN 50000
#define NE 600000
#define NG 64
#define DD 128
#define BIGF 6400000   // 50000*128 floats

// ---------------- int degree histogram ----------------
__global__ void deg_kernel(const int* __restrict__ src, const int* __restrict__ dst,
                           int* __restrict__ dsrc, int* __restrict__ ddst, int E) {
    int e = blockIdx.x * blockDim.x + threadIdx.x;
    if (e < E) {
        atomicAdd(&dsrc[src[e]], 1);
        atomicAdd(&ddst[dst[e]], 1);
    }
}

__global__ void rsq_kernel(const int* __restrict__ cnt, float* __restrict__ out, int n) {
    int i = blockIdx.x * blockDim.x + threadIdx.x;
    if (i < n) out[i] = rsqrtf(fmaxf((float)cnt[i], 1.0f));
}

// ---------------- single-block exclusive scan: row_ptr[0]=0, row_ptr[i+1]=sum cnt[0..i] ---
__global__ __launch_bounds__(1024) void scan_kernel(const int* __restrict__ cnt,
                                                    int* __restrict__ row_ptr, int n) {
    __shared__ int sm[1024];
    __shared__ int carry;
    if (threadIdx.x == 0) { carry = 0; row_ptr[0] = 0; }
    __syncthreads();
    for (int base = 0; base < n; base += 1024) {
        int i = base + threadIdx.x;
        int v = (i < n) ? cnt[i] : 0;
        sm[threadIdx.x] = v;
        __syncthreads();
        for (int off = 1; off < 1024; off <<= 1) {
            int t = (threadIdx.x >= off) ? sm[threadIdx.x - off] : 0;
            __syncthreads();
            sm[threadIdx.x] += t;
            __syncthreads();
        }
        if (i < n) row_ptr[i + 1] = carry + sm[threadIdx.x];
        __syncthreads();
        if (threadIdx.x == 0) carry += sm[1023];
        __syncthreads();
    }
}

// ---------------- CSR fill ----------------
__global__ void fill_csr(const int* __restrict__ src, const int* __restrict__ dst,
                         const int* __restrict__ row_ptr, int* __restrict__ cursor,
                         int* __restrict__ col, int E) {
    int e = blockIdx.x * blockDim.x + threadIdx.x;
    if (e < E) {
        int d = dst[e];
        int pos = atomicAdd(&cursor[d], 1);
        col[row_ptr[d] + pos] = src[e];
    }
}

// ---------------- row-scaled GEMM: out[m][n] = rsq[m] * sum_k A[m][k]*W[k][n] ----------------
__global__ __launch_bounds__(256) void proj_gemm(const float* __restrict__ A,
                                                 const float* __restrict__ W,
                                                 const float* __restrict__ rsq,
                                                 float* __restrict__ out,
                                                 int M, int K) {
    __shared__ float As[16][72];
    __shared__ float Ws[16][128];
    const int bm = blockIdx.x * 64;
    const int t  = threadIdx.x;
    const int ty = t >> 5;
    const int tx = t & 31;

    float acc[8][4];
#pragma unroll
    for (int r = 0; r < 8; ++r)
#pragma unroll
        for (int c = 0; c < 4; ++c) acc[r][c] = 0.0f;

    for (int k0 = 0; k0 < K; k0 += 16) {
#pragma unroll
        for (int it = 0; it < 4; ++it) {
            int m = (t >> 4) + 16 * it;
            int k = (t & 15);
            int gm = bm + m, gk = k0 + k;
            float v = (gm < M && gk < K) ? A[(size_t)gm * K + gk] : 0.0f;
            As[k][m] = v;
        }
#pragma unroll
        for (int it = 0; it < 8; ++it) {
            int k = (t >> 7) + 2 * it;
            int n = (t & 127);
            int gk = k0 + k;
            Ws[k][n] = (gk < K) ? W[(size_t)gk * 128 + n] : 0.0f;
        }
        __syncthreads();
#pragma unroll
        for (int kk = 0; kk < 16; ++kk) {
            float a0[8];
#pragma unroll
            for (int r = 0; r < 8; ++r) a0[r] = As[kk][ty * 8 + r];
            float4 wv = *(const float4*)&Ws[kk][tx * 4];
#pragma unroll
            for (int r = 0; r < 8; ++r) {
                acc[r][0] = fmaf(a0[r], wv.x, acc[r][0]);
                acc[r][1] = fmaf(a0[r], wv.y, acc[r][1]);
                acc[r][2] = fmaf(a0[r], wv.z, acc[r][2]);
                acc[r][3] = fmaf(a0[r], wv.w, acc[r][3]);
            }
        }
        __syncthreads();
    }
#pragma unroll
    for (int r = 0; r < 8; ++r) {
        int gm = bm + ty * 8 + r;
        if (gm < M) {
            float s = rsq[gm];
            float4 v = make_float4(acc[r][0] * s, acc[r][1] * s, acc[r][2] * s, acc[r][3] * s);
            *(float4*)&out[(size_t)gm * 128 + tx * 4] = v;
        }
    }
}

// ---------------- fused gather + finalize: one wave per dst row ----------------
// h[row] = elu(ln(rsq_in[row] * sum_{e in csr[row]} xs[col[e]] + bias))
__global__ __launch_bounds__(256) void gather_finalize(const float* __restrict__ xs,
                                                       const int* __restrict__ row_ptr,
                                                       const int* __restrict__ col,
                                                       const float* __restrict__ rsq_in,
                                                       const float* __restrict__ bias,
                                                       const float* __restrict__ g,
                                                       const float* __restrict__ bln,
                                                       float* __restrict__ out, int M) {
    int row  = blockIdx.x * 4 + (threadIdx.x >> 6);
    int lane = threadIdx.x & 63;
    if (row >= M) return;
    int beg = row_ptr[row], end = row_ptr[row + 1];

    float a0 = 0.0f, a1 = 0.0f;
    int e = beg;
    for (; e + 1 < end; e += 2) {
        int s0 = col[e], s1 = col[e + 1];
        float2 v0 = *(const float2*)&xs[(size_t)s0 * 128 + lane * 2];
        float2 v1 = *(const float2*)&xs[(size_t)s1 * 128 + lane * 2];
        a0 += v0.x + v1.x;
        a1 += v0.y + v1.y;
    }
    if (e < end) {
        int s = col[e];
        float2 v = *(const float2*)&xs[(size_t)s * 128 + lane * 2];
        a0 += v.x;
        a1 += v.y;
    }

    float sc = rsq_in[row];
    float2 bv = *(const float2*)&bias[lane * 2];
    float x0 = a0 * sc + bv.x;
    float x1 = a1 * sc + bv.y;

    float sum = x0 + x1;
#pragma unroll
    for (int m = 1; m < 64; m <<= 1) sum += __shfl_xor(sum, m, 64);
    float mu = sum * (1.0f / 128.0f);

    float d0 = x0 - mu, d1 = x1 - mu;
    float ss = d0 * d0 + d1 * d1;
#pragma unroll
    for (int m = 1; m < 64; m <<= 1) ss += __shfl_xor(ss, m, 64);
    float rstd = rsqrtf(ss * (1.0f / 128.0f) + 1e-5f);

    float2 gv = *(const float2*)&g[lane * 2];
    float2 bl = *(const float2*)&bln[lane * 2];
    float y0 = d0 * rstd * gv.x + bl.x;
    float y1 = d1 * rstd * gv.y + bl.y;
    y0 = (y0 > 0.0f) ? y0 : expm1f(y0);
    y1 = (y1 > 0.0f) ? y1 : expm1f(y1);
    *(float2*)&out[(size_t)row * 128 + lane * 2] = make_float2(y0, y1);
}

// ---------------- pooling accumulate ----------------
__global__ __launch_bounds__(256) void pool_acc(const float* __restrict__ h,
                                                const int* __restrict__ gid,
                                                float* __restrict__ sum,
                                                float* __restrict__ cnt, int M) {
    int i = blockIdx.x * blockDim.x + threadIdx.x;
    int node = i >> 5;
    if (node >= M) return;
    int f4 = i & 31;
    int gI = gid[node];
    float4 v = ((const float4*)h)[(size_t)node * 32 + f4];
    float* p = &sum[gI * 128 + f4 * 4];
    atomicAdd(p + 0, v.x);
    atomicAdd(p + 1, v.y);
    atomicAdd(p + 2, v.z);
    atomicAdd(p + 3, v.w);
    if (f4 == 0) atomicAdd(&cnt[gI], 1.0f);
}

// ---------------- head ----------------
__global__ __launch_bounds__(128) void head_kernel(const float* __restrict__ sum_l,
                                                   const float* __restrict__ cnt_l,
                                                   const float* __restrict__ sum_n,
                                                   const float* __restrict__ cnt_n,
                                                   const float* __restrict__ W_fc,
                                                   const float* __restrict__ b_fc,
                                                   const float* __restrict__ W_out,
                                                   const float* __restrict__ b_out,
                                                   float* __restrict__ out) {
    int gI = blockIdx.x;
    int j = threadIdx.x;
    __shared__ float hg[128];
    __shared__ float red[2];
    float cl = fmaxf(cnt_l[gI], 1.0f);
    float cn = fmaxf(cnt_n[gI], 1.0f);
    hg[j] = sum_l[gI * 128 + j] / cl + sum_n[gI * 128 + j] / cn;
    __syncthreads();
    float acc = b_fc[j];
#pragma unroll 8
    for (int k = 0; k < 128; ++k) acc = fmaf(hg[k], W_fc[k * 128 + j], acc);
    float fc = fmaxf(acc, 0.0f);
    float v = fc * W_out[j];
#pragma unroll
    for (int m = 1; m < 64; m <<= 1) v += __shfl_xor(v, m, 64);
    if ((j & 63) == 0) red[j >> 6] = v;
    __syncthreads();
    if (j == 0) out[gI] = red[0] + red[1] + b_out[0];
}

extern "C" void kernel_launch(void* const* d_in, const int* in_sizes, int n_in,
                              void* d_out, int out_size, void* d_ws, size_t ws_size,
                              hipStream_t stream) {
    const float* feat_l = (const float*)d_in[0];
    const float* feat_n = (const float*)d_in[1];
    const float* W0_l2n = (const float*)d_in[2];
    const float* b0_l2n = (const float*)d_in[3];
    const float* W0_n2l = (const float*)d_in[4];
    const float* b0_n2l = (const float*)d_in[5];
    const float* W_l2n  = (const float*)d_in[6];
    const float* b_l2n  = (const float*)d_in[7];
    const float* W_n2l  = (const float*)d_in[8];
    const float* b_n2l  = (const float*)d_in[9];
    const float* ln_g_n = (const float*)d_in[10];
    const float* ln_b_n = (const float*)d_in[11];
    const float* ln_g_l = (const float*)d_in[12];
    const float* ln_b_l = (const float*)d_in[13];
    const float* W_fc   = (const float*)d_in[14];
    const float* b_fc   = (const float*)d_in[15];
    const float* W_out  = (const float*)d_in[16];
    const float* b_out  = (const float*)d_in[17];
    const int* src_l2n  = (const int*)d_in[18];
    const int* dst_l2n  = (const int*)d_in[19];
    const int* src_n2l  = (const int*)d_in[20];
    const int* dst_n2l  = (const int*)d_in[21];
    const int* gid_l    = (const int*)d_in[22];
    const int* gid_n    = (const int*)d_in[23];

    // ---- workspace layout ----
    char* ws = (char*)d_ws;
    int*   icnt         = (int*)ws;                 // 4 x 50000 ints
    float* rsq          = (float*)(ws + 200000 * 4);// 4 x 50000 floats
    int*   row_ptr_l2n  = (int*)(ws + 400000 * 4);  // NN+1
    int*   row_ptr_n2l  = row_ptr_l2n + (NN + 1);   // NL+1
    int*   cursor       = row_ptr_n2l + (NL + 1);   // 50000
    int*   col_l2n      = cursor + 50000;           // E
    int*   col_n2l      = col_l2n + NE;             // E
    float* big          = (float*)(col_n2l + NE);
    float* B0 = big;
    float* B1 = big + (size_t)BIGF;
    float* B2 = big + (size_t)2 * BIGF;
    float* pool = big + (size_t)3 * BIGF;
    float* sum_l = pool;
    float* sum_n = pool + NG * DD;
    float* cnt_l = pool + 2 * NG * DD;
    float* cnt_n = cnt_l + NG;

    int* icnt_src_l2n = icnt;               // out-deg of L (l2n)
    int* icnt_dst_l2n = icnt + NL;          // in-deg of N  (l2n)
    int* icnt_src_n2l = icnt + NL + NN;     // out-deg of N (n2l)
    int* icnt_dst_n2l = icnt + NL + 2 * NN; // in-deg of L  (n2l)
    float* rsq_src_l2n = rsq;
    float* rsq_dst_l2n = rsq + NL;
    float* rsq_src_n2l = rsq + NL + NN;
    float* rsq_dst_n2l = rsq + NL + 2 * NN;

    const int TB = 256;
    const int gemm_grid = (NL + 63) / 64;
    const int gath_grid = (NL + 3) / 4;
    const int pool_grid = ((size_t)NL * 32 + TB - 1) / TB;
    const int edge_grid = (NE + TB - 1) / TB;

    // ---- degrees + CSR build (edge lists identical across layers) ----
    hipMemsetAsync(icnt, 0, 200000 * sizeof(int), stream);
    deg_kernel<<<edge_grid, TB, 0, stream>>>(src_l2n, dst_l2n, icnt_src_l2n, icnt_dst_l2n, NE);
    deg_kernel<<<edge_grid, TB, 0, stream>>>(src_n2l, dst_n2l, icnt_src_n2l, icnt_dst_n2l, NE);
    rsq_kernel<<<(200000 + TB - 1) / TB, TB, 0, stream>>>(icnt, rsq, 200000);

    scan_kernel<<<1, 1024, 0, stream>>>(icnt_dst_l2n, row_ptr_l2n, NN);
    hipMemsetAsync(cursor, 0, 50000 * sizeof(int), stream);
    fill_csr<<<edge_grid, TB, 0, stream>>>(src_l2n, dst_l2n, row_ptr_l2n, cursor, col_l2n, NE);

    scan_kernel<<<1, 1024, 0, stream>>>(icnt_dst_n2l, row_ptr_n2l, NL);
    hipMemsetAsync(cursor, 0, 50000 * sizeof(int), stream);
    fill_csr<<<edge_grid, TB, 0, stream>>>(src_n2l, dst_n2l, row_ptr_n2l, cursor, col_n2l, NE);

    // ---- layer 0 ----
    proj_gemm<<<gemm_grid, TB, 0, stream>>>(feat_l, W0_l2n, rsq_src_l2n, B0, NL, 300);
    proj_gemm<<<gemm_grid, TB, 0, stream>>>(feat_n, W0_n2l, rsq_src_n2l, B1, NN, 200);
    gather_finalize<<<gath_grid, TB, 0, stream>>>(B0, row_ptr_l2n, col_l2n, rsq_dst_l2n,
                                                  b0_l2n, ln_g_n, ln_b_n, B2, NN);
    gather_finalize<<<gath_grid, TB, 0, stream>>>(B1, row_ptr_n2l, col_n2l, rsq_dst_n2l,
                                                  b0_n2l, ln_g_l, ln_b_l, B0, NL);
    float* hl = B0;
    float* hn = B2;
    float* sp = B1;

    // ---- layers 1,2 (K=128) ----
    for (int i = 1; i <= 2; ++i) {
        const float* Wl = W_l2n + (size_t)(i - 1) * DD * DD;
        const float* bl = b_l2n + (size_t)(i - 1) * DD;
        const float* Wn = W_n2l + (size_t)(i - 1) * DD * DD;
        const float* bn = b_n2l + (size_t)(i - 1) * DD;

        proj_gemm<<<gemm_grid, TB, 0, stream>>>(hl, Wl, rsq_src_l2n, sp, NL, DD);  // X
        proj_gemm<<<gemm_grid, TB, 0, stream>>>(hn, Wn, rsq_src_n2l, hl, NN, DD);  // Y (hl free)
        gather_finalize<<<gath_grid, TB, 0, stream>>>(sp, row_ptr_l2n, col_l2n, rsq_dst_l2n,
                                                      bl, ln_g_n + (size_t)i * DD,
                                                      ln_b_n + (size_t)i * DD, hn, NN);
        gather_finalize<<<gath_grid, TB, 0, stream>>>(hl, row_ptr_n2l, col_n2l, rsq_dst_n2l,
                                                      bn, ln_g_l + (size_t)i * DD,
                                                      ln_b_l + (size_t)i * DD, sp, NL);
        float* t = hl; hl = sp; sp = t;   // new h_l in sp_old; old hl buffer becomes spare
    }

    // ---- pooling + head ----
    hipMemsetAsync(sum_l, 0, (size_t)(2 * NG * DD + 2 * NG) * sizeof(float), stream);
    pool_acc<<<pool_grid, TB, 0, stream>>>(hl, gid_l, sum_l, cnt_l, NL);
    pool_acc<<<pool_grid, TB, 0, stream>>>(hn, gid_n, sum_n, cnt_n, NN);
    head_kernel<<<NG, 128, 0, stream>>>(sum_l, cnt_l, sum_n, cnt_n, W_fc, b_fc, W_out, b_out,
                                        (float*)d_out);
}

// Round 3
// 1035.409 us; speedup vs baseline: 7.3344x; 1.7084x over previous
//
#include <hip/hip_runtime.h>
#include <math.h>

#define NL 50000
#define NN 50000
#define NE 600000
#define NG 64
#define DD 128
#define BIGF 6400000   // 50000*128 floats
#define PSPLIT 8

// ---------------- int degree histogram ----------------
__global__ void deg_kernel(const int* __restrict__ src, const int* __restrict__ dst,
                           int* __restrict__ dsrc, int* __restrict__ ddst, int E) {
    int e = blockIdx.x * blockDim.x + threadIdx.x;
    if (e < E) {
        atomicAdd(&dsrc[src[e]], 1);
        atomicAdd(&ddst[dst[e]], 1);
    }
}

__global__ void rsq_kernel(const int* __restrict__ cnt, float* __restrict__ out, int n) {
    int i = blockIdx.x * blockDim.x + threadIdx.x;
    if (i < n) out[i] = rsqrtf(fmaxf((float)cnt[i], 1.0f));
}

// ---------------- single-block exclusive scan ----------------
__global__ __launch_bounds__(1024) void scan_kernel(const int* __restrict__ cnt,
                                                    int* __restrict__ row_ptr, int n) {
    __shared__ int sm[1024];
    __shared__ int carry;
    if (threadIdx.x == 0) { carry = 0; row_ptr[0] = 0; }
    __syncthreads();
    for (int base = 0; base < n; base += 1024) {
        int i = base + threadIdx.x;
        int v = (i < n) ? cnt[i] : 0;
        sm[threadIdx.x] = v;
        __syncthreads();
        for (int off = 1; off < 1024; off <<= 1) {
            int t = (threadIdx.x >= off) ? sm[threadIdx.x - off] : 0;
            __syncthreads();
            sm[threadIdx.x] += t;
            __syncthreads();
        }
        if (i < n) row_ptr[i + 1] = carry + sm[threadIdx.x];
        __syncthreads();
        if (threadIdx.x == 0) carry += sm[1023];
        __syncthreads();
    }
}

// ---------------- CSR fill ----------------
__global__ void fill_csr(const int* __restrict__ src, const int* __restrict__ dst,
                         const int* __restrict__ row_ptr, int* __restrict__ cursor,
                         int* __restrict__ col, int E) {
    int e = blockIdx.x * blockDim.x + threadIdx.x;
    if (e < E) {
        int d = dst[e];
        int pos = atomicAdd(&cursor[d], 1);
        col[row_ptr[d] + pos] = src[e];
    }
}

// ---------------- row-scaled GEMM ----------------
__global__ __launch_bounds__(256) void proj_gemm(const float* __restrict__ A,
                                                 const float* __restrict__ W,
                                                 const float* __restrict__ rsq,
                                                 float* __restrict__ out,
                                                 int M, int K) {
    __shared__ float As[16][72];
    __shared__ float Ws[16][128];
    const int bm = blockIdx.x * 64;
    const int t  = threadIdx.x;
    const int ty = t >> 5;
    const int tx = t & 31;

    float acc[8][4];
#pragma unroll
    for (int r = 0; r < 8; ++r)
#pragma unroll
        for (int c = 0; c < 4; ++c) acc[r][c] = 0.0f;

    for (int k0 = 0; k0 < K; k0 += 16) {
#pragma unroll
        for (int it = 0; it < 4; ++it) {
            int m = (t >> 4) + 16 * it;
            int k = (t & 15);
            int gm = bm + m, gk = k0 + k;
            float v = (gm < M && gk < K) ? A[(size_t)gm * K + gk] : 0.0f;
            As[k][m] = v;
        }
#pragma unroll
        for (int it = 0; it < 8; ++it) {
            int k = (t >> 7) + 2 * it;
            int n = (t & 127);
            int gk = k0 + k;
            Ws[k][n] = (gk < K) ? W[(size_t)gk * 128 + n] : 0.0f;
        }
        __syncthreads();
#pragma unroll
        for (int kk = 0; kk < 16; ++kk) {
            float a0[8];
#pragma unroll
            for (int r = 0; r < 8; ++r) a0[r] = As[kk][ty * 8 + r];
            float4 wv = *(const float4*)&Ws[kk][tx * 4];
#pragma unroll
            for (int r = 0; r < 8; ++r) {
                acc[r][0] = fmaf(a0[r], wv.x, acc[r][0]);
                acc[r][1] = fmaf(a0[r], wv.y, acc[r][1]);
                acc[r][2] = fmaf(a0[r], wv.z, acc[r][2]);
                acc[r][3] = fmaf(a0[r], wv.w, acc[r][3]);
            }
        }
        __syncthreads();
    }
#pragma unroll
    for (int r = 0; r < 8; ++r) {
        int gm = bm + ty * 8 + r;
        if (gm < M) {
            float s = rsq[gm];
            float4 v = make_float4(acc[r][0] * s, acc[r][1] * s, acc[r][2] * s, acc[r][3] * s);
            *(float4*)&out[(size_t)gm * 128 + tx * 4] = v;
        }
    }
}

// ---------------- fused gather + finalize: one wave per dst row ----------------
__global__ __launch_bounds__(256) void gather_finalize(const float* __restrict__ xs,
                                                       const int* __restrict__ row_ptr,
                                                       const int* __restrict__ col,
                                                       const float* __restrict__ rsq_in,
                                                       const float* __restrict__ bias,
                                                       const float* __restrict__ g,
                                                       const float* __restrict__ bln,
                                                       float* __restrict__ out, int M) {
    int row  = blockIdx.x * 4 + (threadIdx.x >> 6);
    int lane = threadIdx.x & 63;
    if (row >= M) return;
    int beg = row_ptr[row], end = row_ptr[row + 1];

    float a0 = 0.0f, a1 = 0.0f;
    int e = beg;
    for (; e + 1 < end; e += 2) {
        int s0 = col[e], s1 = col[e + 1];
        float2 v0 = *(const float2*)&xs[(size_t)s0 * 128 + lane * 2];
        float2 v1 = *(const float2*)&xs[(size_t)s1 * 128 + lane * 2];
        a0 += v0.x + v1.x;
        a1 += v0.y + v1.y;
    }
    if (e < end) {
        int s = col[e];
        float2 v = *(const float2*)&xs[(size_t)s * 128 + lane * 2];
        a0 += v.x;
        a1 += v.y;
    }

    float sc = rsq_in[row];
    float2 bv = *(const float2*)&bias[lane * 2];
    float x0 = a0 * sc + bv.x;
    float x1 = a1 * sc + bv.y;

    float sum = x0 + x1;
#pragma unroll
    for (int m = 1; m < 64; m <<= 1) sum += __shfl_xor(sum, m, 64);
    float mu = sum * (1.0f / 128.0f);

    float d0 = x0 - mu, d1 = x1 - mu;
    float ss = d0 * d0 + d1 * d1;
#pragma unroll
    for (int m = 1; m < 64; m <<= 1) ss += __shfl_xor(ss, m, 64);
    float rstd = rsqrtf(ss * (1.0f / 128.0f) + 1e-5f);

    float2 gv = *(const float2*)&g[lane * 2];
    float2 bl = *(const float2*)&bln[lane * 2];
    float y0 = d0 * rstd * gv.x + bl.x;
    float y1 = d1 * rstd * gv.y + bl.y;
    y0 = (y0 > 0.0f) ? y0 : expm1f(y0);
    y1 = (y1 > 0.0f) ? y1 : expm1f(y1);
    *(float2*)&out[(size_t)row * 128 + lane * 2] = make_float2(y0, y1);
}

// ---------------- segmented pooling: partial sums, no atomics, deterministic ----------------
// grid = NG*PSPLIT blocks of 128 threads; partial[(g*PSPLIT+p)*128 + j]
__global__ __launch_bounds__(128) void pool_partial(const float* __restrict__ h,
                                                    const int* __restrict__ gid,
                                                    float* __restrict__ partial, int M) {
    int g = blockIdx.x / PSPLIT;
    int p = blockIdx.x % PSPLIT;
    int j = threadIdx.x;
    __shared__ int bounds[2];
    if (j < 2) {
        int target = g + j;
        int lo = 0, hi = M;
        while (lo < hi) { int mid = (lo + hi) >> 1; if (gid[mid] < target) lo = mid + 1; else hi = mid; }
        bounds[j] = lo;
    }
    __syncthreads();
    int beg = bounds[0], end = bounds[1];
    int len = end - beg;
    int chunk = (len + PSPLIT - 1) / PSPLIT;
    int s0i = beg + p * chunk;
    int e0i = min(s0i + chunk, end);

    float s0 = 0.0f, s1 = 0.0f, s2 = 0.0f, s3 = 0.0f;
    int i = s0i;
    for (; i + 3 < e0i; i += 4) {
        s0 += h[(size_t)(i + 0) * 128 + j];
        s1 += h[(size_t)(i + 1) * 128 + j];
        s2 += h[(size_t)(i + 2) * 128 + j];
        s3 += h[(size_t)(i + 3) * 128 + j];
    }
    for (; i < e0i; ++i) s0 += h[(size_t)i * 128 + j];
    partial[(size_t)(g * PSPLIT + p) * 128 + j] = (s0 + s1) + (s2 + s3);
}

// ---------------- head: reduce partials, mean, FC, out ----------------
__global__ __launch_bounds__(128) void head_kernel(const float* __restrict__ part_l,
                                                   const float* __restrict__ part_n,
                                                   const int* __restrict__ gid_l,
                                                   const int* __restrict__ gid_n,
                                                   const float* __restrict__ W_fc,
                                                   const float* __restrict__ b_fc,
                                                   const float* __restrict__ W_out,
                                                   const float* __restrict__ b_out,
                                                   float* __restrict__ out) {
    int g = blockIdx.x;
    int j = threadIdx.x;
    __shared__ float hg[128];
    __shared__ float red[2];
    __shared__ int bounds[4];
    if (j < 4) {
        const int* gid = (j < 2) ? gid_l : gid_n;
        int target = g + (j & 1);
        int lo = 0, hi = 50000;
        while (lo < hi) { int mid = (lo + hi) >> 1; if (gid[mid] < target) lo = mid + 1; else hi = mid; }
        bounds[j] = lo;
    }
    __syncthreads();
    float cl = fmaxf((float)(bounds[1] - bounds[0]), 1.0f);
    float cn = fmaxf((float)(bounds[3] - bounds[2]), 1.0f);
    float sl = 0.0f, sn = 0.0f;
#pragma unroll
    for (int p = 0; p < PSPLIT; ++p) {
        sl += part_l[(size_t)(g * PSPLIT + p) * 128 + j];
        sn += part_n[(size_t)(g * PSPLIT + p) * 128 + j];
    }
    hg[j] = sl / cl + sn / cn;
    __syncthreads();
    float acc = b_fc[j];
#pragma unroll 8
    for (int k = 0; k < 128; ++k) acc = fmaf(hg[k], W_fc[k * 128 + j], acc);
    float fc = fmaxf(acc, 0.0f);
    float v = fc * W_out[j];
#pragma unroll
    for (int m = 1; m < 64; m <<= 1) v += __shfl_xor(v, m, 64);
    if ((j & 63) == 0) red[j >> 6] = v;
    __syncthreads();
    if (j == 0) out[g] = red[0] + red[1] + b_out[0];
}

extern "C" void kernel_launch(void* const* d_in, const int* in_sizes, int n_in,
                              void* d_out, int out_size, void* d_ws, size_t ws_size,
                              hipStream_t stream) {
    const float* feat_l = (const float*)d_in[0];
    const float* feat_n = (const float*)d_in[1];
    const float* W0_l2n = (const float*)d_in[2];
    const float* b0_l2n = (const float*)d_in[3];
    const float* W0_n2l = (const float*)d_in[4];
    const float* b0_n2l = (const float*)d_in[5];
    const float* W_l2n  = (const float*)d_in[6];
    const float* b_l2n  = (const float*)d_in[7];
    const float* W_n2l  = (const float*)d_in[8];
    const float* b_n2l  = (const float*)d_in[9];
    const float* ln_g_n = (const float*)d_in[10];
    const float* ln_b_n = (const float*)d_in[11];
    const float* ln_g_l = (const float*)d_in[12];
    const float* ln_b_l = (const float*)d_in[13];
    const float* W_fc   = (const float*)d_in[14];
    const float* b_fc   = (const float*)d_in[15];
    const float* W_out  = (const float*)d_in[16];
    const float* b_out  = (const float*)d_in[17];
    const int* src_l2n  = (const int*)d_in[18];
    const int* dst_l2n  = (const int*)d_in[19];
    const int* src_n2l  = (const int*)d_in[20];
    const int* dst_n2l  = (const int*)d_in[21];
    const int* gid_l    = (const int*)d_in[22];
    const int* gid_n    = (const int*)d_in[23];

    // ---- workspace layout ----
    char* ws = (char*)d_ws;
    int*   icnt         = (int*)ws;                 // 4 x 50000 ints
    float* rsq          = (float*)(ws + 200000 * 4);// 4 x 50000 floats
    int*   row_ptr_l2n  = (int*)(ws + 400000 * 4);  // NN+1
    int*   row_ptr_n2l  = row_ptr_l2n + (NN + 1);   // NL+1
    int*   cursor       = row_ptr_n2l + (NL + 1);   // 50000
    int*   col_l2n      = cursor + 50000;           // E
    int*   col_n2l      = col_l2n + NE;             // E
    float* big          = (float*)(col_n2l + NE);
    float* B0 = big;
    float* B1 = big + (size_t)BIGF;
    float* B2 = big + (size_t)2 * BIGF;
    float* pool = big + (size_t)3 * BIGF;
    float* part_l = pool;                        // NG*PSPLIT*128
    float* part_n = pool + NG * PSPLIT * DD;     // NG*PSPLIT*128

    int* icnt_src_l2n = icnt;
    int* icnt_dst_l2n = icnt + NL;
    int* icnt_src_n2l = icnt + NL + NN;
    int* icnt_dst_n2l = icnt + NL + 2 * NN;
    float* rsq_src_l2n = rsq;
    float* rsq_dst_l2n = rsq + NL;
    float* rsq_src_n2l = rsq + NL + NN;
    float* rsq_dst_n2l = rsq + NL + 2 * NN;

    const int TB = 256;
    const int gemm_grid = (NL + 63) / 64;
    const int gath_grid = (NL + 3) / 4;
    const int edge_grid = (NE + TB - 1) / TB;

    // ---- degrees + CSR build ----
    hipMemsetAsync(icnt, 0, 200000 * sizeof(int), stream);
    deg_kernel<<<edge_grid, TB, 0, stream>>>(src_l2n, dst_l2n, icnt_src_l2n, icnt_dst_l2n, NE);
    deg_kernel<<<edge_grid, TB, 0, stream>>>(src_n2l, dst_n2l, icnt_src_n2l, icnt_dst_n2l, NE);
    rsq_kernel<<<(200000 + TB - 1) / TB, TB, 0, stream>>>(icnt, rsq, 200000);

    scan_kernel<<<1, 1024, 0, stream>>>(icnt_dst_l2n, row_ptr_l2n, NN);
    hipMemsetAsync(cursor, 0, 50000 * sizeof(int), stream);
    fill_csr<<<edge_grid, TB, 0, stream>>>(src_l2n, dst_l2n, row_ptr_l2n, cursor, col_l2n, NE);

    scan_kernel<<<1, 1024, 0, stream>>>(icnt_dst_n2l, row_ptr_n2l, NL);
    hipMemsetAsync(cursor, 0, 50000 * sizeof(int), stream);
    fill_csr<<<edge_grid, TB, 0, stream>>>(src_n2l, dst_n2l, row_ptr_n2l, cursor, col_n2l, NE);

    // ---- layer 0 ----
    proj_gemm<<<gemm_grid, TB, 0, stream>>>(feat_l, W0_l2n, rsq_src_l2n, B0, NL, 300);
    proj_gemm<<<gemm_grid, TB, 0, stream>>>(feat_n, W0_n2l, rsq_src_n2l, B1, NN, 200);
    gather_finalize<<<gath_grid, TB, 0, stream>>>(B0, row_ptr_l2n, col_l2n, rsq_dst_l2n,
                                                  b0_l2n, ln_g_n, ln_b_n, B2, NN);
    gather_finalize<<<gath_grid, TB, 0, stream>>>(B1, row_ptr_n2l, col_n2l, rsq_dst_n2l,
                                                  b0_n2l, ln_g_l, ln_b_l, B0, NL);
    float* hl = B0;
    float* hn = B2;
    float* sp = B1;

    // ---- layers 1,2 (K=128) ----
    for (int i = 1; i <= 2; ++i) {
        const float* Wl = W_l2n + (size_t)(i - 1) * DD * DD;
        const float* bl = b_l2n + (size_t)(i - 1) * DD;
        const float* Wn = W_n2l + (size_t)(i - 1) * DD * DD;
        const float* bn = b_n2l + (size_t)(i - 1) * DD;

        proj_gemm<<<gemm_grid, TB, 0, stream>>>(hl, Wl, rsq_src_l2n, sp, NL, DD);
        proj_gemm<<<gemm_grid, TB, 0, stream>>>(hn, Wn, rsq_src_n2l, hl, NN, DD);
        gather_finalize<<<gath_grid, TB, 0, stream>>>(sp, row_ptr_l2n, col_l2n, rsq_dst_l2n,
                                                      bl, ln_g_n + (size_t)i * DD,
                                                      ln_b_n + (size_t)i * DD, hn, NN);
        gather_finalize<<<gath_grid, TB, 0, stream>>>(hl, row_ptr_n2l, col_n2l, rsq_dst_n2l,
                                                      bn, ln_g_l + (size_t)i * DD,
                                                      ln_b_l + (size_t)i * DD, sp, NL);
        float* t = hl; hl = sp; sp = t;
    }

    // ---- pooling + head (deterministic, no atomics) ----
    pool_partial<<<NG * PSPLIT, 128, 0, stream>>>(hl, gid_l, part_l, NL);
    pool_partial<<<NG * PSPLIT, 128, 0, stream>>>(hn, gid_n, part_n, NN);
    head_kernel<<<NG, 128, 0, stream>>>(part_l, part_n, gid_l, gid_n,
                                        W_fc, b_fc, W_out, b_out, (float*)d_out);
}

// Round 4
// 804.734 us; speedup vs baseline: 9.4368x; 1.2866x over previous
//
#include <hip/hip_runtime.h>
#include <math.h>

#define NL 50000
#define NN 50000
#define NE 600000
#define NG 64
#define DD 128
#define MPAD 50048      // 391*128, padded rows for bf16 h buffers
#define PSPLIT 8

typedef unsigned short u16;
typedef unsigned int u32;
using bf16x8 = __attribute__((ext_vector_type(8))) short;
using f32x4  = __attribute__((ext_vector_type(4))) float;

__device__ __forceinline__ u16 f2bf(float x) {
    u32 u = __float_as_uint(x);
    u32 r = (u + 0x7fffu + ((u >> 16) & 1u)) >> 16;
    return (u16)r;
}
__device__ __forceinline__ float bf2f(u16 x) {
    return __uint_as_float(((u32)x) << 16);
}
__device__ __forceinline__ void gload16(const void* g, void* l) {
    __builtin_amdgcn_global_load_lds((const __attribute__((address_space(1))) void*)g,
                                     (__attribute__((address_space(3))) void*)l, 16, 0, 0);
}

// ---------------- int degree histogram ----------------
__global__ void deg_kernel(const int* __restrict__ src, const int* __restrict__ dst,
                           int* __restrict__ dsrc, int* __restrict__ ddst, int E) {
    int e = blockIdx.x * blockDim.x + threadIdx.x;
    if (e < E) {
        atomicAdd(&dsrc[src[e]], 1);
        atomicAdd(&ddst[dst[e]], 1);
    }
}

__global__ void rsq_kernel(const int* __restrict__ cnt, float* __restrict__ out, int n) {
    int i = blockIdx.x * blockDim.x + threadIdx.x;
    if (i < n) out[i] = rsqrtf(fmaxf((float)cnt[i], 1.0f));
}

// ---------------- single-block exclusive scan ----------------
__global__ __launch_bounds__(1024) void scan_kernel(const int* __restrict__ cnt,
                                                    int* __restrict__ row_ptr, int n) {
    __shared__ int sm[1024];
    __shared__ int carry;
    if (threadIdx.x == 0) { carry = 0; row_ptr[0] = 0; }
    __syncthreads();
    for (int base = 0; base < n; base += 1024) {
        int i = base + threadIdx.x;
        int v = (i < n) ? cnt[i] : 0;
        sm[threadIdx.x] = v;
        __syncthreads();
        for (int off = 1; off < 1024; off <<= 1) {
            int t = (threadIdx.x >= off) ? sm[threadIdx.x - off] : 0;
            __syncthreads();
            sm[threadIdx.x] += t;
            __syncthreads();
        }
        if (i < n) row_ptr[i + 1] = carry + sm[threadIdx.x];
        __syncthreads();
        if (threadIdx.x == 0) carry += sm[1023];
        __syncthreads();
    }
}

// ---------------- CSR fill ----------------
__global__ void fill_csr(const int* __restrict__ src, const int* __restrict__ dst,
                         const int* __restrict__ row_ptr, int* __restrict__ cursor,
                         int* __restrict__ col, int E) {
    int e = blockIdx.x * blockDim.x + threadIdx.x;
    if (e < E) {
        int d = dst[e];
        int pos = atomicAdd(&cursor[d], 1);
        col[row_ptr[d] + pos] = src[e];
    }
}

// ---------------- W -> bf16, transposed [n][k], K zero-padded to KP ----------------
__global__ void conv_wt(const float* __restrict__ W, u16* __restrict__ Wt, int K, int KP) {
    int i = blockIdx.x * blockDim.x + threadIdx.x;
    if (i >= 128 * KP) return;
    int n = i / KP, k = i % KP;
    float v = (k < K) ? W[(size_t)k * 128 + n] : 0.0f;
    Wt[i] = f2bf(v);
}

// ---------------- MFMA GEMM: out[m][n] = rsq[m] * sum_k A[m][k]*W[k][n] ----------------
// BM=64, BN=128, 256 threads = 4 waves (2x2), 16x16x32 bf16 MFMA, BK=32.
// A: AF32 ? fp32 [50000][K] (guarded, cvt on stage) : bf16 [MPAD][KP] (global_load_lds)
// Wt: bf16 [128][KP] (transposed, zero-padded). LDS slot-swizzle: slot ^= (row&3).
template<int KP, bool AF32>
__global__ __launch_bounds__(256) void mfma_gemm(const void* __restrict__ Av, int K,
                                                 const u16* __restrict__ Wt,
                                                 const float* __restrict__ rsq,
                                                 float* __restrict__ out) {
    constexpr int NT = KP / 32;
    __shared__ __align__(16) u16 As[64 * 32];
    __shared__ __align__(16) u16 Bs[128 * 32];
    const int t    = threadIdx.x;
    const int lane = t & 63;
    const int wid  = t >> 6;
    const int wr   = wid >> 1;      // 0..1 row half
    const int wc   = wid & 1;       // 0..1 col half
    const int brow = blockIdx.x * 64;
    const int l15  = lane & 15;
    const int kg   = lane >> 4;     // 0..3

    f32x4 acc[2][4];
#pragma unroll
    for (int mi = 0; mi < 2; ++mi)
#pragma unroll
        for (int ni = 0; ni < 4; ++ni) acc[mi][ni] = (f32x4){0.f, 0.f, 0.f, 0.f};

    const int srow = t >> 2;        // 0..63 A-stage row
    const int sl   = t & 3;         // LDS slot it fills
    const int fo   = (kg ^ (l15 & 3)) * 8;   // swizzled frag k-offset (u16 units)

    for (int ks = 0; ks < NT; ++ks) {
        const int k0 = ks * 32;
        // ---- stage A tile 64x32 ----
        if constexpr (AF32) {
            const float* A = (const float*)Av;
            int grow = brow + srow;
            int kb = k0 + (sl ^ (srow & 3)) * 8;
            u32 pk[4];
#pragma unroll
            for (int p = 0; p < 4; ++p) {
                int ka = kb + 2 * p, kb2 = kb + 2 * p + 1;
                float v0 = (grow < NL && ka  < K) ? A[(size_t)grow * K + ka]  : 0.0f;
                float v1 = (grow < NL && kb2 < K) ? A[(size_t)grow * K + kb2] : 0.0f;
                pk[p] = (u32)f2bf(v0) | ((u32)f2bf(v1) << 16);
            }
            *(uint4*)&As[srow * 32 + sl * 8] = make_uint4(pk[0], pk[1], pk[2], pk[3]);
        } else {
            const u16* A = (const u16*)Av;
            const u16* src = A + (size_t)(brow + srow) * KP + k0 + (sl ^ (srow & 3)) * 8;
            void* dst = (void*)&As[(size_t)(t & ~63) * 8];   // wave-uniform base, lane*16B
            gload16(src, dst);
        }
        // ---- stage Wt tile 128x32 (2 rounds) ----
#pragma unroll
        for (int j = 0; j < 2; ++j) {
            int lidx = j * 256 + t;
            int n = lidx >> 2, bs = lidx & 3;
            const u16* src = Wt + (size_t)n * KP + k0 + (bs ^ (n & 3)) * 8;
            void* dst = (void*)&Bs[(size_t)(j * 256 + (t & ~63)) * 8];
            gload16(src, dst);
        }
        __syncthreads();

        bf16x8 a0 = *(const bf16x8*)&As[(wr * 32 +  0 + l15) * 32 + fo];
        bf16x8 a1 = *(const bf16x8*)&As[(wr * 32 + 16 + l15) * 32 + fo];
#pragma unroll
        for (int ni = 0; ni < 4; ++ni) {
            bf16x8 b = *(const bf16x8*)&Bs[(wc * 64 + ni * 16 + l15) * 32 + fo];
            acc[0][ni] = __builtin_amdgcn_mfma_f32_16x16x32_bf16(a0, b, acc[0][ni], 0, 0, 0);
            acc[1][ni] = __builtin_amdgcn_mfma_f32_16x16x32_bf16(a1, b, acc[1][ni], 0, 0, 0);
        }
        __syncthreads();
    }

    // ---- epilogue: D row = (lane>>4)*4 + reg, col = lane&15 (m89 layout) ----
#pragma unroll
    for (int mi = 0; mi < 2; ++mi) {
#pragma unroll
        for (int r = 0; r < 4; ++r) {
            int grow = brow + wr * 32 + mi * 16 + kg * 4 + r;
            if (grow < NL) {
                float s = rsq[grow];
#pragma unroll
                for (int ni = 0; ni < 4; ++ni) {
                    int gcol = wc * 64 + ni * 16 + l15;
                    out[(size_t)grow * 128 + gcol] = acc[mi][ni][r] * s;
                }
            }
        }
    }
}

// ---------------- fused gather + finalize -> bf16 h ----------------
__global__ __launch_bounds__(256) void gather_finalize(const float* __restrict__ xs,
                                                       const int* __restrict__ row_ptr,
                                                       const int* __restrict__ col,
                                                       const float* __restrict__ rsq_in,
                                                       const float* __restrict__ bias,
                                                       const float* __restrict__ g,
                                                       const float* __restrict__ bln,
                                                       u16* __restrict__ out, int M) {
    int row  = blockIdx.x * 4 + (threadIdx.x >> 6);
    int lane = threadIdx.x & 63;
    if (row >= M) return;
    int beg = row_ptr[row], end = row_ptr[row + 1];

    float a0 = 0.0f, a1 = 0.0f;
    int e = beg;
    for (; e + 1 < end; e += 2) {
        int s0 = col[e], s1 = col[e + 1];
        float2 v0 = *(const float2*)&xs[(size_t)s0 * 128 + lane * 2];
        float2 v1 = *(const float2*)&xs[(size_t)s1 * 128 + lane * 2];
        a0 += v0.x + v1.x;
        a1 += v0.y + v1.y;
    }
    if (e < end) {
        int s = col[e];
        float2 v = *(const float2*)&xs[(size_t)s * 128 + lane * 2];
        a0 += v.x;
        a1 += v.y;
    }

    float sc = rsq_in[row];
    float2 bv = *(const float2*)&bias[lane * 2];
    float x0 = a0 * sc + bv.x;
    float x1 = a1 * sc + bv.y;

    float sum = x0 + x1;
#pragma unroll
    for (int m = 1; m < 64; m <<= 1) sum += __shfl_xor(sum, m, 64);
    float mu = sum * (1.0f / 128.0f);

    float d0 = x0 - mu, d1 = x1 - mu;
    float ss = d0 * d0 + d1 * d1;
#pragma unroll
    for (int m = 1; m < 64; m <<= 1) ss += __shfl_xor(ss, m, 64);
    float rstd = rsqrtf(ss * (1.0f / 128.0f) + 1e-5f);

    float2 gv = *(const float2*)&g[lane * 2];
    float2 bl = *(const float2*)&bln[lane * 2];
    float y0 = d0 * rstd * gv.x + bl.x;
    float y1 = d1 * rstd * gv.y + bl.y;
    y0 = (y0 > 0.0f) ? y0 : expm1f(y0);
    y1 = (y1 > 0.0f) ? y1 : expm1f(y1);
    ((u32*)out)[(size_t)row * 64 + lane] = (u32)f2bf(y0) | ((u32)f2bf(y1) << 16);
}

// ---------------- segmented pooling from bf16 h ----------------
__global__ __launch_bounds__(128) void pool_partial(const u16* __restrict__ h,
                                                    const int* __restrict__ gid,
                                                    float* __restrict__ partial, int M) {
    int g = blockIdx.x / PSPLIT;
    int p = blockIdx.x % PSPLIT;
    int j = threadIdx.x;
    __shared__ int bounds[2];
    if (j < 2) {
        int target = g + j;
        int lo = 0, hi = M;
        while (lo < hi) { int mid = (lo + hi) >> 1; if (gid[mid] < target) lo = mid + 1; else hi = mid; }
        bounds[j] = lo;
    }
    __syncthreads();
    int beg = bounds[0], end = bounds[1];
    int len = end - beg;
    int chunk = (len + PSPLIT - 1) / PSPLIT;
    int s0i = beg + p * chunk;
    int e0i = min(s0i + chunk, end);

    float s0 = 0.0f, s1 = 0.0f, s2 = 0.0f, s3 = 0.0f;
    int i = s0i;
    for (; i + 3 < e0i; i += 4) {
        s0 += bf2f(h[(size_t)(i + 0) * 128 + j]);
        s1 += bf2f(h[(size_t)(i + 1) * 128 + j]);
        s2 += bf2f(h[(size_t)(i + 2) * 128 + j]);
        s3 += bf2f(h[(size_t)(i + 3) * 128 + j]);
    }
    for (; i < e0i; ++i) s0 += bf2f(h[(size_t)i * 128 + j]);
    partial[(size_t)(g * PSPLIT + p) * 128 + j] = (s0 + s1) + (s2 + s3);
}

// ---------------- head ----------------
__global__ __launch_bounds__(128) void head_kernel(const float* __restrict__ part_l,
                                                   const float* __restrict__ part_n,
                                                   const int* __restrict__ gid_l,
                                                   const int* __restrict__ gid_n,
                                                   const float* __restrict__ W_fc,
                                                   const float* __restrict__ b_fc,
                                                   const float* __restrict__ W_out,
                                                   const float* __restrict__ b_out,
                                                   float* __restrict__ out) {
    int g = blockIdx.x;
    int j = threadIdx.x;
    __shared__ float hg[128];
    __shared__ float red[2];
    __shared__ int bounds[4];
    if (j < 4) {
        const int* gid = (j < 2) ? gid_l : gid_n;
        int target = g + (j & 1);
        int lo = 0, hi = 50000;
        while (lo < hi) { int mid = (lo + hi) >> 1; if (gid[mid] < target) lo = mid + 1; else hi = mid; }
        bounds[j] = lo;
    }
    __syncthreads();
    float cl = fmaxf((float)(bounds[1] - bounds[0]), 1.0f);
    float cn = fmaxf((float)(bounds[3] - bounds[2]), 1.0f);
    float sl = 0.0f, sn = 0.0f;
#pragma unroll
    for (int p = 0; p < PSPLIT; ++p) {
        sl += part_l[(size_t)(g * PSPLIT + p) * 128 + j];
        sn += part_n[(size_t)(g * PSPLIT + p) * 128 + j];
    }
    hg[j] = sl / cl + sn / cn;
    __syncthreads();
    float acc = b_fc[j];
#pragma unroll 8
    for (int k = 0; k < 128; ++k) acc = fmaf(hg[k], W_fc[k * 128 + j], acc);
    float fc = fmaxf(acc, 0.0f);
    float v = fc * W_out[j];
#pragma unroll
    for (int m = 1; m < 64; m <<= 1) v += __shfl_xor(v, m, 64);
    if ((j & 63) == 0) red[j >> 6] = v;
    __syncthreads();
    if (j == 0) out[g] = red[0] + red[1] + b_out[0];
}

static inline size_t align_up(size_t x, size_t a) { return (x + a - 1) & ~(a - 1); }

extern "C" void kernel_launch(void* const* d_in, const int* in_sizes, int n_in,
                              void* d_out, int out_size, void* d_ws, size_t ws_size,
                              hipStream_t stream) {
    const float* feat_l = (const float*)d_in[0];
    const float* feat_n = (const float*)d_in[1];
    const float* W0_l2n = (const float*)d_in[2];
    const float* b0_l2n = (const float*)d_in[3];
    const float* W0_n2l = (const float*)d_in[4];
    const float* b0_n2l = (const float*)d_in[5];
    const float* W_l2n  = (const float*)d_in[6];
    const float* b_l2n  = (const float*)d_in[7];
    const float* W_n2l  = (const float*)d_in[8];
    const float* b_n2l  = (const float*)d_in[9];
    const float* ln_g_n = (const float*)d_in[10];
    const float* ln_b_n = (const float*)d_in[11];
    const float* ln_g_l = (const float*)d_in[12];
    const float* ln_b_l = (const float*)d_in[13];
    const float* W_fc   = (const float*)d_in[14];
    const float* b_fc   = (const float*)d_in[15];
    const float* W_out  = (const float*)d_in[16];
    const float* b_out  = (const float*)d_in[17];
    const int* src_l2n  = (const int*)d_in[18];
    const int* dst_l2n  = (const int*)d_in[19];
    const int* src_n2l  = (const int*)d_in[20];
    const int* dst_n2l  = (const int*)d_in[21];
    const int* gid_l    = (const int*)d_in[22];
    const int* gid_n    = (const int*)d_in[23];

    // ---- workspace layout (bytes, 256-aligned sections) ----
    char* ws = (char*)d_ws;
    size_t off = 0;
    auto take = [&](size_t bytes) { char* p = ws + off; off = align_up(off + bytes, 256); return p; };
    int*   icnt        = (int*)take(200000 * 4);
    float* rsq         = (float*)take(200000 * 4);
    int*   row_ptr_l2n = (int*)take((NN + 1) * 4);
    int*   row_ptr_n2l = (int*)take((NL + 1) * 4);
    int*   cursor      = (int*)take(50000 * 4);
    int*   col_l2n     = (int*)take((size_t)NE * 4);
    int*   col_n2l     = (int*)take((size_t)NE * 4);
    u16*   Wt0_l2n     = (u16*)take(128 * 320 * 2);
    u16*   Wt0_n2l     = (u16*)take(128 * 224 * 2);
    u16*   Wt_l2n0     = (u16*)take(128 * 128 * 2);
    u16*   Wt_l2n1     = (u16*)take(128 * 128 * 2);
    u16*   Wt_n2l0     = (u16*)take(128 * 128 * 2);
    u16*   Wt_n2l1     = (u16*)take(128 * 128 * 2);
    float* xs0         = (float*)take((size_t)NL * 128 * 4);
    float* xs1         = (float*)take((size_t)NL * 128 * 4);
    u16*   hl          = (u16*)take((size_t)MPAD * 128 * 2);
    u16*   hn          = (u16*)take((size_t)MPAD * 128 * 2);
    float* part_l      = (float*)take((size_t)NG * PSPLIT * 128 * 4);
    float* part_n      = (float*)take((size_t)NG * PSPLIT * 128 * 4);

    int* icnt_src_l2n = icnt;
    int* icnt_dst_l2n = icnt + NL;
    int* icnt_src_n2l = icnt + NL + NN;
    int* icnt_dst_n2l = icnt + NL + 2 * NN;
    float* rsq_src_l2n = rsq;
    float* rsq_dst_l2n = rsq + NL;
    float* rsq_src_n2l = rsq + NL + NN;
    float* rsq_dst_n2l = rsq + NL + 2 * NN;

    const int TB = 256;
    const int gemm_grid = (NL + 63) / 64;       // 782
    const int gath_grid = (NL + 3) / 4;
    const int edge_grid = (NE + TB - 1) / TB;

    // ---- degrees + CSR build ----
    hipMemsetAsync(icnt, 0, 200000 * sizeof(int), stream);
    deg_kernel<<<edge_grid, TB, 0, stream>>>(src_l2n, dst_l2n, icnt_src_l2n, icnt_dst_l2n, NE);
    deg_kernel<<<edge_grid, TB, 0, stream>>>(src_n2l, dst_n2l, icnt_src_n2l, icnt_dst_n2l, NE);
    rsq_kernel<<<(200000 + TB - 1) / TB, TB, 0, stream>>>(icnt, rsq, 200000);

    scan_kernel<<<1, 1024, 0, stream>>>(icnt_dst_l2n, row_ptr_l2n, NN);
    hipMemsetAsync(cursor, 0, 50000 * sizeof(int), stream);
    fill_csr<<<edge_grid, TB, 0, stream>>>(src_l2n, dst_l2n, row_ptr_l2n, cursor, col_l2n, NE);

    scan_kernel<<<1, 1024, 0, stream>>>(icnt_dst_n2l, row_ptr_n2l, NL);
    hipMemsetAsync(cursor, 0, 50000 * sizeof(int), stream);
    fill_csr<<<edge_grid, TB, 0, stream>>>(src_n2l, dst_n2l, row_ptr_n2l, cursor, col_n2l, NE);

    // ---- weight conversion (bf16, transposed, K-padded) ----
    conv_wt<<<(128 * 320 + TB - 1) / TB, TB, 0, stream>>>(W0_l2n, Wt0_l2n, 300, 320);
    conv_wt<<<(128 * 224 + TB - 1) / TB, TB, 0, stream>>>(W0_n2l, Wt0_n2l, 200, 224);
    conv_wt<<<(128 * 128 + TB - 1) / TB, TB, 0, stream>>>(W_l2n,                 Wt_l2n0, 128, 128);
    conv_wt<<<(128 * 128 + TB - 1) / TB, TB, 0, stream>>>(W_l2n + 128 * 128,     Wt_l2n1, 128, 128);
    conv_wt<<<(128 * 128 + TB - 1) / TB, TB, 0, stream>>>(W_n2l,                 Wt_n2l0, 128, 128);
    conv_wt<<<(128 * 128 + TB - 1) / TB, TB, 0, stream>>>(W_n2l + 128 * 128,     Wt_n2l1, 128, 128);

    // ---- layer 0 ----
    mfma_gemm<320, true><<<gemm_grid, TB, 0, stream>>>(feat_l, 300, Wt0_l2n, rsq_src_l2n, xs0);
    mfma_gemm<224, true><<<gemm_grid, TB, 0, stream>>>(feat_n, 200, Wt0_n2l, rsq_src_n2l, xs1);
    gather_finalize<<<gath_grid, TB, 0, stream>>>(xs0, row_ptr_l2n, col_l2n, rsq_dst_l2n,
                                                  b0_l2n, ln_g_n, ln_b_n, hn, NN);
    gather_finalize<<<gath_grid, TB, 0, stream>>>(xs1, row_ptr_n2l, col_n2l, rsq_dst_n2l,
                                                  b0_n2l, ln_g_l, ln_b_l, hl, NL);

    // ---- layers 1,2 (K=128, bf16 A via global_load_lds) ----
    const u16* Wls[2] = {Wt_l2n0, Wt_l2n1};
    const u16* Wns[2] = {Wt_n2l0, Wt_n2l1};
    for (int i = 1; i <= 2; ++i) {
        const float* bl = b_l2n + (size_t)(i - 1) * DD;
        const float* bn = b_n2l + (size_t)(i - 1) * DD;
        mfma_gemm<128, false><<<gemm_grid, TB, 0, stream>>>(hl, 128, Wls[i - 1], rsq_src_l2n, xs0);
        mfma_gemm<128, false><<<gemm_grid, TB, 0, stream>>>(hn, 128, Wns[i - 1], rsq_src_n2l, xs1);
        gather_finalize<<<gath_grid, TB, 0, stream>>>(xs0, row_ptr_l2n, col_l2n, rsq_dst_l2n,
                                                      bl, ln_g_n + (size_t)i * DD,
                                                      ln_b_n + (size_t)i * DD, hn, NN);
        gather_finalize<<<gath_grid, TB, 0, stream>>>(xs1, row_ptr_n2l, col_n2l, rsq_dst_n2l,
                                                      bn, ln_g_l + (size_t)i * DD,
                                                      ln_b_l + (size_t)i * DD, hl, NL);
    }

    // ---- pooling + head ----
    pool_partial<<<NG * PSPLIT, 128, 0, stream>>>(hl, gid_l, part_l, NL);
    pool_partial<<<NG * PSPLIT, 128, 0, stream>>>(hn, gid_n, part_n, NN);
    head_kernel<<<NG, 128, 0, stream>>>(part_l, part_n, gid_l, gid_n,
                                        W_fc, b_fc, W_out, b_out, (float*)d_out);
}

// Round 5
// 641.087 us; speedup vs baseline: 11.8456x; 1.2553x over previous
//
#include <hip/hip_runtime.h>
#include <math.h>

#define NL 50000
#define NN 50000
#define NE 600000
#define NG 64
#define DD 128
#define PSPLIT 8

typedef unsigned short u16;
typedef unsigned int u32;
using bf16x8 = __attribute__((ext_vector_type(8))) short;
using f32x4  = __attribute__((ext_vector_type(4))) float;

__device__ __forceinline__ u16 f2bf(float x) {
    u32 u = __float_as_uint(x);
    u32 r = (u + 0x7fffu + ((u >> 16) & 1u)) >> 16;
    return (u16)r;
}
__device__ __forceinline__ float bf2f(u16 x) {
    return __uint_as_float(((u32)x) << 16);
}
__device__ __forceinline__ void gload16(const void* g, void* l) {
    __builtin_amdgcn_global_load_lds((const __attribute__((address_space(1))) void*)g,
                                     (__attribute__((address_space(3))) void*)l, 16, 0, 0);
}

// ---------------- int degree histogram ----------------
__global__ void deg_kernel(const int* __restrict__ src, const int* __restrict__ dst,
                           int* __restrict__ dsrc, int* __restrict__ ddst, int E) {
    int e = blockIdx.x * blockDim.x + threadIdx.x;
    if (e < E) {
        atomicAdd(&dsrc[src[e]], 1);
        atomicAdd(&ddst[dst[e]], 1);
    }
}

__global__ void rsq_kernel(const int* __restrict__ cnt, float* __restrict__ out, int n) {
    int i = blockIdx.x * blockDim.x + threadIdx.x;
    if (i < n) out[i] = rsqrtf(fmaxf((float)cnt[i], 1.0f));
}

// ---------------- segment allocation: beg[i] = bump-alloc of cnt[i] (order-free CSR) ------
// blocks 0..nblkA-1 -> graph A, rest -> graph B. One atomic per block.
__global__ __launch_bounds__(256) void alloc_beg(const int* __restrict__ cntA, int* __restrict__ begA, int nA,
                                                 const int* __restrict__ cntB, int* __restrict__ begB, int nB,
                                                 int* __restrict__ ctrs) {
    int nblkA = (nA + 255) >> 8;
    const int* cnt; int* beg; int* ctr; int base_i; int n;
    if ((int)blockIdx.x < nblkA) { cnt = cntA; beg = begA; ctr = ctrs;     base_i = blockIdx.x * 256;           n = nA; }
    else                         { cnt = cntB; beg = begB; ctr = ctrs + 1; base_i = (blockIdx.x - nblkA) * 256; n = nB; }
    int i = base_i + threadIdx.x;
    int v = (i < n) ? cnt[i] : 0;
    __shared__ int sm[256];
    __shared__ int sbase;
    sm[threadIdx.x] = v;
    __syncthreads();
    for (int off = 1; off < 256; off <<= 1) {
        int t = (threadIdx.x >= (unsigned)off) ? sm[threadIdx.x - off] : 0;
        __syncthreads();
        sm[threadIdx.x] += t;
        __syncthreads();
    }
    if (threadIdx.x == 255) sbase = atomicAdd(ctr, sm[255]);
    __syncthreads();
    if (i < n) beg[i] = sbase + sm[threadIdx.x] - v;
}

// ---------------- CSR fill ----------------
__global__ void fill_csr(const int* __restrict__ src, const int* __restrict__ dst,
                         const int* __restrict__ beg, int* __restrict__ cursor,
                         int* __restrict__ col, int E) {
    int e = blockIdx.x * blockDim.x + threadIdx.x;
    if (e < E) {
        int d = dst[e];
        int pos = atomicAdd(&cursor[d], 1);
        col[beg[d] + pos] = src[e];
    }
}

// ---------------- W -> bf16, transposed [n][k], K zero-padded to KP ----------------
__global__ void conv_wt(const float* __restrict__ W, u16* __restrict__ Wt, int K, int KP) {
    int i = blockIdx.x * blockDim.x + threadIdx.x;
    if (i >= 128 * KP) return;
    int n = i / KP, k = i % KP;
    float v = (k < K) ? W[(size_t)k * 128 + n] : 0.0f;
    Wt[i] = f2bf(v);
}

// ---------------- MFMA GEMM, optional fused bias+LN+ELU epilogue ----------------
// BM=64, BN=128, 4 waves (2x2), 16x16x32 bf16 MFMA, BK=32.
// A is fp32 (guarded reg-stage with cvt). Wt bf16 [128][KP]. slot-swizzle slot^(row&3).
// LN=false: outF[m][n] = rsq[m]*acc.   LN=true: outH = elu(ln(rsq[m]*acc + bias)) bf16.
template<int KP, bool LN>
__global__ __launch_bounds__(256) void mfma_gemm(const float* __restrict__ A, int K,
                                                 const u16* __restrict__ Wt,
                                                 const float* __restrict__ rsq,
                                                 const float* __restrict__ bias,
                                                 const float* __restrict__ g,
                                                 const float* __restrict__ bln,
                                                 float* __restrict__ outF,
                                                 u16* __restrict__ outH) {
    constexpr int NT = KP / 32;
    __shared__ __align__(16) u16 As[64 * 32];
    __shared__ __align__(16) u16 Bs[128 * 32];
    const int t    = threadIdx.x;
    const int lane = t & 63;
    const int wid  = t >> 6;
    const int wr   = wid >> 1;
    const int wc   = wid & 1;
    const int brow = blockIdx.x * 64;
    const int l15  = lane & 15;
    const int kg   = lane >> 4;

    f32x4 acc[2][4];
#pragma unroll
    for (int mi = 0; mi < 2; ++mi)
#pragma unroll
        for (int ni = 0; ni < 4; ++ni) acc[mi][ni] = (f32x4){0.f, 0.f, 0.f, 0.f};

    const int srow = t >> 2;
    const int sl   = t & 3;
    const int fo   = (kg ^ (l15 & 3)) * 8;

    for (int ks = 0; ks < NT; ++ks) {
        const int k0 = ks * 32;
        // stage A tile 64x32 (fp32 -> bf16)
        {
            int grow = brow + srow;
            int kb = k0 + (sl ^ (srow & 3)) * 8;
            u32 pk[4];
#pragma unroll
            for (int p = 0; p < 4; ++p) {
                int ka = kb + 2 * p, kb2 = kb + 2 * p + 1;
                float v0 = (grow < NL && ka  < K) ? A[(size_t)grow * K + ka]  : 0.0f;
                float v1 = (grow < NL && kb2 < K) ? A[(size_t)grow * K + kb2] : 0.0f;
                pk[p] = (u32)f2bf(v0) | ((u32)f2bf(v1) << 16);
            }
            *(uint4*)&As[srow * 32 + sl * 8] = make_uint4(pk[0], pk[1], pk[2], pk[3]);
        }
        // stage Wt tile 128x32 (global_load_lds, 2 rounds)
#pragma unroll
        for (int j = 0; j < 2; ++j) {
            int lidx = j * 256 + t;
            int n = lidx >> 2, bs = lidx & 3;
            const u16* src = Wt + (size_t)n * KP + k0 + (bs ^ (n & 3)) * 8;
            void* dst = (void*)&Bs[(size_t)(j * 256 + (t & ~63)) * 8];
            gload16(src, dst);
        }
        __syncthreads();

        bf16x8 a0 = *(const bf16x8*)&As[(wr * 32 +  0 + l15) * 32 + fo];
        bf16x8 a1 = *(const bf16x8*)&As[(wr * 32 + 16 + l15) * 32 + fo];
#pragma unroll
        for (int ni = 0; ni < 4; ++ni) {
            bf16x8 b = *(const bf16x8*)&Bs[(wc * 64 + ni * 16 + l15) * 32 + fo];
            acc[0][ni] = __builtin_amdgcn_mfma_f32_16x16x32_bf16(a0, b, acc[0][ni], 0, 0, 0);
            acc[1][ni] = __builtin_amdgcn_mfma_f32_16x16x32_bf16(a1, b, acc[1][ni], 0, 0, 0);
        }
        __syncthreads();
    }

    if constexpr (!LN) {
        // D layout: row = kg*4 + r, col = l15 (m89)
#pragma unroll
        for (int mi = 0; mi < 2; ++mi)
#pragma unroll
            for (int r = 0; r < 4; ++r) {
                int grow = brow + wr * 32 + mi * 16 + kg * 4 + r;
                if (grow < NL) {
                    float s = rsq[grow];
#pragma unroll
                    for (int ni = 0; ni < 4; ++ni)
                        outF[(size_t)grow * 128 + wc * 64 + ni * 16 + l15] = acc[mi][ni][r] * s;
                }
            }
    } else {
        __shared__ float rs[2][64][2];   // [sum|sumsq][row][wc]
        float b4[4], g4[4], bl4[4];
#pragma unroll
        for (int ni = 0; ni < 4; ++ni) {
            int c = wc * 64 + ni * 16 + l15;
            b4[ni] = bias[c]; g4[ni] = g[c]; bl4[ni] = bln[c];
        }
        float rsv[2][4];
#pragma unroll
        for (int mi = 0; mi < 2; ++mi)
#pragma unroll
            for (int r = 0; r < 4; ++r) {
                int grow = brow + wr * 32 + mi * 16 + kg * 4 + r;
                rsv[mi][r] = (grow < NL) ? rsq[grow] : 0.0f;
            }
#pragma unroll
        for (int mi = 0; mi < 2; ++mi)
#pragma unroll
            for (int r = 0; r < 4; ++r) {
                int lrow = wr * 32 + mi * 16 + kg * 4 + r;
                float s1 = 0.f, s2 = 0.f;
#pragma unroll
                for (int ni = 0; ni < 4; ++ni) {
                    float xv = acc[mi][ni][r] * rsv[mi][r] + b4[ni];
                    s1 += xv; s2 += xv * xv;
                }
#pragma unroll
                for (int m = 1; m < 16; m <<= 1) {
                    s1 += __shfl_xor(s1, m, 64);
                    s2 += __shfl_xor(s2, m, 64);
                }
                if (l15 == 0) { rs[0][lrow][wc] = s1; rs[1][lrow][wc] = s2; }
            }
        __syncthreads();
#pragma unroll
        for (int mi = 0; mi < 2; ++mi)
#pragma unroll
            for (int r = 0; r < 4; ++r) {
                int lrow = wr * 32 + mi * 16 + kg * 4 + r;
                int grow = brow + lrow;
                if (grow < NL) {
                    float S1 = rs[0][lrow][0] + rs[0][lrow][1];
                    float S2 = rs[1][lrow][0] + rs[1][lrow][1];
                    float mu = S1 * (1.0f / 128.0f);
                    float var = S2 * (1.0f / 128.0f) - mu * mu;
                    float rstd = rsqrtf(fmaxf(var, 0.0f) + 1e-5f);
#pragma unroll
                    for (int ni = 0; ni < 4; ++ni) {
                        float xv = acc[mi][ni][r] * rsv[mi][r] + b4[ni];
                        float y = (xv - mu) * rstd * g4[ni] + bl4[ni];
                        y = (y > 0.0f) ? y : expm1f(y);
                        outH[(size_t)grow * 128 + wc * 64 + ni * 16 + l15] = f2bf(y);
                    }
                }
            }
    }
}

// ---------------- layer0 gather + finalize (fp32 xs in, bf16 h out) ----------------
__global__ __launch_bounds__(256) void gather_finalize(const float* __restrict__ xs,
                                                       const int* __restrict__ beg,
                                                       const int* __restrict__ cnt,
                                                       const int* __restrict__ col,
                                                       const float* __restrict__ rsq_in,
                                                       const float* __restrict__ bias,
                                                       const float* __restrict__ g,
                                                       const float* __restrict__ bln,
                                                       u16* __restrict__ out, int M) {
    int row  = blockIdx.x * 4 + (threadIdx.x >> 6);
    int lane = threadIdx.x & 63;
    if (row >= M) return;
    int b = beg[row], n = cnt[row];

    float a0 = 0.0f, a1 = 0.0f;
    int e = 0;
    for (; e + 1 < n; e += 2) {
        int s0 = col[b + e], s1 = col[b + e + 1];
        float2 v0 = *(const float2*)&xs[(size_t)s0 * 128 + lane * 2];
        float2 v1 = *(const float2*)&xs[(size_t)s1 * 128 + lane * 2];
        a0 += v0.x + v1.x;
        a1 += v0.y + v1.y;
    }
    if (e < n) {
        int s = col[b + e];
        float2 v = *(const float2*)&xs[(size_t)s * 128 + lane * 2];
        a0 += v.x;
        a1 += v.y;
    }

    float sc = rsq_in[row];
    float2 bv = *(const float2*)&bias[lane * 2];
    float x0 = a0 * sc + bv.x;
    float x1 = a1 * sc + bv.y;

    float sum = x0 + x1;
#pragma unroll
    for (int m = 1; m < 64; m <<= 1) sum += __shfl_xor(sum, m, 64);
    float mu = sum * (1.0f / 128.0f);

    float d0 = x0 - mu, d1 = x1 - mu;
    float ss = d0 * d0 + d1 * d1;
#pragma unroll
    for (int m = 1; m < 64; m <<= 1) ss += __shfl_xor(ss, m, 64);
    float rstd = rsqrtf(ss * (1.0f / 128.0f) + 1e-5f);

    float2 gv = *(const float2*)&g[lane * 2];
    float2 bl = *(const float2*)&bln[lane * 2];
    float y0 = d0 * rstd * gv.x + bl.x;
    float y1 = d1 * rstd * gv.y + bl.y;
    y0 = (y0 > 0.0f) ? y0 : expm1f(y0);
    y1 = (y1 > 0.0f) ? y1 : expm1f(y1);
    ((u32*)out)[(size_t)row * 64 + lane] = (u32)f2bf(y0) | ((u32)f2bf(y1) << 16);
}

// ---------------- layers 1-2 gather: agg[dst] = sum rsq_src[s]*h[s] (bf16 in, fp32 out) ----
__global__ __launch_bounds__(256) void gather_scale(const u16* __restrict__ h,
                                                    const int* __restrict__ beg,
                                                    const int* __restrict__ cnt,
                                                    const int* __restrict__ col,
                                                    const float* __restrict__ rsq_src,
                                                    float* __restrict__ agg, int M) {
    int row  = blockIdx.x * 4 + (threadIdx.x >> 6);
    int lane = threadIdx.x & 63;
    if (row >= M) return;
    int b = beg[row], n = cnt[row];
    const u32* h32 = (const u32*)h;

    float a0 = 0.0f, a1 = 0.0f;
    int e = 0;
    for (; e + 1 < n; e += 2) {
        int s0 = col[b + e], s1 = col[b + e + 1];
        float r0 = rsq_src[s0], r1 = rsq_src[s1];
        u32 p0 = h32[(size_t)s0 * 64 + lane];
        u32 p1 = h32[(size_t)s1 * 64 + lane];
        a0 = fmaf(r0, bf2f((u16)p0), a0);
        a1 = fmaf(r0, bf2f((u16)(p0 >> 16)), a1);
        a0 = fmaf(r1, bf2f((u16)p1), a0);
        a1 = fmaf(r1, bf2f((u16)(p1 >> 16)), a1);
    }
    if (e < n) {
        int s = col[b + e];
        float r = rsq_src[s];
        u32 p = h32[(size_t)s * 64 + lane];
        a0 = fmaf(r, bf2f((u16)p), a0);
        a1 = fmaf(r, bf2f((u16)(p >> 16)), a1);
    }
    *(float2*)&agg[(size_t)row * 128 + lane * 2] = make_float2(a0, a1);
}

// ---------------- segmented pooling from bf16 h ----------------
__global__ __launch_bounds__(128) void pool_partial(const u16* __restrict__ h,
                                                    const int* __restrict__ gid,
                                                    float* __restrict__ partial, int M) {
    int g = blockIdx.x / PSPLIT;
    int p = blockIdx.x % PSPLIT;
    int j = threadIdx.x;
    __shared__ int bounds[2];
    if (j < 2) {
        int target = g + j;
        int lo = 0, hi = M;
        while (lo < hi) { int mid = (lo + hi) >> 1; if (gid[mid] < target) lo = mid + 1; else hi = mid; }
        bounds[j] = lo;
    }
    __syncthreads();
    int beg = bounds[0], end = bounds[1];
    int len = end - beg;
    int chunk = (len + PSPLIT - 1) / PSPLIT;
    int s0i = beg + p * chunk;
    int e0i = min(s0i + chunk, end);

    float s0 = 0.0f, s1 = 0.0f, s2 = 0.0f, s3 = 0.0f;
    int i = s0i;
    for (; i + 3 < e0i; i += 4) {
        s0 += bf2f(h[(size_t)(i + 0) * 128 + j]);
        s1 += bf2f(h[(size_t)(i + 1) * 128 + j]);
        s2 += bf2f(h[(size_t)(i + 2) * 128 + j]);
        s3 += bf2f(h[(size_t)(i + 3) * 128 + j]);
    }
    for (; i < e0i; ++i) s0 += bf2f(h[(size_t)i * 128 + j]);
    partial[(size_t)(g * PSPLIT + p) * 128 + j] = (s0 + s1) + (s2 + s3);
}

// ---------------- head ----------------
__global__ __launch_bounds__(128) void head_kernel(const float* __restrict__ part_l,
                                                   const float* __restrict__ part_n,
                                                   const int* __restrict__ gid_l,
                                                   const int* __restrict__ gid_n,
                                                   const float* __restrict__ W_fc,
                                                   const float* __restrict__ b_fc,
                                                   const float* __restrict__ W_out,
                                                   const float* __restrict__ b_out,
                                                   float* __restrict__ out) {
    int g = blockIdx.x;
    int j = threadIdx.x;
    __shared__ float hg[128];
    __shared__ float red[2];
    __shared__ int bounds[4];
    if (j < 4) {
        const int* gid = (j < 2) ? gid_l : gid_n;
        int target = g + (j & 1);
        int lo = 0, hi = 50000;
        while (lo < hi) { int mid = (lo + hi) >> 1; if (gid[mid] < target) lo = mid + 1; else hi = mid; }
        bounds[j] = lo;
    }
    __syncthreads();
    float cl = fmaxf((float)(bounds[1] - bounds[0]), 1.0f);
    float cn = fmaxf((float)(bounds[3] - bounds[2]), 1.0f);
    float sl = 0.0f, sn = 0.0f;
#pragma unroll
    for (int p = 0; p < PSPLIT; ++p) {
        sl += part_l[(size_t)(g * PSPLIT + p) * 128 + j];
        sn += part_n[(size_t)(g * PSPLIT + p) * 128 + j];
    }
    hg[j] = sl / cl + sn / cn;
    __syncthreads();
    float acc = b_fc[j];
#pragma unroll 8
    for (int k = 0; k < 128; ++k) acc = fmaf(hg[k], W_fc[k * 128 + j], acc);
    float fc = fmaxf(acc, 0.0f);
    float v = fc * W_out[j];
#pragma unroll
    for (int m = 1; m < 64; m <<= 1) v += __shfl_xor(v, m, 64);
    if ((j & 63) == 0) red[j >> 6] = v;
    __syncthreads();
    if (j == 0) out[g] = red[0] + red[1] + b_out[0];
}

static inline size_t align_up(size_t x, size_t a) { return (x + a - 1) & ~(a - 1); }

extern "C" void kernel_launch(void* const* d_in, const int* in_sizes, int n_in,
                              void* d_out, int out_size, void* d_ws, size_t ws_size,
                              hipStream_t stream) {
    const float* feat_l = (const float*)d_in[0];
    const float* feat_n = (const float*)d_in[1];
    const float* W0_l2n = (const float*)d_in[2];
    const float* b0_l2n = (const float*)d_in[3];
    const float* W0_n2l = (const float*)d_in[4];
    const float* b0_n2l = (const float*)d_in[5];
    const float* W_l2n  = (const float*)d_in[6];
    const float* b_l2n  = (const float*)d_in[7];
    const float* W_n2l  = (const float*)d_in[8];
    const float* b_n2l  = (const float*)d_in[9];
    const float* ln_g_n = (const float*)d_in[10];
    const float* ln_b_n = (const float*)d_in[11];
    const float* ln_g_l = (const float*)d_in[12];
    const float* ln_b_l = (const float*)d_in[13];
    const float* W_fc   = (const float*)d_in[14];
    const float* b_fc   = (const float*)d_in[15];
    const float* W_out  = (const float*)d_in[16];
    const float* b_out  = (const float*)d_in[17];
    const int* src_l2n  = (const int*)d_in[18];
    const int* dst_l2n  = (const int*)d_in[19];
    const int* src_n2l  = (const int*)d_in[20];
    const int* dst_n2l  = (const int*)d_in[21];
    const int* gid_l    = (const int*)d_in[22];
    const int* gid_n    = (const int*)d_in[23];

    // ---- workspace layout ----
    char* ws = (char*)d_ws;
    size_t off = 0;
    auto take = [&](size_t bytes) { char* p = ws + off; off = align_up(off + bytes, 256); return p; };
    int*   icnt        = (int*)take(200000 * 4);
    float* rsq         = (float*)take(200000 * 4);
    int*   beg_l2n     = (int*)take(NN * 4);
    int*   beg_n2l     = (int*)take(NL * 4);
    int*   cursor      = (int*)take(50002 * 4);   // +2 ctrs at [50000],[50001]
    int*   col_l2n     = (int*)take((size_t)NE * 4);
    int*   col_n2l     = (int*)take((size_t)NE * 4);
    u16*   Wt0_l2n     = (u16*)take(128 * 320 * 2);
    u16*   Wt0_n2l     = (u16*)take(128 * 224 * 2);
    u16*   Wt_l2n0     = (u16*)take(128 * 128 * 2);
    u16*   Wt_l2n1     = (u16*)take(128 * 128 * 2);
    u16*   Wt_n2l0     = (u16*)take(128 * 128 * 2);
    u16*   Wt_n2l1     = (u16*)take(128 * 128 * 2);
    float* xs0         = (float*)take((size_t)NL * 128 * 4);
    float* xs1         = (float*)take((size_t)NL * 128 * 4);
    u16*   hl          = (u16*)take((size_t)NL * 128 * 2);
    u16*   hn          = (u16*)take((size_t)NN * 128 * 2);
    float* part_l      = (float*)take((size_t)NG * PSPLIT * 128 * 4);
    float* part_n      = (float*)take((size_t)NG * PSPLIT * 128 * 4);

    int* icnt_src_l2n = icnt;
    int* icnt_dst_l2n = icnt + NL;
    int* icnt_src_n2l = icnt + NL + NN;
    int* icnt_dst_n2l = icnt + NL + 2 * NN;
    float* rsq_src_l2n = rsq;
    float* rsq_dst_l2n = rsq + NL;
    float* rsq_src_n2l = rsq + NL + NN;
    float* rsq_dst_n2l = rsq + NL + 2 * NN;

    const int TB = 256;
    const int gemm_grid = (NL + 63) / 64;
    const int gath_grid = (NL + 3) / 4;
    const int edge_grid = (NE + TB - 1) / TB;
    const int alloc_grid = 2 * ((NL + 255) / 256);

    // ---- degrees + order-free CSR build ----
    hipMemsetAsync(icnt, 0, 200000 * sizeof(int), stream);
    deg_kernel<<<edge_grid, TB, 0, stream>>>(src_l2n, dst_l2n, icnt_src_l2n, icnt_dst_l2n, NE);
    deg_kernel<<<edge_grid, TB, 0, stream>>>(src_n2l, dst_n2l, icnt_src_n2l, icnt_dst_n2l, NE);
    rsq_kernel<<<(200000 + TB - 1) / TB, TB, 0, stream>>>(icnt, rsq, 200000);

    hipMemsetAsync(cursor, 0, 50002 * sizeof(int), stream);
    alloc_beg<<<alloc_grid, TB, 0, stream>>>(icnt_dst_l2n, beg_l2n, NN,
                                             icnt_dst_n2l, beg_n2l, NL, cursor + 50000);
    fill_csr<<<edge_grid, TB, 0, stream>>>(src_l2n, dst_l2n, beg_l2n, cursor, col_l2n, NE);
    hipMemsetAsync(cursor, 0, 50000 * sizeof(int), stream);
    fill_csr<<<edge_grid, TB, 0, stream>>>(src_n2l, dst_n2l, beg_n2l, cursor, col_n2l, NE);

    // ---- weight conversion ----
    conv_wt<<<(128 * 320 + TB - 1) / TB, TB, 0, stream>>>(W0_l2n, Wt0_l2n, 300, 320);
    conv_wt<<<(128 * 224 + TB - 1) / TB, TB, 0, stream>>>(W0_n2l, Wt0_n2l, 200, 224);
    conv_wt<<<(128 * 128 + TB - 1) / TB, TB, 0, stream>>>(W_l2n,             Wt_l2n0, 128, 128);
    conv_wt<<<(128 * 128 + TB - 1) / TB, TB, 0, stream>>>(W_l2n + 128 * 128, Wt_l2n1, 128, 128);
    conv_wt<<<(128 * 128 + TB - 1) / TB, TB, 0, stream>>>(W_n2l,             Wt_n2l0, 128, 128);
    conv_wt<<<(128 * 128 + TB - 1) / TB, TB, 0, stream>>>(W_n2l + 128 * 128, Wt_n2l1, 128, 128);

    // ---- layer 0: project-first, then gather+LN ----
    mfma_gemm<320, false><<<gemm_grid, TB, 0, stream>>>(feat_l, 300, Wt0_l2n, rsq_src_l2n,
                                                        nullptr, nullptr, nullptr, xs0, nullptr);
    mfma_gemm<224, false><<<gemm_grid, TB, 0, stream>>>(feat_n, 200, Wt0_n2l, rsq_src_n2l,
                                                        nullptr, nullptr, nullptr, xs1, nullptr);
    gather_finalize<<<gath_grid, TB, 0, stream>>>(xs0, beg_l2n, icnt_dst_l2n, col_l2n, rsq_dst_l2n,
                                                  b0_l2n, ln_g_n, ln_b_n, hn, NN);
    gather_finalize<<<gath_grid, TB, 0, stream>>>(xs1, beg_n2l, icnt_dst_n2l, col_n2l, rsq_dst_n2l,
                                                  b0_n2l, ln_g_l, ln_b_l, hl, NL);

    // ---- layers 1,2: gather-first (bf16 h), then GEMM with fused LN+ELU ----
    const u16* Wls[2] = {Wt_l2n0, Wt_l2n1};
    const u16* Wns[2] = {Wt_n2l0, Wt_n2l1};
    for (int i = 1; i <= 2; ++i) {
        const float* bl = b_l2n + (size_t)(i - 1) * DD;
        const float* bn = b_n2l + (size_t)(i - 1) * DD;
        gather_scale<<<gath_grid, TB, 0, stream>>>(hl, beg_l2n, icnt_dst_l2n, col_l2n,
                                                   rsq_src_l2n, xs0, NN);
        gather_scale<<<gath_grid, TB, 0, stream>>>(hn, beg_n2l, icnt_dst_n2l, col_n2l,
                                                   rsq_src_n2l, xs1, NL);
        mfma_gemm<128, true><<<gemm_grid, TB, 0, stream>>>(xs0, 128, Wls[i - 1], rsq_dst_l2n,
                                                           bl, ln_g_n + (size_t)i * DD,
                                                           ln_b_n + (size_t)i * DD, nullptr, hn);
        mfma_gemm<128, true><<<gemm_grid, TB, 0, stream>>>(xs1, 128, Wns[i - 1], rsq_dst_n2l,
                                                           bn, ln_g_l + (size_t)i * DD,
                                                           ln_b_l + (size_t)i * DD, nullptr, hl);
    }

    // ---- pooling + head ----
    pool_partial<<<NG * PSPLIT, 128, 0, stream>>>(hl, gid_l, part_l, NL);
    pool_partial<<<NG * PSPLIT, 128, 0, stream>>>(hn, gid_n, part_n, NN);
    head_kernel<<<NG, 128, 0, stream>>>(part_l, part_n, gid_l, gid_n,
                                        W_fc, b_fc, W_out, b_out, (float*)d_out);
}

// Round 6
// 623.060 us; speedup vs baseline: 12.1884x; 1.0289x over previous
//
#include <hip/hip_runtime.h>
#include <math.h>

#define NL 50000
#define NN 50000
#define NE 600000
#define NG 64
#define DD 128
#define MPAD 50048      // 782*64
#define PSPLIT 8

typedef unsigned short u16;
typedef unsigned int u32;
using bf16x8 = __attribute__((ext_vector_type(8))) short;
using f32x4  = __attribute__((ext_vector_type(4))) float;

__device__ __forceinline__ u16 f2bf(float x) {
    u32 u = __float_as_uint(x);
    u32 r = (u + 0x7fffu + ((u >> 16) & 1u)) >> 16;
    return (u16)r;
}
__device__ __forceinline__ float bf2f(u16 x) {
    return __uint_as_float(((u32)x) << 16);
}
__device__ __forceinline__ void gload16(const void* g, void* l) {
    __builtin_amdgcn_global_load_lds((const __attribute__((address_space(1))) void*)g,
                                     (__attribute__((address_space(3))) void*)l, 16, 0, 0);
}

// ---------------- degree histogram ----------------
__global__ void deg_kernel(const int* __restrict__ src, const int* __restrict__ dst,
                           int* __restrict__ dsrc, int* __restrict__ ddst, int E) {
    int e = blockIdx.x * blockDim.x + threadIdx.x;
    if (e < E) {
        atomicAdd(&dsrc[src[e]], 1);
        atomicAdd(&ddst[dst[e]], 1);
    }
}

__global__ void rsq_kernel(const int* __restrict__ cnt, float* __restrict__ out, int n) {
    int i = blockIdx.x * blockDim.x + threadIdx.x;
    if (i < n) out[i] = rsqrtf(fmaxf((float)cnt[i], 1.0f));
}

// ---------------- order-free segment allocation (one atomic per block) ----------------
__global__ __launch_bounds__(256) void alloc_beg(const int* __restrict__ cntA, int* __restrict__ begA, int nA,
                                                 const int* __restrict__ cntB, int* __restrict__ begB, int nB,
                                                 int* __restrict__ ctrs) {
    int nblkA = (nA + 255) >> 8;
    const int* cnt; int* beg; int* ctr; int base_i; int n;
    if ((int)blockIdx.x < nblkA) { cnt = cntA; beg = begA; ctr = ctrs;     base_i = blockIdx.x * 256;           n = nA; }
    else                         { cnt = cntB; beg = begB; ctr = ctrs + 1; base_i = (blockIdx.x - nblkA) * 256; n = nB; }
    int i = base_i + threadIdx.x;
    int v = (i < n) ? cnt[i] : 0;
    __shared__ int sm[256];
    __shared__ int sbase;
    sm[threadIdx.x] = v;
    __syncthreads();
    for (int off = 1; off < 256; off <<= 1) {
        int t = (threadIdx.x >= (unsigned)off) ? sm[threadIdx.x - off] : 0;
        __syncthreads();
        sm[threadIdx.x] += t;
        __syncthreads();
    }
    if (threadIdx.x == 255) sbase = atomicAdd(ctr, sm[255]);
    __syncthreads();
    if (i < n) beg[i] = sbase + sm[threadIdx.x] - v;
}

// ---------------- CSR fill ----------------
__global__ void fill_csr(const int* __restrict__ src, const int* __restrict__ dst,
                         const int* __restrict__ beg, int* __restrict__ cursor,
                         int* __restrict__ col, int E) {
    int e = blockIdx.x * blockDim.x + threadIdx.x;
    if (e < E) {
        int d = dst[e];
        int pos = atomicAdd(&cursor[d], 1);
        col[beg[d] + pos] = src[e];
    }
}

// ---------------- W -> bf16, transposed [n][k], K zero-padded to KP ----------------
__global__ void conv_wt(const float* __restrict__ W, u16* __restrict__ Wt, int K, int KP) {
    int i = blockIdx.x * blockDim.x + threadIdx.x;
    if (i >= 128 * KP) return;
    int n = i / KP, k = i % KP;
    float v = (k < K) ? W[(size_t)k * 128 + n] : 0.0f;
    Wt[i] = f2bf(v);
}

// ---------------- feats fp32 [M][K] -> bf16 [MPAD][KP] (zero pad both dims) ----------------
__global__ void conv_feat(const float* __restrict__ F, u16* __restrict__ out,
                          int M, int K, int KP, int total8) {
    int i = blockIdx.x * blockDim.x + threadIdx.x;
    if (i >= total8) return;
    int row = i / (KP >> 3);
    int k0  = (i % (KP >> 3)) << 3;
    u32 pk[4];
#pragma unroll
    for (int p = 0; p < 4; ++p) {
        int ka = k0 + 2 * p, kb = k0 + 2 * p + 1;
        float v0 = (row < M && ka < K) ? F[(size_t)row * K + ka] : 0.0f;
        float v1 = (row < M && kb < K) ? F[(size_t)row * K + kb] : 0.0f;
        pk[p] = (u32)f2bf(v0) | ((u32)f2bf(v1) << 16);
    }
    *(uint4*)&out[(size_t)row * KP + k0] = make_uint4(pk[0], pk[1], pk[2], pk[3]);
}

// ---------------- MFMA GEMM (all-bf16, gload16 staging, 1 barrier/K-step) ----------------
// out_raw[m][n] = sum_k A[m][k]*Wt[n][k].
// LN=false: out = f2bf(rsq[m]*raw)           (layer-0 xs, rsq = rsq_src)
// LN=true : out = f2bf(elu(ln(rsq[m]*raw + bias)))   (rsq = rsq_dst)
template<int KP, bool LN>
__global__ __launch_bounds__(256) void mfma_gemm(const u16* __restrict__ A,
                                                 const u16* __restrict__ Wt,
                                                 const float* __restrict__ rsq,
                                                 const float* __restrict__ bias,
                                                 const float* __restrict__ g,
                                                 const float* __restrict__ bln,
                                                 u16* __restrict__ out) {
    constexpr int NT = KP / 32;
    __shared__ __align__(16) u16 As[2][64 * 32];
    __shared__ __align__(16) u16 Bs[2][128 * 32];
    __shared__ float rs[2][64][2];
    const int t    = threadIdx.x;
    const int lane = t & 63;
    const int wid  = t >> 6;
    const int wr   = wid >> 1;
    const int wc   = wid & 1;
    const int brow = blockIdx.x * 64;
    const int l15  = lane & 15;
    const int kg   = lane >> 4;

    f32x4 acc[2][4];
#pragma unroll
    for (int mi = 0; mi < 2; ++mi)
#pragma unroll
        for (int ni = 0; ni < 4; ++ni) acc[mi][ni] = (f32x4){0.f, 0.f, 0.f, 0.f};

    // stage source addressing (pre-swizzled chunks, key = (row>>1)&3)
    const int ar = t >> 2;                       // local A row 0..63
    const int ach = (t & 3) ^ ((ar >> 1) & 3);   // source chunk for A
    const u16* a_src = A + (size_t)(brow + ar) * KP + ach * 8;
    const int bn0 = t >> 2;                      // B row round 0
    const int bn1 = (256 + t) >> 2;              // B row round 1
    const u16* b_src0 = Wt + (size_t)bn0 * KP + ((t & 3) ^ ((bn0 >> 1) & 3)) * 8;
    const u16* b_src1 = Wt + (size_t)bn1 * KP + ((t & 3) ^ ((bn1 >> 1) & 3)) * 8;

#define STAGE(kt, buf)                                                        \
    do {                                                                      \
        gload16(a_src + (kt) * 32, (char*)&As[buf][0] + wid * 1024);          \
        gload16(b_src0 + (kt) * 32, (char*)&Bs[buf][0] + wid * 1024);         \
        gload16(b_src1 + (kt) * 32, (char*)&Bs[buf][0] + 4096 + wid * 1024);  \
    } while (0)

    STAGE(0, 0);
    __syncthreads();

    const int fo = (kg ^ ((l15 >> 1) & 3)) * 8;  // frag chunk (swizzled read)
#pragma unroll
    for (int kt = 0; kt < NT; ++kt) {
        const int cur = kt & 1;
        if (kt + 1 < NT) STAGE(kt + 1, cur ^ 1);
        bf16x8 a0 = *(const bf16x8*)&As[cur][(wr * 32 +  0 + l15) * 32 + fo];
        bf16x8 a1 = *(const bf16x8*)&As[cur][(wr * 32 + 16 + l15) * 32 + fo];
#pragma unroll
        for (int ni = 0; ni < 4; ++ni) {
            bf16x8 b = *(const bf16x8*)&Bs[cur][(wc * 64 + ni * 16 + l15) * 32 + fo];
            acc[0][ni] = __builtin_amdgcn_mfma_f32_16x16x32_bf16(a0, b, acc[0][ni], 0, 0, 0);
            acc[1][ni] = __builtin_amdgcn_mfma_f32_16x16x32_bf16(a1, b, acc[1][ni], 0, 0, 0);
        }
        __syncthreads();
    }
#undef STAGE

    if constexpr (!LN) {
#pragma unroll
        for (int mi = 0; mi < 2; ++mi)
#pragma unroll
            for (int r = 0; r < 4; ++r) {
                int grow = brow + wr * 32 + mi * 16 + kg * 4 + r;
                if (grow < NL) {
                    float s = rsq[grow];
#pragma unroll
                    for (int ni = 0; ni < 4; ++ni)
                        out[(size_t)grow * 128 + wc * 64 + ni * 16 + l15] = f2bf(acc[mi][ni][r] * s);
                }
            }
    } else {
        float b4[4], g4[4], bl4[4];
#pragma unroll
        for (int ni = 0; ni < 4; ++ni) {
            int c = wc * 64 + ni * 16 + l15;
            b4[ni] = bias[c]; g4[ni] = g[c]; bl4[ni] = bln[c];
        }
        float rsv[2][4];
#pragma unroll
        for (int mi = 0; mi < 2; ++mi)
#pragma unroll
            for (int r = 0; r < 4; ++r) {
                int grow = brow + wr * 32 + mi * 16 + kg * 4 + r;
                rsv[mi][r] = (grow < NL) ? rsq[grow] : 0.0f;
            }
#pragma unroll
        for (int mi = 0; mi < 2; ++mi)
#pragma unroll
            for (int r = 0; r < 4; ++r) {
                int lrow = wr * 32 + mi * 16 + kg * 4 + r;
                float s1 = 0.f, s2 = 0.f;
#pragma unroll
                for (int ni = 0; ni < 4; ++ni) {
                    float xv = acc[mi][ni][r] * rsv[mi][r] + b4[ni];
                    s1 += xv; s2 += xv * xv;
                }
#pragma unroll
                for (int m = 1; m < 16; m <<= 1) {
                    s1 += __shfl_xor(s1, m, 64);
                    s2 += __shfl_xor(s2, m, 64);
                }
                if (l15 == 0) { rs[0][lrow][wc] = s1; rs[1][lrow][wc] = s2; }
            }
        __syncthreads();
#pragma unroll
        for (int mi = 0; mi < 2; ++mi)
#pragma unroll
            for (int r = 0; r < 4; ++r) {
                int lrow = wr * 32 + mi * 16 + kg * 4 + r;
                int grow = brow + lrow;
                if (grow < NL) {
                    float S1 = rs[0][lrow][0] + rs[0][lrow][1];
                    float S2 = rs[1][lrow][0] + rs[1][lrow][1];
                    float mu = S1 * (1.0f / 128.0f);
                    float var = S2 * (1.0f / 128.0f) - mu * mu;
                    float rstd = rsqrtf(fmaxf(var, 0.0f) + 1e-5f);
#pragma unroll
                    for (int ni = 0; ni < 4; ++ni) {
                        float xv = acc[mi][ni][r] * rsv[mi][r] + b4[ni];
                        float y = (xv - mu) * rstd * g4[ni] + bl4[ni];
                        y = (y > 0.0f) ? y : expm1f(y);
                        out[(size_t)grow * 128 + wc * 64 + ni * 16 + l15] = f2bf(y);
                    }
                }
            }
    }
}

// ---------------- layer-0 gather (bf16 xs, unit edge weight) + LN + ELU -> bf16 ----------------
__global__ __launch_bounds__(256) void gather_ln(const u16* __restrict__ xs,
                                                 const int* __restrict__ beg,
                                                 const int* __restrict__ cnt,
                                                 const int* __restrict__ col,
                                                 const float* __restrict__ rsq_in,
                                                 const float* __restrict__ bias,
                                                 const float* __restrict__ g,
                                                 const float* __restrict__ bln,
                                                 u16* __restrict__ out, int M) {
    int row  = blockIdx.x * 4 + (threadIdx.x >> 6);
    int lane = threadIdx.x & 63;
    if (row >= M) return;
    int b = beg[row], n = cnt[row];
    const u32* x32 = (const u32*)xs;

    float a0 = 0.0f, a1 = 0.0f;
    int e = 0;
    for (; e + 1 < n; e += 2) {
        u32 p0 = x32[(size_t)col[b + e] * 64 + lane];
        u32 p1 = x32[(size_t)col[b + e + 1] * 64 + lane];
        a0 += bf2f((u16)p0) + bf2f((u16)p1);
        a1 += bf2f((u16)(p0 >> 16)) + bf2f((u16)(p1 >> 16));
    }
    if (e < n) {
        u32 p = x32[(size_t)col[b + e] * 64 + lane];
        a0 += bf2f((u16)p);
        a1 += bf2f((u16)(p >> 16));
    }

    float sc = rsq_in[row];
    float2 bv = *(const float2*)&bias[lane * 2];
    float x0 = a0 * sc + bv.x;
    float x1 = a1 * sc + bv.y;

    float sum = x0 + x1;
#pragma unroll
    for (int m = 1; m < 64; m <<= 1) sum += __shfl_xor(sum, m, 64);
    float mu = sum * (1.0f / 128.0f);

    float d0 = x0 - mu, d1 = x1 - mu;
    float ss = d0 * d0 + d1 * d1;
#pragma unroll
    for (int m = 1; m < 64; m <<= 1) ss += __shfl_xor(ss, m, 64);
    float rstd = rsqrtf(ss * (1.0f / 128.0f) + 1e-5f);

    float2 gv = *(const float2*)&g[lane * 2];
    float2 bl = *(const float2*)&bln[lane * 2];
    float y0 = d0 * rstd * gv.x + bl.x;
    float y1 = d1 * rstd * gv.y + bl.y;
    y0 = (y0 > 0.0f) ? y0 : expm1f(y0);
    y1 = (y1 > 0.0f) ? y1 : expm1f(y1);
    ((u32*)out)[(size_t)row * 64 + lane] = (u32)f2bf(y0) | ((u32)f2bf(y1) << 16);
}

// ---------------- layers 1-2 gather: agg[dst] = bf16( sum rsq_src[s]*h[s] ) ----------------
__global__ __launch_bounds__(256) void gather_scale(const u16* __restrict__ h,
                                                    const int* __restrict__ beg,
                                                    const int* __restrict__ cnt,
                                                    const int* __restrict__ col,
                                                    const float* __restrict__ rsq_src,
                                                    u16* __restrict__ agg, int M) {
    int row  = blockIdx.x * 4 + (threadIdx.x >> 6);
    int lane = threadIdx.x & 63;
    if (row >= M) return;
    int b = beg[row], n = cnt[row];
    const u32* h32 = (const u32*)h;

    float a0 = 0.0f, a1 = 0.0f;
    int e = 0;
    for (; e + 1 < n; e += 2) {
        int s0 = col[b + e], s1 = col[b + e + 1];
        float r0 = rsq_src[s0], r1 = rsq_src[s1];
        u32 p0 = h32[(size_t)s0 * 64 + lane];
        u32 p1 = h32[(size_t)s1 * 64 + lane];
        a0 = fmaf(r0, bf2f((u16)p0), a0);
        a1 = fmaf(r0, bf2f((u16)(p0 >> 16)), a1);
        a0 = fmaf(r1, bf2f((u16)p1), a0);
        a1 = fmaf(r1, bf2f((u16)(p1 >> 16)), a1);
    }
    if (e < n) {
        int s = col[b + e];
        float r = rsq_src[s];
        u32 p = h32[(size_t)s * 64 + lane];
        a0 = fmaf(r, bf2f((u16)p), a0);
        a1 = fmaf(r, bf2f((u16)(p >> 16)), a1);
    }
    ((u32*)agg)[(size_t)row * 64 + lane] = (u32)f2bf(a0) | ((u32)f2bf(a1) << 16);
}

// ---------------- segmented pooling from bf16 h ----------------
__global__ __launch_bounds__(128) void pool_partial(const u16* __restrict__ h,
                                                    const int* __restrict__ gid,
                                                    float* __restrict__ partial, int M) {
    int g = blockIdx.x / PSPLIT;
    int p = blockIdx.x % PSPLIT;
    int j = threadIdx.x;
    __shared__ int bounds[2];
    if (j < 2) {
        int target = g + j;
        int lo = 0, hi = M;
        while (lo < hi) { int mid = (lo + hi) >> 1; if (gid[mid] < target) lo = mid + 1; else hi = mid; }
        bounds[j] = lo;
    }
    __syncthreads();
    int beg = bounds[0], end = bounds[1];
    int len = end - beg;
    int chunk = (len + PSPLIT - 1) / PSPLIT;
    int s0i = beg + p * chunk;
    int e0i = min(s0i + chunk, end);

    float s0 = 0.0f, s1 = 0.0f, s2 = 0.0f, s3 = 0.0f;
    int i = s0i;
    for (; i + 3 < e0i; i += 4) {
        s0 += bf2f(h[(size_t)(i + 0) * 128 + j]);
        s1 += bf2f(h[(size_t)(i + 1) * 128 + j]);
        s2 += bf2f(h[(size_t)(i + 2) * 128 + j]);
        s3 += bf2f(h[(size_t)(i + 3) * 128 + j]);
    }
    for (; i < e0i; ++i) s0 += bf2f(h[(size_t)i * 128 + j]);
    partial[(size_t)(g * PSPLIT + p) * 128 + j] = (s0 + s1) + (s2 + s3);
}

// ---------------- head ----------------
__global__ __launch_bounds__(128) void head_kernel(const float* __restrict__ part_l,
                                                   const float* __restrict__ part_n,
                                                   const int* __restrict__ gid_l,
                                                   const int* __restrict__ gid_n,
                                                   const float* __restrict__ W_fc,
                                                   const float* __restrict__ b_fc,
                                                   const float* __restrict__ W_out,
                                                   const float* __restrict__ b_out,
                                                   float* __restrict__ out) {
    int g = blockIdx.x;
    int j = threadIdx.x;
    __shared__ float hg[128];
    __shared__ float red[2];
    __shared__ int bounds[4];
    if (j < 4) {
        const int* gid = (j < 2) ? gid_l : gid_n;
        int target = g + (j & 1);
        int lo = 0, hi = 50000;
        while (lo < hi) { int mid = (lo + hi) >> 1; if (gid[mid] < target) lo = mid + 1; else hi = mid; }
        bounds[j] = lo;
    }
    __syncthreads();
    float cl = fmaxf((float)(bounds[1] - bounds[0]), 1.0f);
    float cn = fmaxf((float)(bounds[3] - bounds[2]), 1.0f);
    float sl = 0.0f, sn = 0.0f;
#pragma unroll
    for (int p = 0; p < PSPLIT; ++p) {
        sl += part_l[(size_t)(g * PSPLIT + p) * 128 + j];
        sn += part_n[(size_t)(g * PSPLIT + p) * 128 + j];
    }
    hg[j] = sl / cl + sn / cn;
    __syncthreads();
    float acc = b_fc[j];
#pragma unroll 8
    for (int k = 0; k < 128; ++k) acc = fmaf(hg[k], W_fc[k * 128 + j], acc);
    float fc = fmaxf(acc, 0.0f);
    float v = fc * W_out[j];
#pragma unroll
    for (int m = 1; m < 64; m <<= 1) v += __shfl_xor(v, m, 64);
    if ((j & 63) == 0) red[j >> 6] = v;
    __syncthreads();
    if (j == 0) out[g] = red[0] + red[1] + b_out[0];
}

static inline size_t align_up(size_t x, size_t a) { return (x + a - 1) & ~(a - 1); }

extern "C" void kernel_launch(void* const* d_in, const int* in_sizes, int n_in,
                              void* d_out, int out_size, void* d_ws, size_t ws_size,
                              hipStream_t stream) {
    const float* feat_l = (const float*)d_in[0];
    const float* feat_n = (const float*)d_in[1];
    const float* W0_l2n = (const float*)d_in[2];
    const float* b0_l2n = (const float*)d_in[3];
    const float* W0_n2l = (const float*)d_in[4];
    const float* b0_n2l = (const float*)d_in[5];
    const float* W_l2n  = (const float*)d_in[6];
    const float* b_l2n  = (const float*)d_in[7];
    const float* W_n2l  = (const float*)d_in[8];
    const float* b_n2l  = (const float*)d_in[9];
    const float* ln_g_n = (const float*)d_in[10];
    const float* ln_b_n = (const float*)d_in[11];
    const float* ln_g_l = (const float*)d_in[12];
    const float* ln_b_l = (const float*)d_in[13];
    const float* W_fc   = (const float*)d_in[14];
    const float* b_fc   = (const float*)d_in[15];
    const float* W_out  = (const float*)d_in[16];
    const float* b_out  = (const float*)d_in[17];
    const int* src_l2n  = (const int*)d_in[18];
    const int* dst_l2n  = (const int*)d_in[19];
    const int* src_n2l  = (const int*)d_in[20];
    const int* dst_n2l  = (const int*)d_in[21];
    const int* gid_l    = (const int*)d_in[22];
    const int* gid_n    = (const int*)d_in[23];

    // ---- workspace layout (with aliasing to stay < ~101 MB) ----
    char* ws = (char*)d_ws;
    size_t off = 0;
    auto take = [&](size_t bytes) { char* p = ws + off; off = align_up(off + bytes, 256); return p; };
    int*   icnt        = (int*)take(200000 * 4);
    float* rsq         = (float*)take(200000 * 4);
    int*   beg_l2n     = (int*)take(NN * 4);
    int*   beg_n2l     = (int*)take(NL * 4);
    int*   cursor      = (int*)take(50002 * 4);
    int*   col_l2n     = (int*)take((size_t)NE * 4);
    int*   col_n2l     = (int*)take((size_t)NE * 4);
    u16*   Wt0_l2n     = (u16*)take(128 * 320 * 2);
    u16*   Wt0_n2l     = (u16*)take(128 * 224 * 2);
    u16*   Wt_l2n0     = (u16*)take(128 * 128 * 2);
    u16*   Wt_l2n1     = (u16*)take(128 * 128 * 2);
    u16*   Wt_n2l0     = (u16*)take(128 * 128 * 2);
    u16*   Wt_n2l1     = (u16*)take(128 * 128 * 2);
    u16*   featA       = (u16*)take((size_t)MPAD * 320 * 2);  // featb_l; later agg0+agg1
    u16*   featB       = (u16*)take((size_t)MPAD * 224 * 2);  // featb_n; later xs0
    u16*   xs1         = (u16*)take((size_t)MPAD * 128 * 2);
    u16*   hl          = (u16*)take((size_t)MPAD * 128 * 2);
    u16*   hn          = (u16*)take((size_t)MPAD * 128 * 2);
    float* part_l      = (float*)take((size_t)NG * PSPLIT * 128 * 4);
    float* part_n      = (float*)take((size_t)NG * PSPLIT * 128 * 4);

    u16* featb_l = featA;
    u16* featb_n = featB;
    u16* agg0 = featA;                            // alive only after featb_l dead
    u16* agg1 = featA + (size_t)MPAD * 128;
    u16* xs0  = featB;                            // alive only after featb_n dead

    int* icnt_src_l2n = icnt;
    int* icnt_dst_l2n = icnt + NL;
    int* icnt_src_n2l = icnt + NL + NN;
    int* icnt_dst_n2l = icnt + NL + 2 * NN;
    float* rsq_src_l2n = rsq;
    float* rsq_dst_l2n = rsq + NL;
    float* rsq_src_n2l = rsq + NL + NN;
    float* rsq_dst_n2l = rsq + NL + 2 * NN;

    const int TB = 256;
    const int gemm_grid = MPAD / 64;              // 782
    const int gath_grid = (NL + 3) / 4;
    const int edge_grid = (NE + TB - 1) / TB;
    const int alloc_grid = 2 * ((NL + 255) / 256);

    // ---- degrees + order-free CSR build ----
    hipMemsetAsync(icnt, 0, 200000 * sizeof(int), stream);
    deg_kernel<<<edge_grid, TB, 0, stream>>>(src_l2n, dst_l2n, icnt_src_l2n, icnt_dst_l2n, NE);
    deg_kernel<<<edge_grid, TB, 0, stream>>>(src_n2l, dst_n2l, icnt_src_n2l, icnt_dst_n2l, NE);
    rsq_kernel<<<(200000 + TB - 1) / TB, TB, 0, stream>>>(icnt, rsq, 200000);

    hipMemsetAsync(cursor, 0, 50002 * sizeof(int), stream);
    alloc_beg<<<alloc_grid, TB, 0, stream>>>(icnt_dst_l2n, beg_l2n, NN,
                                             icnt_dst_n2l, beg_n2l, NL, cursor + 50000);
    fill_csr<<<edge_grid, TB, 0, stream>>>(src_l2n, dst_l2n, beg_l2n, cursor, col_l2n, NE);
    hipMemsetAsync(cursor, 0, 50000 * sizeof(int), stream);
    fill_csr<<<edge_grid, TB, 0, stream>>>(src_n2l, dst_n2l, beg_n2l, cursor, col_n2l, NE);

    // ---- weight + feature conversion ----
    conv_wt<<<(128 * 320 + TB - 1) / TB, TB, 0, stream>>>(W0_l2n, Wt0_l2n, 300, 320);
    conv_wt<<<(128 * 224 + TB - 1) / TB, TB, 0, stream>>>(W0_n2l, Wt0_n2l, 200, 224);
    conv_wt<<<(128 * 128 + TB - 1) / TB, TB, 0, stream>>>(W_l2n,             Wt_l2n0, 128, 128);
    conv_wt<<<(128 * 128 + TB - 1) / TB, TB, 0, stream>>>(W_l2n + 128 * 128, Wt_l2n1, 128, 128);
    conv_wt<<<(128 * 128 + TB - 1) / TB, TB, 0, stream>>>(W_n2l,             Wt_n2l0, 128, 128);
    conv_wt<<<(128 * 128 + TB - 1) / TB, TB, 0, stream>>>(W_n2l + 128 * 128, Wt_n2l1, 128, 128);
    conv_feat<<<(MPAD * 40 + TB - 1) / TB, TB, 0, stream>>>(feat_l, featb_l, NL, 300, 320, MPAD * 40);
    conv_feat<<<(MPAD * 28 + TB - 1) / TB, TB, 0, stream>>>(feat_n, featb_n, NN, 200, 224, MPAD * 28);

    // ---- layer 0: project (n first, so xs0 can reuse featb_n), then gather+LN ----
    mfma_gemm<224, false><<<gemm_grid, TB, 0, stream>>>(featb_n, Wt0_n2l, rsq_src_n2l,
                                                        nullptr, nullptr, nullptr, xs1);
    mfma_gemm<320, false><<<gemm_grid, TB, 0, stream>>>(featb_l, Wt0_l2n, rsq_src_l2n,
                                                        nullptr, nullptr, nullptr, xs0);
    gather_ln<<<gath_grid, TB, 0, stream>>>(xs0, beg_l2n, icnt_dst_l2n, col_l2n, rsq_dst_l2n,
                                            b0_l2n, ln_g_n, ln_b_n, hn, NN);
    gather_ln<<<gath_grid, TB, 0, stream>>>(xs1, beg_n2l, icnt_dst_n2l, col_n2l, rsq_dst_n2l,
                                            b0_n2l, ln_g_l, ln_b_l, hl, NL);

    // ---- layers 1,2: gather-first (bf16), GEMM with fused LN+ELU ----
    const u16* Wls[2] = {Wt_l2n0, Wt_l2n1};
    const u16* Wns[2] = {Wt_n2l0, Wt_n2l1};
    for (int i = 1; i <= 2; ++i) {
        const float* bl = b_l2n + (size_t)(i - 1) * DD;
        const float* bn = b_n2l + (size_t)(i - 1) * DD;
        gather_scale<<<gath_grid, TB, 0, stream>>>(hl, beg_l2n, icnt_dst_l2n, col_l2n,
                                                   rsq_src_l2n, agg0, NN);
        gather_scale<<<gath_grid, TB, 0, stream>>>(hn, beg_n2l, icnt_dst_n2l, col_n2l,
                                                   rsq_src_n2l, agg1, NL);
        mfma_gemm<128, true><<<gemm_grid, TB, 0, stream>>>(agg0, Wls[i - 1], rsq_dst_l2n,
                                                           bl, ln_g_n + (size_t)i * DD,
                                                           ln_b_n + (size_t)i * DD, hn);
        mfma_gemm<128, true><<<gemm_grid, TB, 0, stream>>>(agg1, Wns[i - 1], rsq_dst_n2l,
                                                           bn, ln_g_l + (size_t)i * DD,
                                                           ln_b_l + (size_t)i * DD, hl);
    }

    // ---- pooling + head ----
    pool_partial<<<NG * PSPLIT, 128, 0, stream>>>(hl, gid_l, part_l, NL);
    pool_partial<<<NG * PSPLIT, 128, 0, stream>>>(hn, gid_n, part_n, NN);
    head_kernel<<<NG, 128, 0, stream>>>(part_l, part_n, gid_l, gid_n,
                                        W_fc, b_fc, W_out, b_out, (float*)d_out);
}

// Round 7
// 499.787 us; speedup vs baseline: 15.1947x; 1.2467x over previous
//
#include <hip/hip_runtime.h>
#include <math.h>

#define NL 50000
#define NN 50000
#define NE 600000
#define NG 64
#define DD 128
#define MPAD 50048
#define PSPLIT 8

typedef unsigned short u16;
typedef unsigned int u32;
using bf16x8 = __attribute__((ext_vector_type(8))) short;
using f32x4  = __attribute__((ext_vector_type(4))) float;

__device__ __forceinline__ u16 f2bf(float x) {
    u32 u = __float_as_uint(x);
    u32 r = (u + 0x7fffu + ((u >> 16) & 1u)) >> 16;
    return (u16)r;
}
__device__ __forceinline__ float bf2f(u16 x) {
    return __uint_as_float(((u32)x) << 16);
}
__device__ __forceinline__ void gload16(const void* g, void* l) {
    __builtin_amdgcn_global_load_lds((const __attribute__((address_space(1))) void*)g,
                                     (__attribute__((address_space(3))) void*)l, 16, 0, 0);
}
__device__ __forceinline__ u32 cvtpk(float lo, float hi) {
    u32 r;
    asm("v_cvt_pk_bf16_f32 %0, %1, %2" : "=v"(r) : "v"(lo), "v"(hi));
    return r;
}

// ---------------- fused histograms + position assignment (both directions) ----------------
__global__ __launch_bounds__(256) void deg_pos(const int* __restrict__ s0a, const int* __restrict__ d0a,
                                               int* __restrict__ hs0, int* __restrict__ hd0,
                                               int* __restrict__ pos0,
                                               const int* __restrict__ s1a, const int* __restrict__ d1a,
                                               int* __restrict__ hs1, int* __restrict__ hd1,
                                               int* __restrict__ pos1, int E) {
    int e = blockIdx.x * blockDim.x + threadIdx.x;
    if (e < E) {
        atomicAdd(&hs0[s0a[e]], 1);
        pos0[e] = atomicAdd(&hd0[d0a[e]], 1);
        atomicAdd(&hs1[s1a[e]], 1);
        pos1[e] = atomicAdd(&hd1[d1a[e]], 1);
    }
}

__global__ void rsq_kernel(const int* __restrict__ cnt, float* __restrict__ out, int n) {
    int i = blockIdx.x * blockDim.x + threadIdx.x;
    if (i < n) out[i] = rsqrtf(fmaxf((float)cnt[i], 1.0f));
}

// ---------------- order-free segment allocation (one atomic per block) ----------------
__global__ __launch_bounds__(256) void alloc_beg(const int* __restrict__ cntA, int* __restrict__ begA, int nA,
                                                 const int* __restrict__ cntB, int* __restrict__ begB, int nB,
                                                 int* __restrict__ ctrs) {
    int nblkA = (nA + 255) >> 8;
    const int* cnt; int* beg; int* ctr; int base_i; int n;
    if ((int)blockIdx.x < nblkA) { cnt = cntA; beg = begA; ctr = ctrs;     base_i = blockIdx.x * 256;           n = nA; }
    else                         { cnt = cntB; beg = begB; ctr = ctrs + 1; base_i = (blockIdx.x - nblkA) * 256; n = nB; }
    int i = base_i + threadIdx.x;
    int v = (i < n) ? cnt[i] : 0;
    __shared__ int sm[256];
    __shared__ int sbase;
    sm[threadIdx.x] = v;
    __syncthreads();
    for (int off = 1; off < 256; off <<= 1) {
        int t = (threadIdx.x >= (unsigned)off) ? sm[threadIdx.x - off] : 0;
        __syncthreads();
        sm[threadIdx.x] += t;
        __syncthreads();
    }
    if (threadIdx.x == 255) sbase = atomicAdd(ctr, sm[255]);
    __syncthreads();
    if (i < n) beg[i] = sbase + sm[threadIdx.x] - v;
}

// ---------------- CSR fill, atomic-free (uses precomputed pos) ----------------
__global__ void fill_csr(const int* __restrict__ src, const int* __restrict__ dst,
                         const int* __restrict__ pos, const int* __restrict__ beg,
                         int* __restrict__ col, int E) {
    int e = blockIdx.x * blockDim.x + threadIdx.x;
    if (e < E) col[beg[dst[e]] + pos[e]] = src[e];
}

// ---------------- W -> bf16, transposed [n][k], K zero-padded to KP ----------------
__global__ void conv_wt(const float* __restrict__ W, u16* __restrict__ Wt, int K, int KP) {
    int i = blockIdx.x * blockDim.x + threadIdx.x;
    if (i >= 128 * KP) return;
    int n = i / KP, k = i % KP;
    float v = (k < K) ? W[(size_t)k * 128 + n] : 0.0f;
    Wt[i] = f2bf(v);
}

// ---------------- MFMA GEMM ----------------
// BM=64, BN=128, 4 waves (2x2), 16x16x32 bf16 MFMA, BK=32, double-buffered LDS.
// AF32=true : A fp32 [M][K] staged via float4 + cvt_pk + ds_write (K runtime, KP compile pad)
// AF32=false: A bf16 [MPAD][KP] staged via global_load_lds
// LN=false: out = f2bf(rsq[m]*raw);  LN=true: out = f2bf(elu(ln(rsq[m]*raw + bias)))
template<int KP, bool LN, bool AF32>
__global__ __launch_bounds__(256) void mfma_gemm(const void* __restrict__ Av, int K, int M,
                                                 const u16* __restrict__ Wt,
                                                 const float* __restrict__ rsq,
                                                 const float* __restrict__ bias,
                                                 const float* __restrict__ gw,
                                                 const float* __restrict__ bln,
                                                 u16* __restrict__ out) {
    constexpr int NT = KP / 32;
    __shared__ __align__(16) u16 As[2][64 * 32];
    __shared__ __align__(16) u16 Bs[2][128 * 32];
    __shared__ float rs[2][64][2];
    const int t    = threadIdx.x;
    const int lane = t & 63;
    const int wid  = t >> 6;
    const int wr   = wid >> 1;
    const int wc   = wid & 1;
    const int brow = blockIdx.x * 64;
    const int l15  = lane & 15;
    const int kg   = lane >> 4;

    f32x4 acc[2][4];
#pragma unroll
    for (int mi = 0; mi < 2; ++mi)
#pragma unroll
        for (int ni = 0; ni < 4; ++ni) acc[mi][ni] = (f32x4){0.f, 0.f, 0.f, 0.f};

    // A addressing: LDS[row][chunk] = src[row][chunk ^ key(row)], key = (row>>1)&3
    const int ar   = t >> 2;
    const int ac   = t & 3;
    const int akey = (ar >> 1) & 3;
    const int grow = brow + ar;
    // B addressing
    const int bn0 = t >> 2;
    const int bn1 = (256 + t) >> 2;
    const u16* b_src0 = Wt + (size_t)bn0 * KP + ((t & 3) ^ ((bn0 >> 1) & 3)) * 8;
    const u16* b_src1 = Wt + (size_t)bn1 * KP + ((t & 3) ^ ((bn1 >> 1) & 3)) * 8;
    const u16* a_src = nullptr;
    if constexpr (!AF32) a_src = (const u16*)Av + (size_t)grow * KP + (ac ^ akey) * 8;

#define STAGE_B(kt, buf)                                                          \
    do {                                                                          \
        gload16(b_src0 + (kt) * 32, (char*)&Bs[buf][0] + wid * 1024);             \
        gload16(b_src1 + (kt) * 32, (char*)&Bs[buf][0] + 4096 + wid * 1024);      \
    } while (0)
#define STAGE_A16(kt, buf)                                                        \
    gload16(a_src + (kt) * 32, (char*)&As[buf][0] + wid * 1024)

    struct A8 { float4 x, y; };
    auto loadA = [&](int kt) -> A8 {
        const float* A = (const float*)Av;
        int kbase = kt * 32 + (ac ^ akey) * 8;
        const float* p = A + (size_t)grow * K + kbase;
        A8 r;
        bool rowok = grow < M;
        r.x = (rowok && kbase + 4 <= K) ? *(const float4*)p       : make_float4(0.f, 0.f, 0.f, 0.f);
        r.y = (rowok && kbase + 8 <= K) ? *(const float4*)(p + 4) : make_float4(0.f, 0.f, 0.f, 0.f);
        return r;
    };
    auto writeA = [&](int buf, const A8& r) {
        uint4 w = make_uint4(cvtpk(r.x.x, r.x.y), cvtpk(r.x.z, r.x.w),
                             cvtpk(r.y.x, r.y.y), cvtpk(r.y.z, r.y.w));
        *(uint4*)&As[buf][ar * 32 + ac * 8] = w;
    };

    A8 rnext{};
    if constexpr (AF32) {
        A8 r0 = loadA(0);
        if (NT > 1) rnext = loadA(1);
        writeA(0, r0);
        STAGE_B(0, 0);
    } else {
        STAGE_A16(0, 0);
        STAGE_B(0, 0);
    }
    __syncthreads();

    const int fo = (kg ^ ((l15 >> 1) & 3)) * 8;
#pragma unroll
    for (int kt = 0; kt < NT; ++kt) {
        const int cur = kt & 1;
        if (kt + 1 < NT) {
            if constexpr (AF32) {
                writeA(cur ^ 1, rnext);
                STAGE_B(kt + 1, cur ^ 1);
                if (kt + 2 < NT) rnext = loadA(kt + 2);
            } else {
                STAGE_A16(kt + 1, cur ^ 1);
                STAGE_B(kt + 1, cur ^ 1);
            }
        }
        bf16x8 a0 = *(const bf16x8*)&As[cur][(wr * 32 +  0 + l15) * 32 + fo];
        bf16x8 a1 = *(const bf16x8*)&As[cur][(wr * 32 + 16 + l15) * 32 + fo];
#pragma unroll
        for (int ni = 0; ni < 4; ++ni) {
            bf16x8 b = *(const bf16x8*)&Bs[cur][(wc * 64 + ni * 16 + l15) * 32 + fo];
            acc[0][ni] = __builtin_amdgcn_mfma_f32_16x16x32_bf16(a0, b, acc[0][ni], 0, 0, 0);
            acc[1][ni] = __builtin_amdgcn_mfma_f32_16x16x32_bf16(a1, b, acc[1][ni], 0, 0, 0);
        }
        __syncthreads();
    }
#undef STAGE_B
#undef STAGE_A16

    if constexpr (!LN) {
#pragma unroll
        for (int mi = 0; mi < 2; ++mi)
#pragma unroll
            for (int r = 0; r < 4; ++r) {
                int go = brow + wr * 32 + mi * 16 + kg * 4 + r;
                if (go < M) {
                    float s = rsq[go];
#pragma unroll
                    for (int ni = 0; ni < 4; ++ni)
                        out[(size_t)go * 128 + wc * 64 + ni * 16 + l15] = f2bf(acc[mi][ni][r] * s);
                }
            }
    } else {
        float b4[4], g4[4], bl4[4];
#pragma unroll
        for (int ni = 0; ni < 4; ++ni) {
            int c = wc * 64 + ni * 16 + l15;
            b4[ni] = bias[c]; g4[ni] = gw[c]; bl4[ni] = bln[c];
        }
        float rsv[2][4];
#pragma unroll
        for (int mi = 0; mi < 2; ++mi)
#pragma unroll
            for (int r = 0; r < 4; ++r) {
                int go = brow + wr * 32 + mi * 16 + kg * 4 + r;
                rsv[mi][r] = (go < M) ? rsq[go] : 0.0f;
            }
#pragma unroll
        for (int mi = 0; mi < 2; ++mi)
#pragma unroll
            for (int r = 0; r < 4; ++r) {
                int lrow = wr * 32 + mi * 16 + kg * 4 + r;
                float s1 = 0.f, s2 = 0.f;
#pragma unroll
                for (int ni = 0; ni < 4; ++ni) {
                    float xv = acc[mi][ni][r] * rsv[mi][r] + b4[ni];
                    s1 += xv; s2 += xv * xv;
                }
#pragma unroll
                for (int m = 1; m < 16; m <<= 1) {
                    s1 += __shfl_xor(s1, m, 64);
                    s2 += __shfl_xor(s2, m, 64);
                }
                if (l15 == 0) { rs[0][lrow][wc] = s1; rs[1][lrow][wc] = s2; }
            }
        __syncthreads();
#pragma unroll
        for (int mi = 0; mi < 2; ++mi)
#pragma unroll
            for (int r = 0; r < 4; ++r) {
                int lrow = wr * 32 + mi * 16 + kg * 4 + r;
                int go = brow + lrow;
                if (go < M) {
                    float S1 = rs[0][lrow][0] + rs[0][lrow][1];
                    float S2 = rs[1][lrow][0] + rs[1][lrow][1];
                    float mu = S1 * (1.0f / 128.0f);
                    float var = S2 * (1.0f / 128.0f) - mu * mu;
                    float rstd = rsqrtf(fmaxf(var, 0.0f) + 1e-5f);
#pragma unroll
                    for (int ni = 0; ni < 4; ++ni) {
                        float xv = acc[mi][ni][r] * rsv[mi][r] + b4[ni];
                        float y = (xv - mu) * rstd * g4[ni] + bl4[ni];
                        y = (y > 0.0f) ? y : expm1f(y);
                        out[(size_t)go * 128 + wc * 64 + ni * 16 + l15] = f2bf(y);
                    }
                }
            }
    }
}

// ---------------- layer-0 gather (bf16 xs, unit weight) + LN + ELU -> bf16 ----------------
__global__ __launch_bounds__(256) void gather_ln(const u16* __restrict__ xs,
                                                 const int* __restrict__ beg,
                                                 const int* __restrict__ cnt,
                                                 const int* __restrict__ col,
                                                 const float* __restrict__ rsq_in,
                                                 const float* __restrict__ bias,
                                                 const float* __restrict__ g,
                                                 const float* __restrict__ bln,
                                                 u16* __restrict__ out, int M) {
    int row  = blockIdx.x * 4 + (threadIdx.x >> 6);
    int lane = threadIdx.x & 63;
    if (row >= M) return;
    int b = beg[row], n = cnt[row];
    const u32* x32 = (const u32*)xs;

    float a0 = 0.f, a1 = 0.f, c0 = 0.f, c1 = 0.f;
    int e = 0;
    for (; e + 3 < n; e += 4) {
        int s0 = col[b + e], s1 = col[b + e + 1], s2 = col[b + e + 2], s3 = col[b + e + 3];
        u32 p0 = x32[(size_t)s0 * 64 + lane];
        u32 p1 = x32[(size_t)s1 * 64 + lane];
        u32 p2 = x32[(size_t)s2 * 64 + lane];
        u32 p3 = x32[(size_t)s3 * 64 + lane];
        a0 += bf2f((u16)p0) + bf2f((u16)p1);
        a1 += bf2f((u16)(p0 >> 16)) + bf2f((u16)(p1 >> 16));
        c0 += bf2f((u16)p2) + bf2f((u16)p3);
        c1 += bf2f((u16)(p2 >> 16)) + bf2f((u16)(p3 >> 16));
    }
    for (; e < n; ++e) {
        u32 p = x32[(size_t)col[b + e] * 64 + lane];
        a0 += bf2f((u16)p);
        a1 += bf2f((u16)(p >> 16));
    }
    a0 += c0; a1 += c1;

    float sc = rsq_in[row];
    float2 bv = *(const float2*)&bias[lane * 2];
    float x0 = a0 * sc + bv.x;
    float x1 = a1 * sc + bv.y;

    float sum = x0 + x1;
#pragma unroll
    for (int m = 1; m < 64; m <<= 1) sum += __shfl_xor(sum, m, 64);
    float mu = sum * (1.0f / 128.0f);

    float d0 = x0 - mu, d1 = x1 - mu;
    float ss = d0 * d0 + d1 * d1;
#pragma unroll
    for (int m = 1; m < 64; m <<= 1) ss += __shfl_xor(ss, m, 64);
    float rstd = rsqrtf(ss * (1.0f / 128.0f) + 1e-5f);

    float2 gv = *(const float2*)&g[lane * 2];
    float2 bl = *(const float2*)&bln[lane * 2];
    float y0 = d0 * rstd * gv.x + bl.x;
    float y1 = d1 * rstd * gv.y + bl.y;
    y0 = (y0 > 0.0f) ? y0 : expm1f(y0);
    y1 = (y1 > 0.0f) ? y1 : expm1f(y1);
    ((u32*)out)[(size_t)row * 64 + lane] = (u32)f2bf(y0) | ((u32)f2bf(y1) << 16);
}

// ---------------- layers 1-2 gather: agg[dst] = bf16( sum rsq_src[s]*h[s] ) ----------------
__global__ __launch_bounds__(256) void gather_scale(const u16* __restrict__ h,
                                                    const int* __restrict__ beg,
                                                    const int* __restrict__ cnt,
                                                    const int* __restrict__ col,
                                                    const float* __restrict__ rsq_src,
                                                    u16* __restrict__ agg, int M) {
    int row  = blockIdx.x * 4 + (threadIdx.x >> 6);
    int lane = threadIdx.x & 63;
    if (row >= M) return;
    int b = beg[row], n = cnt[row];
    const u32* h32 = (const u32*)h;

    float a0 = 0.f, a1 = 0.f, c0 = 0.f, c1 = 0.f;
    int e = 0;
    for (; e + 3 < n; e += 4) {
        int s0 = col[b + e], s1 = col[b + e + 1], s2 = col[b + e + 2], s3 = col[b + e + 3];
        float r0 = rsq_src[s0], r1 = rsq_src[s1], r2 = rsq_src[s2], r3 = rsq_src[s3];
        u32 p0 = h32[(size_t)s0 * 64 + lane];
        u32 p1 = h32[(size_t)s1 * 64 + lane];
        u32 p2 = h32[(size_t)s2 * 64 + lane];
        u32 p3 = h32[(size_t)s3 * 64 + lane];
        a0 = fmaf(r0, bf2f((u16)p0), a0); a1 = fmaf(r0, bf2f((u16)(p0 >> 16)), a1);
        c0 = fmaf(r1, bf2f((u16)p1), c0); c1 = fmaf(r1, bf2f((u16)(p1 >> 16)), c1);
        a0 = fmaf(r2, bf2f((u16)p2), a0); a1 = fmaf(r2, bf2f((u16)(p2 >> 16)), a1);
        c0 = fmaf(r3, bf2f((u16)p3), c0); c1 = fmaf(r3, bf2f((u16)(p3 >> 16)), c1);
    }
    for (; e < n; ++e) {
        int s = col[b + e];
        float r = rsq_src[s];
        u32 p = h32[(size_t)s * 64 + lane];
        a0 = fmaf(r, bf2f((u16)p), a0);
        a1 = fmaf(r, bf2f((u16)(p >> 16)), a1);
    }
    a0 += c0; a1 += c1;
    ((u32*)agg)[(size_t)row * 64 + lane] = (u32)f2bf(a0) | ((u32)f2bf(a1) << 16);
}

// ---------------- segmented pooling from bf16 h ----------------
__global__ __launch_bounds__(128) void pool_partial(const u16* __restrict__ h,
                                                    const int* __restrict__ gid,
                                                    float* __restrict__ partial, int M) {
    int g = blockIdx.x / PSPLIT;
    int p = blockIdx.x % PSPLIT;
    int j = threadIdx.x;
    __shared__ int bounds[2];
    if (j < 2) {
        int target = g + j;
        int lo = 0, hi = M;
        while (lo < hi) { int mid = (lo + hi) >> 1; if (gid[mid] < target) lo = mid + 1; else hi = mid; }
        bounds[j] = lo;
    }
    __syncthreads();
    int beg = bounds[0], end = bounds[1];
    int len = end - beg;
    int chunk = (len + PSPLIT - 1) / PSPLIT;
    int s0i = beg + p * chunk;
    int e0i = min(s0i + chunk, end);

    float s0 = 0.f, s1 = 0.f, s2 = 0.f, s3 = 0.f;
    int i = s0i;
    for (; i + 3 < e0i; i += 4) {
        s0 += bf2f(h[(size_t)(i + 0) * 128 + j]);
        s1 += bf2f(h[(size_t)(i + 1) * 128 + j]);
        s2 += bf2f(h[(size_t)(i + 2) * 128 + j]);
        s3 += bf2f(h[(size_t)(i + 3) * 128 + j]);
    }
    for (; i < e0i; ++i) s0 += bf2f(h[(size_t)i * 128 + j]);
    partial[(size_t)(g * PSPLIT + p) * 128 + j] = (s0 + s1) + (s2 + s3);
}

// ---------------- head ----------------
__global__ __launch_bounds__(128) void head_kernel(const float* __restrict__ part_l,
                                                   const float* __restrict__ part_n,
                                                   const int* __restrict__ gid_l,
                                                   const int* __restrict__ gid_n,
                                                   const float* __restrict__ W_fc,
                                                   const float* __restrict__ b_fc,
                                                   const float* __restrict__ W_out,
                                                   const float* __restrict__ b_out,
                                                   float* __restrict__ out) {
    int g = blockIdx.x;
    int j = threadIdx.x;
    __shared__ float hg[128];
    __shared__ float red[2];
    __shared__ int bounds[4];
    if (j < 4) {
        const int* gid = (j < 2) ? gid_l : gid_n;
        int target = g + (j & 1);
        int lo = 0, hi = 50000;
        while (lo < hi) { int mid = (lo + hi) >> 1; if (gid[mid] < target) lo = mid + 1; else hi = mid; }
        bounds[j] = lo;
    }
    __syncthreads();
    float cl = fmaxf((float)(bounds[1] - bounds[0]), 1.0f);
    float cn = fmaxf((float)(bounds[3] - bounds[2]), 1.0f);
    float sl = 0.f, sn = 0.f;
#pragma unroll
    for (int p = 0; p < PSPLIT; ++p) {
        sl += part_l[(size_t)(g * PSPLIT + p) * 128 + j];
        sn += part_n[(size_t)(g * PSPLIT + p) * 128 + j];
    }
    hg[j] = sl / cl + sn / cn;
    __syncthreads();
    float acc = b_fc[j];
#pragma unroll 8
    for (int k = 0; k < 128; ++k) acc = fmaf(hg[k], W_fc[k * 128 + j], acc);
    float fc = fmaxf(acc, 0.0f);
    float v = fc * W_out[j];
#pragma unroll
    for (int m = 1; m < 64; m <<= 1) v += __shfl_xor(v, m, 64);
    if ((j & 63) == 0) red[j >> 6] = v;
    __syncthreads();
    if (j == 0) out[g] = red[0] + red[1] + b_out[0];
}

static inline size_t align_up(size_t x, size_t a) { return (x + a - 1) & ~(a - 1); }

extern "C" void kernel_launch(void* const* d_in, const int* in_sizes, int n_in,
                              void* d_out, int out_size, void* d_ws, size_t ws_size,
                              hipStream_t stream) {
    const float* feat_l = (const float*)d_in[0];
    const float* feat_n = (const float*)d_in[1];
    const float* W0_l2n = (const float*)d_in[2];
    const float* b0_l2n = (const float*)d_in[3];
    const float* W0_n2l = (const float*)d_in[4];
    const float* b0_n2l = (const float*)d_in[5];
    const float* W_l2n  = (const float*)d_in[6];
    const float* b_l2n  = (const float*)d_in[7];
    const float* W_n2l  = (const float*)d_in[8];
    const float* b_n2l  = (const float*)d_in[9];
    const float* ln_g_n = (const float*)d_in[10];
    const float* ln_b_n = (const float*)d_in[11];
    const float* ln_g_l = (const float*)d_in[12];
    const float* ln_b_l = (const float*)d_in[13];
    const float* W_fc   = (const float*)d_in[14];
    const float* b_fc   = (const float*)d_in[15];
    const float* W_out  = (const float*)d_in[16];
    const float* b_out  = (const float*)d_in[17];
    const int* src_l2n  = (const int*)d_in[18];
    const int* dst_l2n  = (const int*)d_in[19];
    const int* src_n2l  = (const int*)d_in[20];
    const int* dst_n2l  = (const int*)d_in[21];
    const int* gid_l    = (const int*)d_in[22];
    const int* gid_n    = (const int*)d_in[23];

    // ---- workspace ----
    char* ws = (char*)d_ws;
    size_t off = 0;
    auto take = [&](size_t bytes) { char* p = ws + off; off = align_up(off + bytes, 256); return p; };
    int*   icnt        = (int*)take(200000 * 4);
    float* rsq         = (float*)take(200000 * 4);
    int*   beg_l2n     = (int*)take(NN * 4);
    int*   beg_n2l     = (int*)take(NL * 4);
    int*   ctrs        = (int*)take(2 * 4);
    int*   pos_l2n     = (int*)take((size_t)NE * 4);
    int*   pos_n2l     = (int*)take((size_t)NE * 4);
    int*   col_l2n     = (int*)take((size_t)NE * 4);
    int*   col_n2l     = (int*)take((size_t)NE * 4);
    u16*   Wt0_l2n     = (u16*)take(128 * 320 * 2);
    u16*   Wt0_n2l     = (u16*)take(128 * 224 * 2);
    u16*   Wt_l2n0     = (u16*)take(128 * 128 * 2);
    u16*   Wt_l2n1     = (u16*)take(128 * 128 * 2);
    u16*   Wt_n2l0     = (u16*)take(128 * 128 * 2);
    u16*   Wt_n2l1     = (u16*)take(128 * 128 * 2);
    u16*   xs0         = (u16*)take((size_t)MPAD * 128 * 2);   // later agg0
    u16*   xs1         = (u16*)take((size_t)MPAD * 128 * 2);   // later agg1
    u16*   hl          = (u16*)take((size_t)MPAD * 128 * 2);
    u16*   hn          = (u16*)take((size_t)MPAD * 128 * 2);
    float* part_l      = (float*)take((size_t)NG * PSPLIT * 128 * 4);
    float* part_n      = (float*)take((size_t)NG * PSPLIT * 128 * 4);
    u16* agg0 = xs0;
    u16* agg1 = xs1;

    int* icnt_src_l2n = icnt;
    int* icnt_dst_l2n = icnt + NL;
    int* icnt_src_n2l = icnt + NL + NN;
    int* icnt_dst_n2l = icnt + NL + 2 * NN;
    float* rsq_src_l2n = rsq;
    float* rsq_dst_l2n = rsq + NL;
    float* rsq_src_n2l = rsq + NL + NN;
    float* rsq_dst_n2l = rsq + NL + 2 * NN;

    const int TB = 256;
    const int gemm_grid = MPAD / 64;              // 782
    const int gath_grid = (NL + 3) / 4;
    const int edge_grid = (NE + TB - 1) / TB;
    const int alloc_grid = 2 * ((NL + 255) / 256);

    // ---- histograms + positions (half the atomics of R6) ----
    hipMemsetAsync(icnt, 0, 200000 * sizeof(int), stream);
    hipMemsetAsync(ctrs, 0, 2 * sizeof(int), stream);
    deg_pos<<<edge_grid, TB, 0, stream>>>(src_l2n, dst_l2n, icnt_src_l2n, icnt_dst_l2n, pos_l2n,
                                          src_n2l, dst_n2l, icnt_src_n2l, icnt_dst_n2l, pos_n2l, NE);
    rsq_kernel<<<(200000 + TB - 1) / TB, TB, 0, stream>>>(icnt, rsq, 200000);
    alloc_beg<<<alloc_grid, TB, 0, stream>>>(icnt_dst_l2n, beg_l2n, NN,
                                             icnt_dst_n2l, beg_n2l, NL, ctrs);
    fill_csr<<<edge_grid, TB, 0, stream>>>(src_l2n, dst_l2n, pos_l2n, beg_l2n, col_l2n, NE);
    fill_csr<<<edge_grid, TB, 0, stream>>>(src_n2l, dst_n2l, pos_n2l, beg_n2l, col_n2l, NE);

    // ---- weight conversion ----
    conv_wt<<<(128 * 320 + TB - 1) / TB, TB, 0, stream>>>(W0_l2n, Wt0_l2n, 300, 320);
    conv_wt<<<(128 * 224 + TB - 1) / TB, TB, 0, stream>>>(W0_n2l, Wt0_n2l, 200, 224);
    conv_wt<<<(128 * 128 + TB - 1) / TB, TB, 0, stream>>>(W_l2n,             Wt_l2n0, 128, 128);
    conv_wt<<<(128 * 128 + TB - 1) / TB, TB, 0, stream>>>(W_l2n + 128 * 128, Wt_l2n1, 128, 128);
    conv_wt<<<(128 * 128 + TB - 1) / TB, TB, 0, stream>>>(W_n2l,             Wt_n2l0, 128, 128);
    conv_wt<<<(128 * 128 + TB - 1) / TB, TB, 0, stream>>>(W_n2l + 128 * 128, Wt_n2l1, 128, 128);

    // ---- layer 0: project fp32 feats directly (fused cvt staging), then gather+LN ----
    mfma_gemm<320, false, true><<<gemm_grid, TB, 0, stream>>>(feat_l, 300, NL, Wt0_l2n,
                                                              rsq_src_l2n, nullptr, nullptr,
                                                              nullptr, xs0);
    mfma_gemm<224, false, true><<<gemm_grid, TB, 0, stream>>>(feat_n, 200, NN, Wt0_n2l,
                                                              rsq_src_n2l, nullptr, nullptr,
                                                              nullptr, xs1);
    gather_ln<<<gath_grid, TB, 0, stream>>>(xs0, beg_l2n, icnt_dst_l2n, col_l2n, rsq_dst_l2n,
                                            b0_l2n, ln_g_n, ln_b_n, hn, NN);
    gather_ln<<<gath_grid, TB, 0, stream>>>(xs1, beg_n2l, icnt_dst_n2l, col_n2l, rsq_dst_n2l,
                                            b0_n2l, ln_g_l, ln_b_l, hl, NL);

    // ---- layers 1,2: gather-first (bf16), GEMM with fused LN+ELU ----
    const u16* Wls[2] = {Wt_l2n0, Wt_l2n1};
    const u16* Wns[2] = {Wt_n2l0, Wt_n2l1};
    for (int i = 1; i <= 2; ++i) {
        const float* bl = b_l2n + (size_t)(i - 1) * DD;
        const float* bn = b_n2l + (size_t)(i - 1) * DD;
        gather_scale<<<gath_grid, TB, 0, stream>>>(hl, beg_l2n, icnt_dst_l2n, col_l2n,
                                                   rsq_src_l2n, agg0, NN);
        gather_scale<<<gath_grid, TB, 0, stream>>>(hn, beg_n2l, icnt_dst_n2l, col_n2l,
                                                   rsq_src_n2l, agg1, NL);
        mfma_gemm<128, true, false><<<gemm_grid, TB, 0, stream>>>(agg0, 128, NN, Wls[i - 1],
                                                                  rsq_dst_l2n, bl,
                                                                  ln_g_n + (size_t)i * DD,
                                                                  ln_b_n + (size_t)i * DD, hn);
        mfma_gemm<128, true, false><<<gemm_grid, TB, 0, stream>>>(agg1, 128, NL, Wns[i - 1],
                                                                  rsq_dst_n2l, bn,
                                                                  ln_g_l + (size_t)i * DD,
                                                                  ln_b_l + (size_t)i * DD, hl);
    }

    // ---- pooling + head ----
    pool_partial<<<NG * PSPLIT, 128, 0, stream>>>(hl, gid_l, part_l, NL);
    pool_partial<<<NG * PSPLIT, 128, 0, stream>>>(hn, gid_n, part_n, NN);
    head_kernel<<<NG, 128, 0, stream>>>(part_l, part_n, gid_l, gid_n,
                                        W_fc, b_fc, W_out, b_out, (float*)d_out);
}

// Round 8
// 499.216 us; speedup vs baseline: 15.2120x; 1.0011x over previous
//
#include <hip/hip_runtime.h>
#include <math.h>

#define NL 50000
#define NN 50000
#define NE 600000
#define NG 64
#define DD 128
#define MPAD 50048
#define PSPLIT 8

typedef unsigned short u16;
typedef unsigned int u32;
using bf16x8 = __attribute__((ext_vector_type(8))) short;
using f32x4  = __attribute__((ext_vector_type(4))) float;

__device__ __forceinline__ u16 f2bf(float x) {
    u32 u = __float_as_uint(x);
    u32 r = (u + 0x7fffu + ((u >> 16) & 1u)) >> 16;
    return (u16)r;
}
__device__ __forceinline__ float bf2f(u16 x) {
    return __uint_as_float(((u32)x) << 16);
}
__device__ __forceinline__ void gload16(const void* g, void* l) {
    __builtin_amdgcn_global_load_lds((const __attribute__((address_space(1))) void*)g,
                                     (__attribute__((address_space(3))) void*)l, 16, 0, 0);
}
__device__ __forceinline__ u32 cvtpk(float lo, float hi) {
    u32 r;
    asm("v_cvt_pk_bf16_f32 %0, %1, %2" : "=v"(r) : "v"(lo), "v"(hi));
    return r;
}

// ---------------- fused histograms + position assignment (both directions) ----------------
__global__ __launch_bounds__(256) void deg_pos(const int* __restrict__ s0a, const int* __restrict__ d0a,
                                               int* __restrict__ hs0, int* __restrict__ hd0,
                                               int* __restrict__ pos0,
                                               const int* __restrict__ s1a, const int* __restrict__ d1a,
                                               int* __restrict__ hs1, int* __restrict__ hd1,
                                               int* __restrict__ pos1, int E) {
    int e = blockIdx.x * blockDim.x + threadIdx.x;
    if (e < E) {
        atomicAdd(&hs0[s0a[e]], 1);
        pos0[e] = atomicAdd(&hd0[d0a[e]], 1);
        atomicAdd(&hs1[s1a[e]], 1);
        pos1[e] = atomicAdd(&hd1[d1a[e]], 1);
    }
}

__global__ void rsq_kernel(const int* __restrict__ cnt, float* __restrict__ out, int n) {
    int i = blockIdx.x * blockDim.x + threadIdx.x;
    if (i < n) out[i] = rsqrtf(fmaxf((float)cnt[i], 1.0f));
}

// ---------------- order-free segment allocation (one atomic per block) ----------------
__global__ __launch_bounds__(256) void alloc_beg(const int* __restrict__ cntA, int* __restrict__ begA, int nA,
                                                 const int* __restrict__ cntB, int* __restrict__ begB, int nB,
                                                 int* __restrict__ ctrs) {
    int nblkA = (nA + 255) >> 8;
    const int* cnt; int* beg; int* ctr; int base_i; int n;
    if ((int)blockIdx.x < nblkA) { cnt = cntA; beg = begA; ctr = ctrs;     base_i = blockIdx.x * 256;           n = nA; }
    else                         { cnt = cntB; beg = begB; ctr = ctrs + 1; base_i = (blockIdx.x - nblkA) * 256; n = nB; }
    int i = base_i + threadIdx.x;
    int v = (i < n) ? cnt[i] : 0;
    __shared__ int sm[256];
    __shared__ int sbase;
    sm[threadIdx.x] = v;
    __syncthreads();
    for (int off = 1; off < 256; off <<= 1) {
        int t = (threadIdx.x >= (unsigned)off) ? sm[threadIdx.x - off] : 0;
        __syncthreads();
        sm[threadIdx.x] += t;
        __syncthreads();
    }
    if (threadIdx.x == 255) sbase = atomicAdd(ctr, sm[255]);
    __syncthreads();
    if (i < n) beg[i] = sbase + sm[threadIdx.x] - v;
}

// ---------------- CSR fill, atomic-free (uses precomputed pos) ----------------
__global__ void fill_csr(const int* __restrict__ src, const int* __restrict__ dst,
                         const int* __restrict__ pos, const int* __restrict__ beg,
                         int* __restrict__ col, int E) {
    int e = blockIdx.x * blockDim.x + threadIdx.x;
    if (e < E) col[beg[dst[e]] + pos[e]] = src[e];
}

// ---------------- W -> bf16, transposed [n][k], K zero-padded to KP ----------------
__global__ void conv_wt(const float* __restrict__ W, u16* __restrict__ Wt, int K, int KP) {
    int i = blockIdx.x * blockDim.x + threadIdx.x;
    if (i >= 128 * KP) return;
    int n = i / KP, k = i % KP;
    float v = (k < K) ? W[(size_t)k * 128 + n] : 0.0f;
    Wt[i] = f2bf(v);
}

// ---------------- MFMA GEMM ----------------
// BM=64, BN=128, 4 waves (2x2), 16x16x32 bf16 MFMA, BK=32, double-buffered LDS.
// AF32=true : A fp32 [M][K] staged via float4 + cvt_pk + ds_write (K runtime, KP compile pad)
// AF32=false: A bf16 [MPAD][KP] staged via global_load_lds
// LN=false: out = f2bf(rsq[m]*raw);  LN=true: out = f2bf(elu(ln(rsq[m]*raw + bias)))
template<int KP, bool LN, bool AF32>
__global__ __launch_bounds__(256) void mfma_gemm(const void* __restrict__ Av, int K, int M,
                                                 const u16* __restrict__ Wt,
                                                 const float* __restrict__ rsq,
                                                 const float* __restrict__ bias,
                                                 const float* __restrict__ gw,
                                                 const float* __restrict__ bln,
                                                 u16* __restrict__ out) {
    constexpr int NT = KP / 32;
    __shared__ __align__(16) u16 As[2][64 * 32];
    __shared__ __align__(16) u16 Bs[2][128 * 32];
    __shared__ float rs[2][64][2];
    const int t    = threadIdx.x;
    const int lane = t & 63;
    const int wid  = t >> 6;
    const int wr   = wid >> 1;
    const int wc   = wid & 1;
    const int brow = blockIdx.x * 64;
    const int l15  = lane & 15;
    const int kg   = lane >> 4;

    f32x4 acc[2][4];
#pragma unroll
    for (int mi = 0; mi < 2; ++mi)
#pragma unroll
        for (int ni = 0; ni < 4; ++ni) acc[mi][ni] = (f32x4){0.f, 0.f, 0.f, 0.f};

    // A addressing: LDS[row][chunk] = src[row][chunk ^ key(row)], key = (row>>1)&3
    const int ar   = t >> 2;
    const int ac   = t & 3;
    const int akey = (ar >> 1) & 3;
    const int grow = brow + ar;
    // B addressing
    const int bn0 = t >> 2;
    const int bn1 = (256 + t) >> 2;
    const u16* b_src0 = Wt + (size_t)bn0 * KP + ((t & 3) ^ ((bn0 >> 1) & 3)) * 8;
    const u16* b_src1 = Wt + (size_t)bn1 * KP + ((t & 3) ^ ((bn1 >> 1) & 3)) * 8;
    const u16* a_src = nullptr;
    if constexpr (!AF32) a_src = (const u16*)Av + (size_t)grow * KP + (ac ^ akey) * 8;

#define STAGE_B(kt, buf)                                                          \
    do {                                                                          \
        gload16(b_src0 + (kt) * 32, (char*)&Bs[buf][0] + wid * 1024);             \
        gload16(b_src1 + (kt) * 32, (char*)&Bs[buf][0] + 4096 + wid * 1024);      \
    } while (0)
#define STAGE_A16(kt, buf)                                                        \
    gload16(a_src + (kt) * 32, (char*)&As[buf][0] + wid * 1024)

    struct A8 { float4 x, y; };
    auto loadA = [&](int kt) -> A8 {
        const float* A = (const float*)Av;
        int kbase = kt * 32 + (ac ^ akey) * 8;
        const float* p = A + (size_t)grow * K + kbase;
        A8 r;
        bool rowok = grow < M;
        r.x = (rowok && kbase + 4 <= K) ? *(const float4*)p       : make_float4(0.f, 0.f, 0.f, 0.f);
        r.y = (rowok && kbase + 8 <= K) ? *(const float4*)(p + 4) : make_float4(0.f, 0.f, 0.f, 0.f);
        return r;
    };
    auto writeA = [&](int buf, const A8& r) {
        uint4 w = make_uint4(cvtpk(r.x.x, r.x.y), cvtpk(r.x.z, r.x.w),
                             cvtpk(r.y.x, r.y.y), cvtpk(r.y.z, r.y.w));
        *(uint4*)&As[buf][ar * 32 + ac * 8] = w;
    };

    A8 rnext{};
    if constexpr (AF32) {
        A8 r0 = loadA(0);
        if (NT > 1) rnext = loadA(1);
        writeA(0, r0);
        STAGE_B(0, 0);
    } else {
        STAGE_A16(0, 0);
        STAGE_B(0, 0);
    }
    __syncthreads();

    const int fo = (kg ^ ((l15 >> 1) & 3)) * 8;
#pragma unroll
    for (int kt = 0; kt < NT; ++kt) {
        const int cur = kt & 1;
        if (kt + 1 < NT) {
            if constexpr (AF32) {
                writeA(cur ^ 1, rnext);
                STAGE_B(kt + 1, cur ^ 1);
                if (kt + 2 < NT) rnext = loadA(kt + 2);
            } else {
                STAGE_A16(kt + 1, cur ^ 1);
                STAGE_B(kt + 1, cur ^ 1);
            }
        }
        bf16x8 a0 = *(const bf16x8*)&As[cur][(wr * 32 +  0 + l15) * 32 + fo];
        bf16x8 a1 = *(const bf16x8*)&As[cur][(wr * 32 + 16 + l15) * 32 + fo];
#pragma unroll
        for (int ni = 0; ni < 4; ++ni) {
            bf16x8 b = *(const bf16x8*)&Bs[cur][(wc * 64 + ni * 16 + l15) * 32 + fo];
            acc[0][ni] = __builtin_amdgcn_mfma_f32_16x16x32_bf16(a0, b, acc[0][ni], 0, 0, 0);
            acc[1][ni] = __builtin_amdgcn_mfma_f32_16x16x32_bf16(a1, b, acc[1][ni], 0, 0, 0);
        }
        __syncthreads();
    }
#undef STAGE_B
#undef STAGE_A16

    if constexpr (!LN) {
#pragma unroll
        for (int mi = 0; mi < 2; ++mi)
#pragma unroll
            for (int r = 0; r < 4; ++r) {
                int go = brow + wr * 32 + mi * 16 + kg * 4 + r;
                if (go < M) {
                    float s = rsq[go];
#pragma unroll
                    for (int ni = 0; ni < 4; ++ni)
                        out[(size_t)go * 128 + wc * 64 + ni * 16 + l15] = f2bf(acc[mi][ni][r] * s);
                }
            }
    } else {
        float b4[4], g4[4], bl4[4];
#pragma unroll
        for (int ni = 0; ni < 4; ++ni) {
            int c = wc * 64 + ni * 16 + l15;
            b4[ni] = bias[c]; g4[ni] = gw[c]; bl4[ni] = bln[c];
        }
        float rsv[2][4];
#pragma unroll
        for (int mi = 0; mi < 2; ++mi)
#pragma unroll
            for (int r = 0; r < 4; ++r) {
                int go = brow + wr * 32 + mi * 16 + kg * 4 + r;
                rsv[mi][r] = (go < M) ? rsq[go] : 0.0f;
            }
#pragma unroll
        for (int mi = 0; mi < 2; ++mi)
#pragma unroll
            for (int r = 0; r < 4; ++r) {
                int lrow = wr * 32 + mi * 16 + kg * 4 + r;
                float s1 = 0.f, s2 = 0.f;
#pragma unroll
                for (int ni = 0; ni < 4; ++ni) {
                    float xv = acc[mi][ni][r] * rsv[mi][r] + b4[ni];
                    s1 += xv; s2 += xv * xv;
                }
#pragma unroll
                for (int m = 1; m < 16; m <<= 1) {
                    s1 += __shfl_xor(s1, m, 64);
                    s2 += __shfl_xor(s2, m, 64);
                }
                if (l15 == 0) { rs[0][lrow][wc] = s1; rs[1][lrow][wc] = s2; }
            }
        __syncthreads();
#pragma unroll
        for (int mi = 0; mi < 2; ++mi)
#pragma unroll
            for (int r = 0; r < 4; ++r) {
                int lrow = wr * 32 + mi * 16 + kg * 4 + r;
                int go = brow + lrow;
                if (go < M) {
                    float S1 = rs[0][lrow][0] + rs[0][lrow][1];
                    float S2 = rs[1][lrow][0] + rs[1][lrow][1];
                    float mu = S1 * (1.0f / 128.0f);
                    float var = S2 * (1.0f / 128.0f) - mu * mu;
                    float rstd = rsqrtf(fmaxf(var, 0.0f) + 1e-5f);
#pragma unroll
                    for (int ni = 0; ni < 4; ++ni) {
                        float xv = acc[mi][ni][r] * rsv[mi][r] + b4[ni];
                        float y = (xv - mu) * rstd * g4[ni] + bl4[ni];
                        y = (y > 0.0f) ? y : expm1f(y);
                        out[(size_t)go * 128 + wc * 64 + ni * 16 + l15] = f2bf(y);
                    }
                }
            }
    }
}

// ---------------- layer-0 gather (bf16 xs, unit weight) + LN + ELU -> bf16 ----------------
__global__ __launch_bounds__(256) void gather_ln(const u16* __restrict__ xs,
                                                 const int* __restrict__ beg,
                                                 const int* __restrict__ cnt,
                                                 const int* __restrict__ col,
                                                 const float* __restrict__ rsq_in,
                                                 const float* __restrict__ bias,
                                                 const float* __restrict__ g,
                                                 const float* __restrict__ bln,
                                                 u16* __restrict__ out, int M) {
    int row  = blockIdx.x * 4 + (threadIdx.x >> 6);
    int lane = threadIdx.x & 63;
    if (row >= M) return;
    int b = beg[row], n = cnt[row];
    const u32* x32 = (const u32*)xs;

    float a0 = 0.f, a1 = 0.f, c0 = 0.f, c1 = 0.f;
    int e = 0;
    for (; e + 3 < n; e += 4) {
        int s0 = col[b + e], s1 = col[b + e + 1], s2 = col[b + e + 2], s3 = col[b + e + 3];
        u32 p0 = x32[(size_t)s0 * 64 + lane];
        u32 p1 = x32[(size_t)s1 * 64 + lane];
        u32 p2 = x32[(size_t)s2 * 64 + lane];
        u32 p3 = x32[(size_t)s3 * 64 + lane];
        a0 += bf2f((u16)p0) + bf2f((u16)p1);
        a1 += bf2f((u16)(p0 >> 16)) + bf2f((u16)(p1 >> 16));
        c0 += bf2f((u16)p2) + bf2f((u16)p3);
        c1 += bf2f((u16)(p2 >> 16)) + bf2f((u16)(p3 >> 16));
    }
    for (; e < n; ++e) {
        u32 p = x32[(size_t)col[b + e] * 64 + lane];
        a0 += bf2f((u16)p);
        a1 += bf2f((u16)(p >> 16));
    }
    a0 += c0; a1 += c1;

    float sc = rsq_in[row];
    float2 bv = *(const float2*)&bias[lane * 2];
    float x0 = a0 * sc + bv.x;
    float x1 = a1 * sc + bv.y;

    float sum = x0 + x1;
#pragma unroll
    for (int m = 1; m < 64; m <<= 1) sum += __shfl_xor(sum, m, 64);
    float mu = sum * (1.0f / 128.0f);

    float d0 = x0 - mu, d1 = x1 - mu;
    float ss = d0 * d0 + d1 * d1;
#pragma unroll
    for (int m = 1; m < 64; m <<= 1) ss += __shfl_xor(ss, m, 64);
    float rstd = rsqrtf(ss * (1.0f / 128.0f) + 1e-5f);

    float2 gv = *(const float2*)&g[lane * 2];
    float2 bl = *(const float2*)&bln[lane * 2];
    float y0 = d0 * rstd * gv.x + bl.x;
    float y1 = d1 * rstd * gv.y + bl.y;
    y0 = (y0 > 0.0f) ? y0 : expm1f(y0);
    y1 = (y1 > 0.0f) ? y1 : expm1f(y1);
    ((u32*)out)[(size_t)row * 64 + lane] = (u32)f2bf(y0) | ((u32)f2bf(y1) << 16);
}

// ---------------- layers 1-2 gather: agg[dst] = bf16( sum rsq_src[s]*h[s] ) ----------------
__global__ __launch_bounds__(256) void gather_scale(const u16* __restrict__ h,
                                                    const int* __restrict__ beg,
                                                    const int* __restrict__ cnt,
                                                    const int* __restrict__ col,
                                                    const float* __restrict__ rsq_src,
                                                    u16* __restrict__ agg, int M) {
    int row  = blockIdx.x * 4 + (threadIdx.x >> 6);
    int lane = threadIdx.x & 63;
    if (row >= M) return;
    int b = beg[row], n = cnt[row];
    const u32* h32 = (const u32*)h;

    float a0 = 0.f, a1 = 0.f, c0 = 0.f, c1 = 0.f;
    int e = 0;
    for (; e + 3 < n; e += 4) {
        int s0 = col[b + e], s1 = col[b + e + 1], s2 = col[b + e + 2], s3 = col[b + e + 3];
        float r0 = rsq_src[s0], r1 = rsq_src[s1], r2 = rsq_src[s2], r3 = rsq_src[s3];
        u32 p0 = h32[(size_t)s0 * 64 + lane];
        u32 p1 = h32[(size_t)s1 * 64 + lane];
        u32 p2 = h32[(size_t)s2 * 64 + lane];
        u32 p3 = h32[(size_t)s3 * 64 + lane];
        a0 = fmaf(r0, bf2f((u16)p0), a0); a1 = fmaf(r0, bf2f((u16)(p0 >> 16)), a1);
        c0 = fmaf(r1, bf2f((u16)p1), c0); c1 = fmaf(r1, bf2f((u16)(p1 >> 16)), c1);
        a0 = fmaf(r2, bf2f((u16)p2), a0); a1 = fmaf(r2, bf2f((u16)(p2 >> 16)), a1);
        c0 = fmaf(r3, bf2f((u16)p3), c0); c1 = fmaf(r3, bf2f((u16)(p3 >> 16)), c1);
    }
    for (; e < n; ++e) {
        int s = col[b + e];
        float r = rsq_src[s];
        u32 p = h32[(size_t)s * 64 + lane];
        a0 = fmaf(r, bf2f((u16)p), a0);
        a1 = fmaf(r, bf2f((u16)(p >> 16)), a1);
    }
    a0 += c0; a1 += c1;
    ((u32*)agg)[(size_t)row * 64 + lane] = (u32)f2bf(a0) | ((u32)f2bf(a1) << 16);
}

// ---------------- segmented pooling from bf16 h ----------------
__global__ __launch_bounds__(128) void pool_partial(const u16* __restrict__ h,
                                                    const int* __restrict__ gid,
                                                    float* __restrict__ partial, int M) {
    int g = blockIdx.x / PSPLIT;
    int p = blockIdx.x % PSPLIT;
    int j = threadIdx.x;
    __shared__ int bounds[2];
    if (j < 2) {
        int target = g + j;
        int lo = 0, hi = M;
        while (lo < hi) { int mid = (lo + hi) >> 1; if (gid[mid] < target) lo = mid + 1; else hi = mid; }
        bounds[j] = lo;
    }
    __syncthreads();
    int beg = bounds[0], end = bounds[1];
    int len = end - beg;
    int chunk = (len + PSPLIT - 1) / PSPLIT;
    int s0i = beg + p * chunk;
    int e0i = min(s0i + chunk, end);

    float s0 = 0.f, s1 = 0.f, s2 = 0.f, s3 = 0.f;
    int i = s0i;
    for (; i + 3 < e0i; i += 4) {
        s0 += bf2f(h[(size_t)(i + 0) * 128 + j]);
        s1 += bf2f(h[(size_t)(i + 1) * 128 + j]);
        s2 += bf2f(h[(size_t)(i + 2) * 128 + j]);
        s3 += bf2f(h[(size_t)(i + 3) * 128 + j]);
    }
    for (; i < e0i; ++i) s0 += bf2f(h[(size_t)i * 128 + j]);
    partial[(size_t)(g * PSPLIT + p) * 128 + j] = (s0 + s1) + (s2 + s3);
}

// ---------------- head ----------------
__global__ __launch_bounds__(128) void head_kernel(const float* __restrict__ part_l,
                                                   const float* __restrict__ part_n,
                                                   const int* __restrict__ gid_l,
                                                   const int* __restrict__ gid_n,
                                                   const float* __restrict__ W_fc,
                                                   const float* __restrict__ b_fc,
                                                   const float* __restrict__ W_out,
                                                   const float* __restrict__ b_out,
                                                   float* __restrict__ out) {
    int g = blockIdx.x;
    int j = threadIdx.x;
    __shared__ float hg[128];
    __shared__ float red[2];
    __shared__ int bounds[4];
    if (j < 4) {
        const int* gid = (j < 2) ? gid_l : gid_n;
        int target = g + (j & 1);
        int lo = 0, hi = 50000;
        while (lo < hi) { int mid = (lo + hi) >> 1; if (gid[mid] < target) lo = mid + 1; else hi = mid; }
        bounds[j] = lo;
    }
    __syncthreads();
    float cl = fmaxf((float)(bounds[1] - bounds[0]), 1.0f);
    float cn = fmaxf((float)(bounds[3] - bounds[2]), 1.0f);
    float sl = 0.f, sn = 0.f;
#pragma unroll
    for (int p = 0; p < PSPLIT; ++p) {
        sl += part_l[(size_t)(g * PSPLIT + p) * 128 + j];
        sn += part_n[(size_t)(g * PSPLIT + p) * 128 + j];
    }
    hg[j] = sl / cl + sn / cn;
    __syncthreads();
    float acc = b_fc[j];
#pragma unroll 8
    for (int k = 0; k < 128; ++k) acc = fmaf(hg[k], W_fc[k * 128 + j], acc);
    float fc = fmaxf(acc, 0.0f);
    float v = fc * W_out[j];
#pragma unroll
    for (int m = 1; m < 64; m <<= 1) v += __shfl_xor(v, m, 64);
    if ((j & 63) == 0) red[j >> 6] = v;
    __syncthreads();
    if (j == 0) out[g] = red[0] + red[1] + b_out[0];
}

static inline size_t align_up(size_t x, size_t a) { return (x + a - 1) & ~(a - 1); }

extern "C" void kernel_launch(void* const* d_in, const int* in_sizes, int n_in,
                              void* d_out, int out_size, void* d_ws, size_t ws_size,
                              hipStream_t stream) {
    const float* feat_l = (const float*)d_in[0];
    const float* feat_n = (const float*)d_in[1];
    const float* W0_l2n = (const float*)d_in[2];
    const float* b0_l2n = (const float*)d_in[3];
    const float* W0_n2l = (const float*)d_in[4];
    const float* b0_n2l = (const float*)d_in[5];
    const float* W_l2n  = (const float*)d_in[6];
    const float* b_l2n  = (const float*)d_in[7];
    const float* W_n2l  = (const float*)d_in[8];
    const float* b_n2l  = (const float*)d_in[9];
    const float* ln_g_n = (const float*)d_in[10];
    const float* ln_b_n = (const float*)d_in[11];
    const float* ln_g_l = (const float*)d_in[12];
    const float* ln_b_l = (const float*)d_in[13];
    const float* W_fc   = (const float*)d_in[14];
    const float* b_fc   = (const float*)d_in[15];
    const float* W_out  = (const float*)d_in[16];
    const float* b_out  = (const float*)d_in[17];
    const int* src_l2n  = (const int*)d_in[18];
    const int* dst_l2n  = (const int*)d_in[19];
    const int* src_n2l  = (const int*)d_in[20];
    const int* dst_n2l  = (const int*)d_in[21];
    const int* gid_l    = (const int*)d_in[22];
    const int* gid_n    = (const int*)d_in[23];

    // ---- workspace ----
    char* ws = (char*)d_ws;
    size_t off = 0;
    auto take = [&](size_t bytes) { char* p = ws + off; off = align_up(off + bytes, 256); return p; };
    int*   icnt        = (int*)take(200000 * 4);
    float* rsq         = (float*)take(200000 * 4);
    int*   beg_l2n     = (int*)take(NN * 4);
    int*   beg_n2l     = (int*)take(NL * 4);
    int*   ctrs        = (int*)take(2 * 4);
    int*   pos_l2n     = (int*)take((size_t)NE * 4);
    int*   pos_n2l     = (int*)take((size_t)NE * 4);
    int*   col_l2n     = (int*)take((size_t)NE * 4);
    int*   col_n2l     = (int*)take((size_t)NE * 4);
    u16*   Wt0_l2n     = (u16*)take(128 * 320 * 2);
    u16*   Wt0_n2l     = (u16*)take(128 * 224 * 2);
    u16*   Wt_l2n0     = (u16*)take(128 * 128 * 2);
    u16*   Wt_l2n1     = (u16*)take(128 * 128 * 2);
    u16*   Wt_n2l0     = (u16*)take(128 * 128 * 2);
    u16*   Wt_n2l1     = (u16*)take(128 * 128 * 2);
    u16*   xs0         = (u16*)take((size_t)MPAD * 128 * 2);   // later agg0
    u16*   xs1         = (u16*)take((size_t)MPAD * 128 * 2);   // later agg1
    u16*   hl          = (u16*)take((size_t)MPAD * 128 * 2);
    u16*   hn          = (u16*)take((size_t)MPAD * 128 * 2);
    float* part_l      = (float*)take((size_t)NG * PSPLIT * 128 * 4);
    float* part_n      = (float*)take((size_t)NG * PSPLIT * 128 * 4);
    u16* agg0 = xs0;
    u16* agg1 = xs1;

    int* icnt_src_l2n = icnt;
    int* icnt_dst_l2n = icnt + NL;
    int* icnt_src_n2l = icnt + NL + NN;
    int* icnt_dst_n2l = icnt + NL + 2 * NN;
    float* rsq_src_l2n = rsq;
    float* rsq_dst_l2n = rsq + NL;
    float* rsq_src_n2l = rsq + NL + NN;
    float* rsq_dst_n2l = rsq + NL + 2 * NN;

    const int TB = 256;
    const int gemm_grid = MPAD / 64;              // 782
    const int gath_grid = (NL + 3) / 4;
    const int edge_grid = (NE + TB - 1) / TB;
    const int alloc_grid = 2 * ((NL + 255) / 256);

    // ---- histograms + positions (half the atomics of R6) ----
    hipMemsetAsync(icnt, 0, 200000 * sizeof(int), stream);
    hipMemsetAsync(ctrs, 0, 2 * sizeof(int), stream);
    deg_pos<<<edge_grid, TB, 0, stream>>>(src_l2n, dst_l2n, icnt_src_l2n, icnt_dst_l2n, pos_l2n,
                                          src_n2l, dst_n2l, icnt_src_n2l, icnt_dst_n2l, pos_n2l, NE);
    rsq_kernel<<<(200000 + TB - 1) / TB, TB, 0, stream>>>(icnt, rsq, 200000);
    alloc_beg<<<alloc_grid, TB, 0, stream>>>(icnt_dst_l2n, beg_l2n, NN,
                                             icnt_dst_n2l, beg_n2l, NL, ctrs);
    fill_csr<<<edge_grid, TB, 0, stream>>>(src_l2n, dst_l2n, pos_l2n, beg_l2n, col_l2n, NE);
    fill_csr<<<edge_grid, TB, 0, stream>>>(src_n2l, dst_n2l, pos_n2l, beg_n2l, col_n2l, NE);

    // ---- weight conversion ----
    conv_wt<<<(128 * 320 + TB - 1) / TB, TB, 0, stream>>>(W0_l2n, Wt0_l2n, 300, 320);
    conv_wt<<<(128 * 224 + TB - 1) / TB, TB, 0, stream>>>(W0_n2l, Wt0_n2l, 200, 224);
    conv_wt<<<(128 * 128 + TB - 1) / TB, TB, 0, stream>>>(W_l2n,             Wt_l2n0, 128, 128);
    conv_wt<<<(128 * 128 + TB - 1) / TB, TB, 0, stream>>>(W_l2n + 128 * 128, Wt_l2n1, 128, 128);
    conv_wt<<<(128 * 128 + TB - 1) / TB, TB, 0, stream>>>(W_n2l,             Wt_n2l0, 128, 128);
    conv_wt<<<(128 * 128 + TB - 1) / TB, TB, 0, stream>>>(W_n2l + 128 * 128, Wt_n2l1, 128, 128);

    // ---- layer 0: project fp32 feats directly (fused cvt staging), then gather+LN ----
    mfma_gemm<320, false, true><<<gemm_grid, TB, 0, stream>>>(feat_l, 300, NL, Wt0_l2n,
                                                              rsq_src_l2n, nullptr, nullptr,
                                                              nullptr, xs0);
    mfma_gemm<224, false, true><<<gemm_grid, TB, 0, stream>>>(feat_n, 200, NN, Wt0_n2l,
                                                              rsq_src_n2l, nullptr, nullptr,
                                                              nullptr, xs1);
    gather_ln<<<gath_grid, TB, 0, stream>>>(xs0, beg_l2n, icnt_dst_l2n, col_l2n, rsq_dst_l2n,
                                            b0_l2n, ln_g_n, ln_b_n, hn, NN);
    gather_ln<<<gath_grid, TB, 0, stream>>>(xs1, beg_n2l, icnt_dst_n2l, col_n2l, rsq_dst_n2l,
                                            b0_n2l, ln_g_l, ln_b_l, hl, NL);

    // ---- layers 1,2: gather-first (bf16), GEMM with fused LN+ELU ----
    const u16* Wls[2] = {Wt_l2n0, Wt_l2n1};
    const u16* Wns[2] = {Wt_n2l0, Wt_n2l1};
    for (int i = 1; i <= 2; ++i) {
        const float* bl = b_l2n + (size_t)(i - 1) * DD;
        const float* bn = b_n2l + (size_t)(i - 1) * DD;
        gather_scale<<<gath_grid, TB, 0, stream>>>(hl, beg_l2n, icnt_dst_l2n, col_l2n,
                                                   rsq_src_l2n, agg0, NN);
        gather_scale<<<gath_grid, TB, 0, stream>>>(hn, beg_n2l, icnt_dst_n2l, col_n2l,
                                                   rsq_src_n2l, agg1, NL);
        mfma_gemm<128, true, false><<<gemm_grid, TB, 0, stream>>>(agg0, 128, NN, Wls[i - 1],
                                                                  rsq_dst_l2n, bl,
                                                                  ln_g_n + (size_t)i * DD,
                                                                  ln_b_n + (size_t)i * DD, hn);
        mfma_gemm<128, true, false><<<gemm_grid, TB, 0, stream>>>(agg1, 128, NL, Wns[i - 1],
                                                                  rsq_dst_n2l, bn,
                                                                  ln_g_l + (size_t)i * DD,
                                                                  ln_b_l + (size_t)i * DD, hl);
    }

    // ---- pooling + head ----
    pool_partial<<<NG * PSPLIT, 128, 0, stream>>>(hl, gid_l, part_l, NL);
    pool_partial<<<NG * PSPLIT, 128, 0, stream>>>(hn, gid_n, part_n, NN);
    head_kernel<<<NG, 128, 0, stream>>>(part_l, part_n, gid_l, gid_n,
                                        W_fc, b_fc, W_out, b_out, (float*)d_out);
}

// Round 9
// 497.573 us; speedup vs baseline: 15.2623x; 1.0033x over previous
//
#include <hip/hip_runtime.h>
#include <math.h>

#define NL 50000
#define NN 50000
#define NE 600000
#define NG 64
#define DD 128
#define MPAD 50048
#define PSPLIT 8

typedef unsigned short u16;
typedef unsigned int u32;
using bf16x8 = __attribute__((ext_vector_type(8))) short;
using f32x4  = __attribute__((ext_vector_type(4))) float;

__device__ __forceinline__ u16 f2bf(float x) {
    u32 u = __float_as_uint(x);
    u32 r = (u + 0x7fffu + ((u >> 16) & 1u)) >> 16;
    return (u16)r;
}
__device__ __forceinline__ float bf2f(u16 x) {
    return __uint_as_float(((u32)x) << 16);
}
__device__ __forceinline__ void gload16(const void* g, void* l) {
    __builtin_amdgcn_global_load_lds((const __attribute__((address_space(1))) void*)g,
                                     (__attribute__((address_space(3))) void*)l, 16, 0, 0);
}
__device__ __forceinline__ u32 cvtpk(float lo, float hi) {
    u32 r;
    asm("v_cvt_pk_bf16_f32 %0, %1, %2" : "=v"(r) : "v"(lo), "v"(hi));
    return r;
}

// ---------------- fused histograms + position assignment (both directions) ----------------
__global__ __launch_bounds__(256) void deg_pos(const int* __restrict__ s0a, const int* __restrict__ d0a,
                                               int* __restrict__ hs0, int* __restrict__ hd0,
                                               int* __restrict__ pos0,
                                               const int* __restrict__ s1a, const int* __restrict__ d1a,
                                               int* __restrict__ hs1, int* __restrict__ hd1,
                                               int* __restrict__ pos1, int E) {
    int e = blockIdx.x * blockDim.x + threadIdx.x;
    if (e < E) {
        atomicAdd(&hs0[s0a[e]], 1);
        pos0[e] = atomicAdd(&hd0[d0a[e]], 1);
        atomicAdd(&hs1[s1a[e]], 1);
        pos1[e] = atomicAdd(&hd1[d1a[e]], 1);
    }
}

__global__ void rsq_kernel(const int* __restrict__ cnt, float* __restrict__ out, int n) {
    int i = blockIdx.x * blockDim.x + threadIdx.x;
    if (i < n) out[i] = rsqrtf(fmaxf((float)cnt[i], 1.0f));
}

// ---------------- order-free segment allocation (one atomic per block) ----------------
__global__ __launch_bounds__(256) void alloc_beg(const int* __restrict__ cntA, int* __restrict__ begA, int nA,
                                                 const int* __restrict__ cntB, int* __restrict__ begB, int nB,
                                                 int* __restrict__ ctrs) {
    int nblkA = (nA + 255) >> 8;
    const int* cnt; int* beg; int* ctr; int base_i; int n;
    if ((int)blockIdx.x < nblkA) { cnt = cntA; beg = begA; ctr = ctrs;     base_i = blockIdx.x * 256;           n = nA; }
    else                         { cnt = cntB; beg = begB; ctr = ctrs + 1; base_i = (blockIdx.x - nblkA) * 256; n = nB; }
    int i = base_i + threadIdx.x;
    int v = (i < n) ? cnt[i] : 0;
    __shared__ int sm[256];
    __shared__ int sbase;
    sm[threadIdx.x] = v;
    __syncthreads();
    for (int off = 1; off < 256; off <<= 1) {
        int t = (threadIdx.x >= (unsigned)off) ? sm[threadIdx.x - off] : 0;
        __syncthreads();
        sm[threadIdx.x] += t;
        __syncthreads();
    }
    if (threadIdx.x == 255) sbase = atomicAdd(ctr, sm[255]);
    __syncthreads();
    if (i < n) beg[i] = sbase + sm[threadIdx.x] - v;
}

// ---------------- CSR fill, atomic-free (uses precomputed pos) ----------------
__global__ void fill_csr(const int* __restrict__ src, const int* __restrict__ dst,
                         const int* __restrict__ pos, const int* __restrict__ beg,
                         int* __restrict__ col, int E) {
    int e = blockIdx.x * blockDim.x + threadIdx.x;
    if (e < E) col[beg[dst[e]] + pos[e]] = src[e];
}

// ---------------- W -> bf16, transposed [n][k], K zero-padded to KP ----------------
__global__ void conv_wt(const float* __restrict__ W, u16* __restrict__ Wt, int K, int KP) {
    int i = blockIdx.x * blockDim.x + threadIdx.x;
    if (i >= 128 * KP) return;
    int n = i / KP, k = i % KP;
    float v = (k < K) ? W[(size_t)k * 128 + n] : 0.0f;
    Wt[i] = f2bf(v);
}

// ---------------- MFMA GEMM ----------------
// BM=64, BN=128, 4 waves (2x2), 16x16x32 bf16 MFMA, BK=32, double-buffered LDS.
// AF32=true : A fp32 [M][K] staged via float4 + cvt_pk + ds_write (K runtime, KP compile pad)
// AF32=false: A bf16 [MPAD][KP] staged via global_load_lds
// LN=false: out = f2bf(rsq[m]*raw);  LN=true: out = f2bf(elu(ln(rsq[m]*raw + bias)))
template<int KP, bool LN, bool AF32>
__global__ __launch_bounds__(256) void mfma_gemm(const void* __restrict__ Av, int K, int M,
                                                 const u16* __restrict__ Wt,
                                                 const float* __restrict__ rsq,
                                                 const float* __restrict__ bias,
                                                 const float* __restrict__ gw,
                                                 const float* __restrict__ bln,
                                                 u16* __restrict__ out) {
    constexpr int NT = KP / 32;
    __shared__ __align__(16) u16 As[2][64 * 32];
    __shared__ __align__(16) u16 Bs[2][128 * 32];
    __shared__ float rs[2][64][2];
    const int t    = threadIdx.x;
    const int lane = t & 63;
    const int wid  = t >> 6;
    const int wr   = wid >> 1;
    const int wc   = wid & 1;
    const int brow = blockIdx.x * 64;
    const int l15  = lane & 15;
    const int kg   = lane >> 4;

    f32x4 acc[2][4];
#pragma unroll
    for (int mi = 0; mi < 2; ++mi)
#pragma unroll
        for (int ni = 0; ni < 4; ++ni) acc[mi][ni] = (f32x4){0.f, 0.f, 0.f, 0.f};

    // A addressing: LDS[row][chunk] = src[row][chunk ^ key(row)], key = (row>>1)&3
    const int ar   = t >> 2;
    const int ac   = t & 3;
    const int akey = (ar >> 1) & 3;
    const int grow = brow + ar;
    // B addressing
    const int bn0 = t >> 2;
    const int bn1 = (256 + t) >> 2;
    const u16* b_src0 = Wt + (size_t)bn0 * KP + ((t & 3) ^ ((bn0 >> 1) & 3)) * 8;
    const u16* b_src1 = Wt + (size_t)bn1 * KP + ((t & 3) ^ ((bn1 >> 1) & 3)) * 8;
    const u16* a_src = nullptr;
    if constexpr (!AF32) a_src = (const u16*)Av + (size_t)grow * KP + (ac ^ akey) * 8;

#define STAGE_B(kt, buf)                                                          \
    do {                                                                          \
        gload16(b_src0 + (kt) * 32, (char*)&Bs[buf][0] + wid * 1024);             \
        gload16(b_src1 + (kt) * 32, (char*)&Bs[buf][0] + 4096 + wid * 1024);      \
    } while (0)
#define STAGE_A16(kt, buf)                                                        \
    gload16(a_src + (kt) * 32, (char*)&As[buf][0] + wid * 1024)

    struct A8 { float4 x, y; };
    auto loadA = [&](int kt) -> A8 {
        const float* A = (const float*)Av;
        int kbase = kt * 32 + (ac ^ akey) * 8;
        const float* p = A + (size_t)grow * K + kbase;
        A8 r;
        bool rowok = grow < M;
        r.x = (rowok && kbase + 4 <= K) ? *(const float4*)p       : make_float4(0.f, 0.f, 0.f, 0.f);
        r.y = (rowok && kbase + 8 <= K) ? *(const float4*)(p + 4) : make_float4(0.f, 0.f, 0.f, 0.f);
        return r;
    };
    auto writeA = [&](int buf, const A8& r) {
        uint4 w = make_uint4(cvtpk(r.x.x, r.x.y), cvtpk(r.x.z, r.x.w),
                             cvtpk(r.y.x, r.y.y), cvtpk(r.y.z, r.y.w));
        *(uint4*)&As[buf][ar * 32 + ac * 8] = w;
    };

    A8 rnext{};
    if constexpr (AF32) {
        A8 r0 = loadA(0);
        if (NT > 1) rnext = loadA(1);
        writeA(0, r0);
        STAGE_B(0, 0);
    } else {
        STAGE_A16(0, 0);
        STAGE_B(0, 0);
    }
    __syncthreads();

    const int fo = (kg ^ ((l15 >> 1) & 3)) * 8;
#pragma unroll
    for (int kt = 0; kt < NT; ++kt) {
        const int cur = kt & 1;
        if (kt + 1 < NT) {
            if constexpr (AF32) {
                writeA(cur ^ 1, rnext);
                STAGE_B(kt + 1, cur ^ 1);
                if (kt + 2 < NT) rnext = loadA(kt + 2);
            } else {
                STAGE_A16(kt + 1, cur ^ 1);
                STAGE_B(kt + 1, cur ^ 1);
            }
        }
        bf16x8 a0 = *(const bf16x8*)&As[cur][(wr * 32 +  0 + l15) * 32 + fo];
        bf16x8 a1 = *(const bf16x8*)&As[cur][(wr * 32 + 16 + l15) * 32 + fo];
#pragma unroll
        for (int ni = 0; ni < 4; ++ni) {
            bf16x8 b = *(const bf16x8*)&Bs[cur][(wc * 64 + ni * 16 + l15) * 32 + fo];
            acc[0][ni] = __builtin_amdgcn_mfma_f32_16x16x32_bf16(a0, b, acc[0][ni], 0, 0, 0);
            acc[1][ni] = __builtin_amdgcn_mfma_f32_16x16x32_bf16(a1, b, acc[1][ni], 0, 0, 0);
        }
        __syncthreads();
    }
#undef STAGE_B
#undef STAGE_A16

    if constexpr (!LN) {
#pragma unroll
        for (int mi = 0; mi < 2; ++mi)
#pragma unroll
            for (int r = 0; r < 4; ++r) {
                int go = brow + wr * 32 + mi * 16 + kg * 4 + r;
                if (go < M) {
                    float s = rsq[go];
#pragma unroll
                    for (int ni = 0; ni < 4; ++ni)
                        out[(size_t)go * 128 + wc * 64 + ni * 16 + l15] = f2bf(acc[mi][ni][r] * s);
                }
            }
    } else {
        float b4[4], g4[4], bl4[4];
#pragma unroll
        for (int ni = 0; ni < 4; ++ni) {
            int c = wc * 64 + ni * 16 + l15;
            b4[ni] = bias[c]; g4[ni] = gw[c]; bl4[ni] = bln[c];
        }
        float rsv[2][4];
#pragma unroll
        for (int mi = 0; mi < 2; ++mi)
#pragma unroll
            for (int r = 0; r < 4; ++r) {
                int go = brow + wr * 32 + mi * 16 + kg * 4 + r;
                rsv[mi][r] = (go < M) ? rsq[go] : 0.0f;
            }
#pragma unroll
        for (int mi = 0; mi < 2; ++mi)
#pragma unroll
            for (int r = 0; r < 4; ++r) {
                int lrow = wr * 32 + mi * 16 + kg * 4 + r;
                float s1 = 0.f, s2 = 0.f;
#pragma unroll
                for (int ni = 0; ni < 4; ++ni) {
                    float xv = acc[mi][ni][r] * rsv[mi][r] + b4[ni];
                    s1 += xv; s2 += xv * xv;
                }
#pragma unroll
                for (int m = 1; m < 16; m <<= 1) {
                    s1 += __shfl_xor(s1, m, 64);
                    s2 += __shfl_xor(s2, m, 64);
                }
                if (l15 == 0) { rs[0][lrow][wc] = s1; rs[1][lrow][wc] = s2; }
            }
        __syncthreads();
#pragma unroll
        for (int mi = 0; mi < 2; ++mi)
#pragma unroll
            for (int r = 0; r < 4; ++r) {
                int lrow = wr * 32 + mi * 16 + kg * 4 + r;
                int go = brow + lrow;
                if (go < M) {
                    float S1 = rs[0][lrow][0] + rs[0][lrow][1];
                    float S2 = rs[1][lrow][0] + rs[1][lrow][1];
                    float mu = S1 * (1.0f / 128.0f);
                    float var = S2 * (1.0f / 128.0f) - mu * mu;
                    float rstd = rsqrtf(fmaxf(var, 0.0f) + 1e-5f);
#pragma unroll
                    for (int ni = 0; ni < 4; ++ni) {
                        float xv = acc[mi][ni][r] * rsv[mi][r] + b4[ni];
                        float y = (xv - mu) * rstd * g4[ni] + bl4[ni];
                        y = (y > 0.0f) ? y : expm1f(y);
                        out[(size_t)go * 128 + wc * 64 + ni * 16 + l15] = f2bf(y);
                    }
                }
            }
    }
}

// ---------------- layer-0 gather (bf16 xs, unit weight) + LN + ELU -> bf16 ----------------
__global__ __launch_bounds__(256) void gather_ln(const u16* __restrict__ xs,
                                                 const int* __restrict__ beg,
                                                 const int* __restrict__ cnt,
                                                 const int* __restrict__ col,
                                                 const float* __restrict__ rsq_in,
                                                 const float* __restrict__ bias,
                                                 const float* __restrict__ g,
                                                 const float* __restrict__ bln,
                                                 u16* __restrict__ out, int M) {
    int row  = blockIdx.x * 4 + (threadIdx.x >> 6);
    int lane = threadIdx.x & 63;
    if (row >= M) return;
    int b = beg[row], n = cnt[row];
    const u32* x32 = (const u32*)xs;

    float a0 = 0.f, a1 = 0.f, c0 = 0.f, c1 = 0.f;
    int e = 0;
    for (; e + 3 < n; e += 4) {
        int s0 = col[b + e], s1 = col[b + e + 1], s2 = col[b + e + 2], s3 = col[b + e + 3];
        u32 p0 = x32[(size_t)s0 * 64 + lane];
        u32 p1 = x32[(size_t)s1 * 64 + lane];
        u32 p2 = x32[(size_t)s2 * 64 + lane];
        u32 p3 = x32[(size_t)s3 * 64 + lane];
        a0 += bf2f((u16)p0) + bf2f((u16)p1);
        a1 += bf2f((u16)(p0 >> 16)) + bf2f((u16)(p1 >> 16));
        c0 += bf2f((u16)p2) + bf2f((u16)p3);
        c1 += bf2f((u16)(p2 >> 16)) + bf2f((u16)(p3 >> 16));
    }
    for (; e < n; ++e) {
        u32 p = x32[(size_t)col[b + e] * 64 + lane];
        a0 += bf2f((u16)p);
        a1 += bf2f((u16)(p >> 16));
    }
    a0 += c0; a1 += c1;

    float sc = rsq_in[row];
    float2 bv = *(const float2*)&bias[lane * 2];
    float x0 = a0 * sc + bv.x;
    float x1 = a1 * sc + bv.y;

    float sum = x0 + x1;
#pragma unroll
    for (int m = 1; m < 64; m <<= 1) sum += __shfl_xor(sum, m, 64);
    float mu = sum * (1.0f / 128.0f);

    float d0 = x0 - mu, d1 = x1 - mu;
    float ss = d0 * d0 + d1 * d1;
#pragma unroll
    for (int m = 1; m < 64; m <<= 1) ss += __shfl_xor(ss, m, 64);
    float rstd = rsqrtf(ss * (1.0f / 128.0f) + 1e-5f);

    float2 gv = *(const float2*)&g[lane * 2];
    float2 bl = *(const float2*)&bln[lane * 2];
    float y0 = d0 * rstd * gv.x + bl.x;
    float y1 = d1 * rstd * gv.y + bl.y;
    y0 = (y0 > 0.0f) ? y0 : expm1f(y0);
    y1 = (y1 > 0.0f) ? y1 : expm1f(y1);
    ((u32*)out)[(size_t)row * 64 + lane] = (u32)f2bf(y0) | ((u32)f2bf(y1) << 16);
}

// ---------------- layers 1-2 gather: agg[dst] = bf16( sum rsq_src[s]*h[s] ) ----------------
__global__ __launch_bounds__(256) void gather_scale(const u16* __restrict__ h,
                                                    const int* __restrict__ beg,
                                                    const int* __restrict__ cnt,
                                                    const int* __restrict__ col,
                                                    const float* __restrict__ rsq_src,
                                                    u16* __restrict__ agg, int M) {
    int row  = blockIdx.x * 4 + (threadIdx.x >> 6);
    int lane = threadIdx.x & 63;
    if (row >= M) return;
    int b = beg[row], n = cnt[row];
    const u32* h32 = (const u32*)h;

    float a0 = 0.f, a1 = 0.f, c0 = 0.f, c1 = 0.f;
    int e = 0;
    for (; e + 3 < n; e += 4) {
        int s0 = col[b + e], s1 = col[b + e + 1], s2 = col[b + e + 2], s3 = col[b + e + 3];
        float r0 = rsq_src[s0], r1 = rsq_src[s1], r2 = rsq_src[s2], r3 = rsq_src[s3];
        u32 p0 = h32[(size_t)s0 * 64 + lane];
        u32 p1 = h32[(size_t)s1 * 64 + lane];
        u32 p2 = h32[(size_t)s2 * 64 + lane];
        u32 p3 = h32[(size_t)s3 * 64 + lane];
        a0 = fmaf(r0, bf2f((u16)p0), a0); a1 = fmaf(r0, bf2f((u16)(p0 >> 16)), a1);
        c0 = fmaf(r1, bf2f((u16)p1), c0); c1 = fmaf(r1, bf2f((u16)(p1 >> 16)), c1);
        a0 = fmaf(r2, bf2f((u16)p2), a0); a1 = fmaf(r2, bf2f((u16)(p2 >> 16)), a1);
        c0 = fmaf(r3, bf2f((u16)p3), c0); c1 = fmaf(r3, bf2f((u16)(p3 >> 16)), c1);
    }
    for (; e < n; ++e) {
        int s = col[b + e];
        float r = rsq_src[s];
        u32 p = h32[(size_t)s * 64 + lane];
        a0 = fmaf(r, bf2f((u16)p), a0);
        a1 = fmaf(r, bf2f((u16)(p >> 16)), a1);
    }
    a0 += c0; a1 += c1;
    ((u32*)agg)[(size_t)row * 64 + lane] = (u32)f2bf(a0) | ((u32)f2bf(a1) << 16);
}

// ---------------- segmented pooling from bf16 h ----------------
__global__ __launch_bounds__(128) void pool_partial(const u16* __restrict__ h,
                                                    const int* __restrict__ gid,
                                                    float* __restrict__ partial, int M) {
    int g = blockIdx.x / PSPLIT;
    int p = blockIdx.x % PSPLIT;
    int j = threadIdx.x;
    __shared__ int bounds[2];
    if (j < 2) {
        int target = g + j;
        int lo = 0, hi = M;
        while (lo < hi) { int mid = (lo + hi) >> 1; if (gid[mid] < target) lo = mid + 1; else hi = mid; }
        bounds[j] = lo;
    }
    __syncthreads();
    int beg = bounds[0], end = bounds[1];
    int len = end - beg;
    int chunk = (len + PSPLIT - 1) / PSPLIT;
    int s0i = beg + p * chunk;
    int e0i = min(s0i + chunk, end);

    float s0 = 0.f, s1 = 0.f, s2 = 0.f, s3 = 0.f;
    int i = s0i;
    for (; i + 3 < e0i; i += 4) {
        s0 += bf2f(h[(size_t)(i + 0) * 128 + j]);
        s1 += bf2f(h[(size_t)(i + 1) * 128 + j]);
        s2 += bf2f(h[(size_t)(i + 2) * 128 + j]);
        s3 += bf2f(h[(size_t)(i + 3) * 128 + j]);
    }
    for (; i < e0i; ++i) s0 += bf2f(h[(size_t)i * 128 + j]);
    partial[(size_t)(g * PSPLIT + p) * 128 + j] = (s0 + s1) + (s2 + s3);
}

// ---------------- head ----------------
__global__ __launch_bounds__(128) void head_kernel(const float* __restrict__ part_l,
                                                   const float* __restrict__ part_n,
                                                   const int* __restrict__ gid_l,
                                                   const int* __restrict__ gid_n,
                                                   const float* __restrict__ W_fc,
                                                   const float* __restrict__ b_fc,
                                                   const float* __restrict__ W_out,
                                                   const float* __restrict__ b_out,
                                                   float* __restrict__ out) {
    int g = blockIdx.x;
    int j = threadIdx.x;
    __shared__ float hg[128];
    __shared__ float red[2];
    __shared__ int bounds[4];
    if (j < 4) {
        const int* gid = (j < 2) ? gid_l : gid_n;
        int target = g + (j & 1);
        int lo = 0, hi = 50000;
        while (lo < hi) { int mid = (lo + hi) >> 1; if (gid[mid] < target) lo = mid + 1; else hi = mid; }
        bounds[j] = lo;
    }
    __syncthreads();
    float cl = fmaxf((float)(bounds[1] - bounds[0]), 1.0f);
    float cn = fmaxf((float)(bounds[3] - bounds[2]), 1.0f);
    float sl = 0.f, sn = 0.f;
#pragma unroll
    for (int p = 0; p < PSPLIT; ++p) {
        sl += part_l[(size_t)(g * PSPLIT + p) * 128 + j];
        sn += part_n[(size_t)(g * PSPLIT + p) * 128 + j];
    }
    hg[j] = sl / cl + sn / cn;
    __syncthreads();
    float acc = b_fc[j];
#pragma unroll 8
    for (int k = 0; k < 128; ++k) acc = fmaf(hg[k], W_fc[k * 128 + j], acc);
    float fc = fmaxf(acc, 0.0f);
    float v = fc * W_out[j];
#pragma unroll
    for (int m = 1; m < 64; m <<= 1) v += __shfl_xor(v, m, 64);
    if ((j & 63) == 0) red[j >> 6] = v;
    __syncthreads();
    if (j == 0) out[g] = red[0] + red[1] + b_out[0];
}

static inline size_t align_up(size_t x, size_t a) { return (x + a - 1) & ~(a - 1); }

extern "C" void kernel_launch(void* const* d_in, const int* in_sizes, int n_in,
                              void* d_out, int out_size, void* d_ws, size_t ws_size,
                              hipStream_t stream) {
    const float* feat_l = (const float*)d_in[0];
    const float* feat_n = (const float*)d_in[1];
    const float* W0_l2n = (const float*)d_in[2];
    const float* b0_l2n = (const float*)d_in[3];
    const float* W0_n2l = (const float*)d_in[4];
    const float* b0_n2l = (const float*)d_in[5];
    const float* W_l2n  = (const float*)d_in[6];
    const float* b_l2n  = (const float*)d_in[7];
    const float* W_n2l  = (const float*)d_in[8];
    const float* b_n2l  = (const float*)d_in[9];
    const float* ln_g_n = (const float*)d_in[10];
    const float* ln_b_n = (const float*)d_in[11];
    const float* ln_g_l = (const float*)d_in[12];
    const float* ln_b_l = (const float*)d_in[13];
    const float* W_fc   = (const float*)d_in[14];
    const float* b_fc   = (const float*)d_in[15];
    const float* W_out  = (const float*)d_in[16];
    const float* b_out  = (const float*)d_in[17];
    const int* src_l2n  = (const int*)d_in[18];
    const int* dst_l2n  = (const int*)d_in[19];
    const int* src_n2l  = (const int*)d_in[20];
    const int* dst_n2l  = (const int*)d_in[21];
    const int* gid_l    = (const int*)d_in[22];
    const int* gid_n    = (const int*)d_in[23];

    // ---- workspace ----
    char* ws = (char*)d_ws;
    size_t off = 0;
    auto take = [&](size_t bytes) { char* p = ws + off; off = align_up(off + bytes, 256); return p; };
    int*   icnt        = (int*)take(200000 * 4);
    float* rsq         = (float*)take(200000 * 4);
    int*   beg_l2n     = (int*)take(NN * 4);
    int*   beg_n2l     = (int*)take(NL * 4);
    int*   ctrs        = (int*)take(2 * 4);
    int*   pos_l2n     = (int*)take((size_t)NE * 4);
    int*   pos_n2l     = (int*)take((size_t)NE * 4);
    int*   col_l2n     = (int*)take((size_t)NE * 4);
    int*   col_n2l     = (int*)take((size_t)NE * 4);
    u16*   Wt0_l2n     = (u16*)take(128 * 320 * 2);
    u16*   Wt0_n2l     = (u16*)take(128 * 224 * 2);
    u16*   Wt_l2n0     = (u16*)take(128 * 128 * 2);
    u16*   Wt_l2n1     = (u16*)take(128 * 128 * 2);
    u16*   Wt_n2l0     = (u16*)take(128 * 128 * 2);
    u16*   Wt_n2l1     = (u16*)take(128 * 128 * 2);
    u16*   xs0         = (u16*)take((size_t)MPAD * 128 * 2);   // later agg0
    u16*   xs1         = (u16*)take((size_t)MPAD * 128 * 2);   // later agg1
    u16*   hl          = (u16*)take((size_t)MPAD * 128 * 2);
    u16*   hn          = (u16*)take((size_t)MPAD * 128 * 2);
    float* part_l      = (float*)take((size_t)NG * PSPLIT * 128 * 4);
    float* part_n      = (float*)take((size_t)NG * PSPLIT * 128 * 4);
    u16* agg0 = xs0;
    u16* agg1 = xs1;

    int* icnt_src_l2n = icnt;
    int* icnt_dst_l2n = icnt + NL;
    int* icnt_src_n2l = icnt + NL + NN;
    int* icnt_dst_n2l = icnt + NL + 2 * NN;
    float* rsq_src_l2n = rsq;
    float* rsq_dst_l2n = rsq + NL;
    float* rsq_src_n2l = rsq + NL + NN;
    float* rsq_dst_n2l = rsq + NL + 2 * NN;

    const int TB = 256;
    const int gemm_grid = MPAD / 64;              // 782
    const int gath_grid = (NL + 3) / 4;
    const int edge_grid = (NE + TB - 1) / TB;
    const int alloc_grid = 2 * ((NL + 255) / 256);

    // ---- histograms + positions (half the atomics of R6) ----
    hipMemsetAsync(icnt, 0, 200000 * sizeof(int), stream);
    hipMemsetAsync(ctrs, 0, 2 * sizeof(int), stream);
    deg_pos<<<edge_grid, TB, 0, stream>>>(src_l2n, dst_l2n, icnt_src_l2n, icnt_dst_l2n, pos_l2n,
                                          src_n2l, dst_n2l, icnt_src_n2l, icnt_dst_n2l, pos_n2l, NE);
    rsq_kernel<<<(200000 + TB - 1) / TB, TB, 0, stream>>>(icnt, rsq, 200000);
    alloc_beg<<<alloc_grid, TB, 0, stream>>>(icnt_dst_l2n, beg_l2n, NN,
                                             icnt_dst_n2l, beg_n2l, NL, ctrs);
    fill_csr<<<edge_grid, TB, 0, stream>>>(src_l2n, dst_l2n, pos_l2n, beg_l2n, col_l2n, NE);
    fill_csr<<<edge_grid, TB, 0, stream>>>(src_n2l, dst_n2l, pos_n2l, beg_n2l, col_n2l, NE);

    // ---- weight conversion ----
    conv_wt<<<(128 * 320 + TB - 1) / TB, TB, 0, stream>>>(W0_l2n, Wt0_l2n, 300, 320);
    conv_wt<<<(128 * 224 + TB - 1) / TB, TB, 0, stream>>>(W0_n2l, Wt0_n2l, 200, 224);
    conv_wt<<<(128 * 128 + TB - 1) / TB, TB, 0, stream>>>(W_l2n,             Wt_l2n0, 128, 128);
    conv_wt<<<(128 * 128 + TB - 1) / TB, TB, 0, stream>>>(W_l2n + 128 * 128, Wt_l2n1, 128, 128);
    conv_wt<<<(128 * 128 + TB - 1) / TB, TB, 0, stream>>>(W_n2l,             Wt_n2l0, 128, 128);
    conv_wt<<<(128 * 128 + TB - 1) / TB, TB, 0, stream>>>(W_n2l + 128 * 128, Wt_n2l1, 128, 128);

    // ---- layer 0: project fp32 feats directly (fused cvt staging), then gather+LN ----
    mfma_gemm<320, false, true><<<gemm_grid, TB, 0, stream>>>(feat_l, 300, NL, Wt0_l2n,
                                                              rsq_src_l2n, nullptr, nullptr,
                                                              nullptr, xs0);
    mfma_gemm<224, false, true><<<gemm_grid, TB, 0, stream>>>(feat_n, 200, NN, Wt0_n2l,
                                                              rsq_src_n2l, nullptr, nullptr,
                                                              nullptr, xs1);
    gather_ln<<<gath_grid, TB, 0, stream>>>(xs0, beg_l2n, icnt_dst_l2n, col_l2n, rsq_dst_l2n,
                                            b0_l2n, ln_g_n, ln_b_n, hn, NN);
    gather_ln<<<gath_grid, TB, 0, stream>>>(xs1, beg_n2l, icnt_dst_n2l, col_n2l, rsq_dst_n2l,
                                            b0_n2l, ln_g_l, ln_b_l, hl, NL);

    // ---- layers 1,2: gather-first (bf16), GEMM with fused LN+ELU ----
    const u16* Wls[2] = {Wt_l2n0, Wt_l2n1};
    const u16* Wns[2] = {Wt_n2l0, Wt_n2l1};
    for (int i = 1; i <= 2; ++i) {
        const float* bl = b_l2n + (size_t)(i - 1) * DD;
        const float* bn = b_n2l + (size_t)(i - 1) * DD;
        gather_scale<<<gath_grid, TB, 0, stream>>>(hl, beg_l2n, icnt_dst_l2n, col_l2n,
                                                   rsq_src_l2n, agg0, NN);
        gather_scale<<<gath_grid, TB, 0, stream>>>(hn, beg_n2l, icnt_dst_n2l, col_n2l,
                                                   rsq_src_n2l, agg1, NL);
        mfma_gemm<128, true, false><<<gemm_grid, TB, 0, stream>>>(agg0, 128, NN, Wls[i - 1],
                                                                  rsq_dst_l2n, bl,
                                                                  ln_g_n + (size_t)i * DD,
                                                                  ln_b_n + (size_t)i * DD, hn);
        mfma_gemm<128, true, false><<<gemm_grid, TB, 0, stream>>>(agg1, 128, NL, Wns[i - 1],
                                                                  rsq_dst_n2l, bn,
                                                                  ln_g_l + (size_t)i * DD,
                                                                  ln_b_l + (size_t)i * DD, hl);
    }

    // ---- pooling + head ----
    pool_partial<<<NG * PSPLIT, 128, 0, stream>>>(hl, gid_l, part_l, NL);
    pool_partial<<<NG * PSPLIT, 128, 0, stream>>>(hn, gid_n, part_n, NN);
    head_kernel<<<NG, 128, 0, stream>>>(part_l, part_n, gid_l, gid_n,
                                        W_fc, b_fc, W_out, b_out, (float*)d_out);
}